// Round 2
// baseline (555.931 us; speedup 1.0000x reference)
//
#include <hip/hip_runtime.h>

#define N_NODES 100000
#define N_EDGES 600000
#define NCHUNK 98            // ceil(100000/1024)
#define LDS_STRIDE 136       // ushorts per row: 128 + 8 pad
#define NPART 8              // dst partitions, aligned to 8 XCDs
#define PART_SZ (N_NODES / NPART)   // 12500
#define ECHUNK 2048          // edges per bin_kernel block
#define ACH 293              // ceil(600000/2048)
#define BIN_CAP 81920        // per (rel,part) bin capacity (mean 75000, 27 sigma)

typedef __attribute__((ext_vector_type(8))) short short8;
typedef __attribute__((ext_vector_type(4))) float f32x4;
typedef __attribute__((ext_vector_type(2))) unsigned short ushort2v;
typedef __attribute__((ext_vector_type(8))) unsigned short ushort8v;

__device__ __forceinline__ unsigned short f2b(float f) {   // fp32 -> bf16 RNE
    unsigned u = __builtin_bit_cast(unsigned, f);
    return (unsigned short)((u + 0x7fffu + ((u >> 16) & 1u)) >> 16);
}
__device__ __forceinline__ float b2f(unsigned short b) {
    return __builtin_bit_cast(float, (unsigned)b << 16);
}

// ---------------------------------------------------------------------------
// Pass A: 3-bit counting sort of edges by dst partition. Each edge packed
// into 4B: src (17b) | local-dst (14b). LDS-staged compaction -> coalesced
// global writes into per-(rel,part) bins with per-block reserved runs.
__global__ __launch_bounds__(256) void bin_kernel(const int* __restrict__ e0,
                                                  const int* __restrict__ e1,
                                                  const int* __restrict__ e2,
                                                  unsigned* __restrict__ bins,
                                                  int* __restrict__ bincur) {
    int r = blockIdx.y;
    const int* ei = (r == 0) ? e0 : (r == 1 ? e1 : e2);
    int base = blockIdx.x * ECHUNK;
    int nhere = min(ECHUNK, N_EDGES - base);
    __shared__ int lhist[8], lstart[8], lcur[8], gbase[8];
    __shared__ unsigned led[ECHUNK];
    int tid = threadIdx.x;
    if (tid < 8) { lhist[tid] = 0; lcur[tid] = 0; }
    __syncthreads();

    unsigned pk[8]; int bn[8];
#pragma unroll
    for (int k = 0; k < 8; k++) {
        int i = tid + k * 256;
        bn[k] = -1;
        if (i < nhere) {
            int e = base + i;
            int s = ei[e], d = ei[N_EDGES + e];
            int b = d / PART_SZ;
            int ld = d - b * PART_SZ;
            pk[k] = (unsigned)s | ((unsigned)ld << 17);
            bn[k] = b;
            atomicAdd(&lhist[b], 1);
        }
    }
    __syncthreads();
    if (tid == 0) {
        int run = 0;
        for (int b = 0; b < 8; b++) { lstart[b] = run; run += lhist[b]; }
    }
    __syncthreads();
#pragma unroll
    for (int k = 0; k < 8; k++) {
        if (bn[k] >= 0) {
            int slot = atomicAdd(&lcur[bn[k]], 1);
            led[lstart[bn[k]] + slot] = pk[k];
        }
    }
    if (tid < 8) gbase[tid] = atomicAdd(&bincur[r * 8 + tid], lhist[tid]);
    __syncthreads();
    for (int i = tid; i < nhere; i += 256) {
        int b = 0;
#pragma unroll
        for (int bb = 1; bb < 8; bb++) if (i >= lstart[bb]) b = bb;
        bins[(size_t)(r * 8 + b) * BIN_CAP + gbase[b] + (i - lstart[b])] = led[i];
    }
}

// ---------------------------------------------------------------------------
// Partition-local degree count from bins: blockIdx.x = partition -> XCD.
// Per-XCD working set: 0.9MB bin reads + 50KB cnt slice, all L2-resident.
__global__ __launch_bounds__(256) void count_kernel(const unsigned* __restrict__ bins,
                                                    const int* __restrict__ bincur,
                                                    int* __restrict__ cnt) {
    int p = blockIdx.x, r = blockIdx.z;
    int len = bincur[r * 8 + p];
    const unsigned* b = bins + (size_t)(r * 8 + p) * BIN_CAP;
    int* c = cnt + r * N_NODES + p * PART_SZ;
    int base = blockIdx.y * 2048 + threadIdx.x;
#pragma unroll
    for (int k = 0; k < 8; k++) {
        int i = base + k * 256;
        if (i < len) atomicAdd(&c[b[i] >> 17], 1);
    }
}

// ---------------------------------------------------------------------------
__global__ __launch_bounds__(1024) void scan1_kernel(const int* __restrict__ cnt,
                                                     int* __restrict__ rowstart,
                                                     int* __restrict__ blocksum) {
    int r = blockIdx.y;
    int tid = threadIdx.x, lane = tid & 63, wid = tid >> 6;
    int i = blockIdx.x * 1024 + tid;
    __shared__ int wsum[16];
    int v = (i < N_NODES) ? cnt[r * N_NODES + i] : 0;
    int incl = v;
#pragma unroll
    for (int off = 1; off < 64; off <<= 1) {
        int t = __shfl_up(incl, off);
        if (lane >= off) incl += t;
    }
    if (lane == 63) wsum[wid] = incl;
    __syncthreads();
    if (wid == 0) {
        int wv = (lane < 16) ? wsum[lane] : 0;
#pragma unroll
        for (int off = 1; off < 16; off <<= 1) {
            int t = __shfl_up(wv, off);
            if (lane >= off) wv += t;
        }
        if (lane < 16) wsum[lane] = wv;
    }
    __syncthreads();
    int woff = (wid > 0) ? wsum[wid - 1] : 0;
    if (i < N_NODES) rowstart[r * N_NODES + i] = woff + incl - v;
    if (tid == 0) blocksum[r * NCHUNK + blockIdx.x] = wsum[15];
}

__global__ __launch_bounds__(128) void scan2_kernel(int* __restrict__ blocksum) {
    __shared__ int s[3 * NCHUNK];
    int tid = threadIdx.x;
    for (int i = tid; i < 3 * NCHUNK; i += 128) s[i] = blocksum[i];
    __syncthreads();
    if (tid < 3) {
        int run = 0;
        for (int j = 0; j < NCHUNK; j++) { int t = s[tid * NCHUNK + j]; s[tid * NCHUNK + j] = run; run += t; }
    }
    __syncthreads();
    for (int i = tid; i < 3 * NCHUNK; i += 128) blocksum[i] = s[i];
}

// Finalize rowstart and seed cursor = rowstart.
__global__ void scan3_kernel(int* __restrict__ rowstart, const int* __restrict__ blocksum,
                             int* __restrict__ cursor) {
    int r = blockIdx.y;
    int i = blockIdx.x * 256 + threadIdx.x;
    if (i < N_NODES) {
        int v = rowstart[r * N_NODES + i] + blocksum[r * NCHUNK + (i >> 10)];
        rowstart[r * N_NODES + i] = v;
        cursor[r * N_NODES + i] = v;
    }
}

// ---------------------------------------------------------------------------
// Partition-local CSR fill from bins. Per-XCD working set ~2MB (bin reads +
// adj slice + cursor slice) fits 4MiB L2 -> adj lines fill before eviction.
__global__ __launch_bounds__(256) void fill_kernel(const unsigned* __restrict__ bins,
                                                   const int* __restrict__ bincur,
                                                   int* __restrict__ cursor,
                                                   int* __restrict__ adj) {
    int p = blockIdx.x, r = blockIdx.z;
    int len = bincur[r * 8 + p];
    const unsigned* b = bins + (size_t)(r * 8 + p) * BIN_CAP;
    int* cur = cursor + r * N_NODES + p * PART_SZ;
    int* a = adj + (size_t)r * N_EDGES;
    int base = blockIdx.y * 2048 + threadIdx.x;
#pragma unroll
    for (int k = 0; k < 8; k++) {
        int i = base + k * 256;
        if (i < len) {
            unsigned v = b[i];
            int pos = atomicAdd(&cur[v >> 17], 1);
            a[pos] = (int)(v & 0x1FFFFu);
        }
    }
}

// ---------------------------------------------------------------------------
// x (fp32) -> xb (bf16), 8 elems/thread.
__global__ void xcast_kernel(const float* __restrict__ x, unsigned short* __restrict__ xb) {
    int idx = blockIdx.x * 256 + threadIdx.x;
    const float4* p = (const float4*)x + (size_t)idx * 2;
    float4 a = p[0], b = p[1];
    ushort8v o;
    o[0] = f2b(a.x); o[1] = f2b(a.y); o[2] = f2b(a.z); o[3] = f2b(a.w);
    o[4] = f2b(b.x); o[5] = f2b(b.y); o[6] = f2b(b.z); o[7] = f2b(b.w);
    *(ushort8v*)(xb + (size_t)idx * 8) = o;
}

// ---------------------------------------------------------------------------
// Pre-swizzle weights into MFMA B-fragment order.
__global__ void wprep_kernel(const float* __restrict__ Wl, const float* __restrict__ Wr,
                             const float* __restrict__ Wl_f, const float* __restrict__ Wr_f,
                             unsigned short* __restrict__ Wfrag, unsigned short* __restrict__ Wfrag2) {
    int idx = blockIdx.x * 256 + threadIdx.x;      // 448 blocks = 114688 threads
    int j = idx & 7, lane = (idx >> 3) & 63;
    int quad = lane >> 4, l16 = lane & 15;
    if (idx < 98304) {
        int t = (idx >> 9) & 1, s = (idx >> 10) & 7, w = (idx >> 13) & 3, r = idx >> 15;
        int k = s * 32 + quad * 8 + j;
        int n = w * 32 + t * 16 + l16;
        float v = (k < 128) ? Wl[((size_t)r * 128 + k) * 128 + n]
                            : Wr[((size_t)r * 128 + (k - 128)) * 128 + n];
        Wfrag[idx] = f2b(v);
    } else {
        int i2 = idx - 98304;
        if (i2 < 16384) {
            int t = (i2 >> 9) & 1, s = (i2 >> 10) & 3, w = (i2 >> 12) & 3;
            int k = s * 32 + quad * 8 + j;
            int n = w * 32 + t * 16 + l16;
            float v = (n < 64) ? Wl_f[(size_t)k * 64 + n] : Wr_f[(size_t)k * 64 + (n - 64)];
            Wfrag2[i2] = f2b(v);
        }
    }
}

// ---------------------------------------------------------------------------
// Gather-mean from bf16 rows (256 B/row): one wave/node, ushort2 per lane.
__global__ void gather128_kernel(const unsigned short* __restrict__ xb, const int* __restrict__ adj,
                                 const int* __restrict__ rowstart, const int* __restrict__ cnt,
                                 unsigned short* __restrict__ aggb) {
    int node = (blockIdx.x * blockDim.x + threadIdx.x) >> 6;
    int lane = threadIdx.x & 63;
    if (node >= N_NODES) return;
    int start = rowstart[node];
    int deg = cnt[node];
    float ax = 0.f, ay = 0.f;
    int j = 0;
    for (; j + 4 <= deg; j += 4) {
        int s0 = adj[start + j], s1 = adj[start + j + 1];
        int s2 = adj[start + j + 2], s3 = adj[start + j + 3];
        ushort2v v0 = *(const ushort2v*)(xb + (size_t)s0 * 128 + lane * 2);
        ushort2v v1 = *(const ushort2v*)(xb + (size_t)s1 * 128 + lane * 2);
        ushort2v v2 = *(const ushort2v*)(xb + (size_t)s2 * 128 + lane * 2);
        ushort2v v3 = *(const ushort2v*)(xb + (size_t)s3 * 128 + lane * 2);
        ax += b2f(v0.x) + b2f(v1.x) + b2f(v2.x) + b2f(v3.x);
        ay += b2f(v0.y) + b2f(v1.y) + b2f(v2.y) + b2f(v3.y);
    }
    for (; j < deg; j++) {
        int s = adj[start + j];
        ushort2v v = *(const ushort2v*)(xb + (size_t)s * 128 + lane * 2);
        ax += b2f(v.x); ay += b2f(v.y);
    }
    float inv = 1.0f / fmaxf((float)deg, 1.0f);
    ushort2v o; o.x = f2b(ax * inv); o.y = f2b(ay * inv);
    *(ushort2v*)(aggb + (size_t)node * 128 + lane * 2) = o;
}

// ---------------------------------------------------------------------------
// Layer-1 for one relation: hb (+)= relu([agg|x](K=256) @ W + bl) / 3  (bf16 RMW)
__global__ __launch_bounds__(256, 4) void layer1_kernel(
    const unsigned short* __restrict__ aggb, const unsigned short* __restrict__ xb,
    const unsigned short* __restrict__ Wfrag, const float* __restrict__ bl,
    unsigned short* __restrict__ hb, int first) {
    __shared__ unsigned short s_a[64 * LDS_STRIDE];
    __shared__ unsigned short s_x[64 * LDS_STRIDE];
    int tid = threadIdx.x, wave = tid >> 6, lane = tid & 63;
    int quad = lane >> 4, l16 = lane & 15;
    int rowbase = blockIdx.x * 64;

#pragma unroll
    for (int it = 0; it < 4; it++) {
        int idx = tid + it * 256;
        int row = idx >> 4, c = idx & 15;
        int grow = rowbase + row;
        short8 xv = {0, 0, 0, 0, 0, 0, 0, 0};
        if (grow < N_NODES) xv = *(const short8*)(xb + (size_t)grow * 128 + c * 8);
        *(short8*)&s_x[row * LDS_STRIDE + c * 8] = xv;
        short8 av = *(const short8*)(aggb + (size_t)(rowbase + row) * 128 + c * 8);
        *(short8*)&s_a[row * LDS_STRIDE + c * 8] = av;
    }
    __syncthreads();

    f32x4 acc[4][2];
#pragma unroll
    for (int g = 0; g < 4; g++) { acc[g][0] = (f32x4){0.f,0.f,0.f,0.f}; acc[g][1] = (f32x4){0.f,0.f,0.f,0.f}; }

    const unsigned short* W = Wfrag + wave * 8192;
#pragma unroll
    for (int s = 0; s < 8; s++) {
        short8 bf0 = *(const short8*)(W + s * 1024 + lane * 8);         // coalesced 1KB
        short8 bf1 = *(const short8*)(W + s * 1024 + 512 + lane * 8);
        const unsigned short* src = (s < 4) ? s_a : s_x;
        int ko = (s & 3) * 32 + quad * 8;
#pragma unroll
        for (int g = 0; g < 4; g++) {
            short8 af = *(const short8*)&src[(g * 16 + l16) * LDS_STRIDE + ko];
            acc[g][0] = __builtin_amdgcn_mfma_f32_16x16x32_bf16(af, bf0, acc[g][0], 0, 0, 0);
            acc[g][1] = __builtin_amdgcn_mfma_f32_16x16x32_bf16(af, bf1, acc[g][1], 0, 0, 0);
        }
    }

    float b0 = bl[wave * 32 + l16];
    float b1 = bl[wave * 32 + 16 + l16];
#pragma unroll
    for (int g = 0; g < 4; g++)
#pragma unroll
        for (int t = 0; t < 2; t++) {
            float bb = t ? b1 : b0;
            int col = wave * 32 + t * 16 + l16;
#pragma unroll
            for (int q = 0; q < 4; q++) {
                int row = rowbase + g * 16 + quad * 4 + q;
                if (row < N_NODES) {
                    float v = fmaxf(acc[g][t][q] + bb, 0.f) * (1.0f / 3.0f);
                    size_t o = (size_t)row * 128 + col;
                    if (!first) v += b2f(hb[o]);
                    hb[o] = f2b(v);
                }
            }
        }
}

// ---------------------------------------------------------------------------
// Layer-2: [hWl|hWr] = h @ Wf2 (K=128); hWl -> bf16 buffer, out = hWr + bl_f.
__global__ __launch_bounds__(256, 4) void layer2_kernel(
    const unsigned short* __restrict__ hb, const unsigned short* __restrict__ Wfrag2,
    const float* __restrict__ bl_f, unsigned short* __restrict__ hWlb,
    float* __restrict__ out) {
    __shared__ unsigned short s_h[64 * LDS_STRIDE];
    int tid = threadIdx.x, wave = tid >> 6, lane = tid & 63;
    int quad = lane >> 4, l16 = lane & 15;
    int rowbase = blockIdx.x * 64;

#pragma unroll
    for (int it = 0; it < 4; it++) {
        int idx = tid + it * 256;
        int row = idx >> 4, c = idx & 15;
        int grow = rowbase + row;
        short8 hv = {0, 0, 0, 0, 0, 0, 0, 0};
        if (grow < N_NODES) hv = *(const short8*)(hb + (size_t)grow * 128 + c * 8);
        *(short8*)&s_h[row * LDS_STRIDE + c * 8] = hv;
    }
    __syncthreads();

    f32x4 acc[4][2];
#pragma unroll
    for (int g = 0; g < 4; g++) { acc[g][0] = (f32x4){0.f,0.f,0.f,0.f}; acc[g][1] = (f32x4){0.f,0.f,0.f,0.f}; }

    const unsigned short* W = Wfrag2 + wave * 4096;
#pragma unroll
    for (int s = 0; s < 4; s++) {
        short8 bf0 = *(const short8*)(W + s * 1024 + lane * 8);
        short8 bf1 = *(const short8*)(W + s * 1024 + 512 + lane * 8);
        int ko = s * 32 + quad * 8;
#pragma unroll
        for (int g = 0; g < 4; g++) {
            short8 af = *(const short8*)&s_h[(g * 16 + l16) * LDS_STRIDE + ko];
            acc[g][0] = __builtin_amdgcn_mfma_f32_16x16x32_bf16(af, bf0, acc[g][0], 0, 0, 0);
            acc[g][1] = __builtin_amdgcn_mfma_f32_16x16x32_bf16(af, bf1, acc[g][1], 0, 0, 0);
        }
    }

#pragma unroll
    for (int g = 0; g < 4; g++)
#pragma unroll
        for (int t = 0; t < 2; t++) {
            int col = wave * 32 + t * 16 + l16;
#pragma unroll
            for (int q = 0; q < 4; q++) {
                int row = rowbase + g * 16 + quad * 4 + q;
                if (row < N_NODES) {
                    if (col < 64) hWlb[(size_t)row * 64 + col] = f2b(acc[g][t][q]);
                    else out[(size_t)row * 64 + (col - 64)] = acc[g][t][q] + bl_f[col - 64];
                }
            }
        }
}

// ---------------------------------------------------------------------------
// Gather-mean of hWl (bf16, 64 ch) + add into out (holds hWr + bl_f).
__global__ void gather64_kernel(const unsigned short* __restrict__ hWlb, const int* __restrict__ adj,
                                const int* __restrict__ rowstart, const int* __restrict__ cnt,
                                float* __restrict__ out) {
    int node = (blockIdx.x * blockDim.x + threadIdx.x) >> 6;
    int lane = threadIdx.x & 63;
    if (node >= N_NODES) return;
    int start = rowstart[node];
    int deg = cnt[node];
    float a = 0.f;
    int j = 0;
    for (; j + 4 <= deg; j += 4) {
        int s0 = adj[start + j], s1 = adj[start + j + 1];
        int s2 = adj[start + j + 2], s3 = adj[start + j + 3];
        a += b2f(hWlb[(size_t)s0 * 64 + lane]) + b2f(hWlb[(size_t)s1 * 64 + lane])
           + b2f(hWlb[(size_t)s2 * 64 + lane]) + b2f(hWlb[(size_t)s3 * 64 + lane]);
    }
    for (; j < deg; j++) a += b2f(hWlb[(size_t)adj[start + j] * 64 + lane]);
    out[(size_t)node * 64 + lane] += a / fmaxf((float)deg, 1.0f);
}

// ---------------------------------------------------------------------------
extern "C" void kernel_launch(void* const* d_in, const int* in_sizes, int n_in,
                              void* d_out, int out_size, void* d_ws, size_t ws_size,
                              hipStream_t stream) {
    const float* x    = (const float*)d_in[0];
    const float* Wl   = (const float*)d_in[1];
    const float* bl   = (const float*)d_in[2];
    const float* Wr   = (const float*)d_in[3];
    const float* Wl_f = (const float*)d_in[4];
    const float* bl_f = (const float*)d_in[5];
    const float* Wr_f = (const float*)d_in[6];
    const int* ei0 = (const int*)d_in[7];
    const int* ei1 = (const int*)d_in[8];
    const int* ei2 = (const int*)d_in[9];
    float* out = (float*)d_out;

    // workspace layout (offsets), total ~107 MB
    char* ws = (char*)d_ws;
    int* cnt               = (int*)(ws);                                   // 1.2 MB
    int* bincur            = (int*)(ws + 0x128000);                        // 96 B (zeroed w/ cnt)
    int* cursor            = (int*)(ws + ((size_t)2  << 20));              // 1.2 MB
    int* rowstart          = (int*)(ws + ((size_t)4  << 20));              // 1.2 MB
    int* blocksum          = (int*)(ws + ((size_t)6  << 20));              // 1.2 KB
    unsigned short* Wfrag  = (unsigned short*)(ws + ((size_t)7  << 20));   // 192 KB
    unsigned short* Wfrag2 = (unsigned short*)(ws + ((size_t)15 << 19));   // 7.5MB, 32 KB
    int* adj               = (int*)(ws + ((size_t)8  << 20));              // 7.2 MB
    unsigned short* xb     = (unsigned short*)(ws + ((size_t)16 << 20));   // 25.6 MB
    unsigned short* aggb   = (unsigned short*)(ws + ((size_t)42 << 20));   // 25.6 MB
    unsigned short* hb     = (unsigned short*)(ws + ((size_t)68 << 20));   // 25.6 MB
    unsigned short* hWlb   = (unsigned short*)(ws + ((size_t)94 << 20));   // 12.8 MB
    // bins alias aggb: dead before gather128 writes aggb (stream-ordered)
    unsigned* bins         = (unsigned*)(ws + ((size_t)42 << 20));         // 7.68 MB

    hipMemsetAsync(ws, 0, 0x129000, stream);   // cnt + bincur

    bin_kernel<<<dim3(ACH, 3), 256, 0, stream>>>(ei0, ei1, ei2, bins, bincur);
    dim3 gpart(NPART, BIN_CAP / 2048, 3);      // x = dst partition -> XCD
    count_kernel<<<gpart, 256, 0, stream>>>(bins, bincur, cnt);
    scan1_kernel<<<dim3(NCHUNK, 3), 1024, 0, stream>>>(cnt, rowstart, blocksum);
    scan2_kernel<<<1, 128, 0, stream>>>(blocksum);
    scan3_kernel<<<dim3(392, 3), 256, 0, stream>>>(rowstart, blocksum, cursor);
    fill_kernel<<<gpart, 256, 0, stream>>>(bins, bincur, cursor, adj);
    wprep_kernel<<<448, 256, 0, stream>>>(Wl, Wr, Wl_f, Wr_f, Wfrag, Wfrag2);
    xcast_kernel<<<(N_NODES * 128 / 8) / 256, 256, 0, stream>>>(x, xb);

    const int GATHER_BLOCKS = (N_NODES + 3) / 4;   // one wave per node
    const int TILE_BLOCKS = (N_NODES + 63) / 64;   // 1563
    for (int r = 0; r < 3; r++) {
        gather128_kernel<<<GATHER_BLOCKS, 256, 0, stream>>>(
            xb, adj + (size_t)r * N_EDGES, rowstart + r * N_NODES, cnt + r * N_NODES, aggb);
        layer1_kernel<<<TILE_BLOCKS, 256, 0, stream>>>(
            aggb, xb, Wfrag + (size_t)r * 32768, bl + r * 128, hb, r == 0 ? 1 : 0);
    }

    layer2_kernel<<<TILE_BLOCKS, 256, 0, stream>>>(hb, Wfrag2, bl_f, hWlb, out);
    gather64_kernel<<<GATHER_BLOCKS, 256, 0, stream>>>(hWlb, adj, rowstart, cnt, out);
}

// Round 4
// 427.699 us; speedup vs baseline: 1.2998x; 1.2998x over previous
//
#include <hip/hip_runtime.h>

#define N_NODES 100000
#define N_EDGES 600000
#define NCHUNK 98            // ceil(100000/1024)
#define LDS_STRIDE 136       // ushorts per row: 128 + 8 pad
#define SUBP 128             // dst sub-partitions
#define SUB_SZ 782           // nodes per sub-partition (128*782 = 100096 >= 100000)
#define ECHUNK 2048          // edges per bin_kernel block
#define ACH 293              // ceil(600000/2048)
#define BCAP 6144            // per (rel,subpart) bin capacity (mean 4687, +21 sigma)

typedef __attribute__((ext_vector_type(8))) short short8;
typedef __attribute__((ext_vector_type(4))) float f32x4;
typedef __attribute__((ext_vector_type(2))) unsigned short ushort2v;
typedef __attribute__((ext_vector_type(8))) unsigned short ushort8v;

__device__ __forceinline__ unsigned short f2b(float f) {   // fp32 -> bf16 RNE
    unsigned u = __builtin_bit_cast(unsigned, f);
    return (unsigned short)((u + 0x7fffu + ((u >> 16) & 1u)) >> 16);
}
__device__ __forceinline__ float b2f(unsigned short b) {
    return __builtin_bit_cast(float, (unsigned)b << 16);
}

// ---------------------------------------------------------------------------
// Pass A: 128-way counting sort of edges by dst sub-partition. Edge packed
// into 4B: src (17b) | local-dst (10b, <782). LDS-staged compaction ->
// line-granular global writes into per-(rel,subpart) bins.
__global__ __launch_bounds__(256) void bin_kernel(const int* __restrict__ e0,
                                                  const int* __restrict__ e1,
                                                  const int* __restrict__ e2,
                                                  unsigned* __restrict__ bins,
                                                  int* __restrict__ bincur) {
    int r = blockIdx.y;
    const int* ei = (r == 0) ? e0 : (r == 1 ? e1 : e2);
    int base = blockIdx.x * ECHUNK;
    int nhere = min(ECHUNK, N_EDGES - base);
    __shared__ int lhist[SUBP], lstart[SUBP], lcur[SUBP], gbase[SUBP];
    __shared__ unsigned led[ECHUNK];
    __shared__ unsigned char lbkt[ECHUNK];
    int tid = threadIdx.x;
    for (int i = tid; i < SUBP; i += 256) { lhist[i] = 0; lcur[i] = 0; }
    __syncthreads();

    unsigned pk[8]; int bn[8];
#pragma unroll
    for (int k = 0; k < 8; k++) {
        int i = tid + k * 256;
        bn[k] = -1;
        if (i < nhere) {
            int e = base + i;
            int s = ei[e], d = ei[N_EDGES + e];
            int b = d / SUB_SZ;
            int ld = d - b * SUB_SZ;
            pk[k] = (unsigned)s | ((unsigned)ld << 17);
            bn[k] = b;
            atomicAdd(&lhist[b], 1);
        }
    }
    __syncthreads();
    if (tid == 0) {
        int run = 0;
        for (int b = 0; b < SUBP; b++) { lstart[b] = run; run += lhist[b]; }
    }
    __syncthreads();
#pragma unroll
    for (int k = 0; k < 8; k++) {
        if (bn[k] >= 0) {
            int slot = atomicAdd(&lcur[bn[k]], 1);
            int p = lstart[bn[k]] + slot;
            led[p] = pk[k];
            lbkt[p] = (unsigned char)bn[k];
        }
    }
    if (tid < SUBP) gbase[tid] = atomicAdd(&bincur[r * SUBP + tid], lhist[tid]);
    __syncthreads();
    for (int i = tid; i < nhere; i += 256) {
        int b = lbkt[i];
        int dstidx = gbase[b] + (i - lstart[b]);
        if (dstidx < BCAP)   // safety clamp: drop (never fault) on overflow
            bins[(size_t)(r * SUBP + b) * BCAP + dstidx] = led[i];
    }
}

// ---------------------------------------------------------------------------
// Degree count: one block per (rel,subpart). LDS histogram, coalesced cnt out.
__global__ __launch_bounds__(256) void count_kernel(const unsigned* __restrict__ bins,
                                                    const int* __restrict__ bincur,
                                                    int* __restrict__ cnt) {
    int p = blockIdx.x, r = blockIdx.y;
    int n0 = p * SUB_SZ;
    int nodes = min(SUB_SZ, N_NODES - n0);
    __shared__ int hist[SUB_SZ];
    int tid = threadIdx.x;
    for (int i = tid; i < SUB_SZ; i += 256) hist[i] = 0;
    __syncthreads();
    int len = min(bincur[r * SUBP + p], BCAP);
    const unsigned* b = bins + (size_t)(r * SUBP + p) * BCAP;
    for (int i = tid; i < len; i += 256) atomicAdd(&hist[b[i] >> 17], 1);
    __syncthreads();
    for (int i = tid; i < nodes; i += 256) cnt[r * N_NODES + n0 + i] = hist[i];
}

// ---------------------------------------------------------------------------
__global__ __launch_bounds__(1024) void scan1_kernel(const int* __restrict__ cnt,
                                                     int* __restrict__ rowstart,
                                                     int* __restrict__ blocksum) {
    int r = blockIdx.y;
    int tid = threadIdx.x, lane = tid & 63, wid = tid >> 6;
    int i = blockIdx.x * 1024 + tid;
    __shared__ int wsum[16];
    int v = (i < N_NODES) ? cnt[r * N_NODES + i] : 0;
    int incl = v;
#pragma unroll
    for (int off = 1; off < 64; off <<= 1) {
        int t = __shfl_up(incl, off);
        if (lane >= off) incl += t;
    }
    if (lane == 63) wsum[wid] = incl;
    __syncthreads();
    if (wid == 0) {
        int wv = (lane < 16) ? wsum[lane] : 0;
#pragma unroll
        for (int off = 1; off < 16; off <<= 1) {
            int t = __shfl_up(wv, off);
            if (lane >= off) wv += t;
        }
        if (lane < 16) wsum[lane] = wv;
    }
    __syncthreads();
    int woff = (wid > 0) ? wsum[wid - 1] : 0;
    if (i < N_NODES) rowstart[r * N_NODES + i] = woff + incl - v;
    if (tid == 0) blocksum[r * NCHUNK + blockIdx.x] = wsum[15];
}

__global__ __launch_bounds__(128) void scan2_kernel(int* __restrict__ blocksum) {
    __shared__ int s[3 * NCHUNK];
    int tid = threadIdx.x;
    for (int i = tid; i < 3 * NCHUNK; i += 128) s[i] = blocksum[i];
    __syncthreads();
    if (tid < 3) {
        int run = 0;
        for (int j = 0; j < NCHUNK; j++) { int t = s[tid * NCHUNK + j]; s[tid * NCHUNK + j] = run; run += t; }
    }
    __syncthreads();
    for (int i = tid; i < 3 * NCHUNK; i += 128) blocksum[i] = s[i];
}

__global__ void scan3_kernel(int* __restrict__ rowstart, const int* __restrict__ blocksum) {
    int r = blockIdx.y;
    int i = blockIdx.x * 256 + threadIdx.x;
    if (i < N_NODES)
        rowstart[r * N_NODES + i] += blocksum[r * NCHUNK + (i >> 10)];
}

// ---------------------------------------------------------------------------
// CSR fill: one block per (rel,subpart). Local cursor + adj slice staged in
// LDS (LDS atomics only), then streamed out with coalesced sequential stores.
// No global atomics, no scattered global stores.
__global__ __launch_bounds__(256) void fill_kernel(const unsigned* __restrict__ bins,
                                                   const int* __restrict__ bincur,
                                                   const int* __restrict__ rowstart,
                                                   int* __restrict__ adj) {
    int p = blockIdx.x, r = blockIdx.y;
    int n0 = p * SUB_SZ;
    int nodes = min(SUB_SZ, N_NODES - n0);
    __shared__ int lcur[SUB_SZ];
    __shared__ int sstage[BCAP];
    int tid = threadIdx.x;
    const int* rs = rowstart + r * N_NODES + n0;
    int rbase = rs[0];
    for (int i = tid; i < nodes; i += 256) lcur[i] = rs[i] - rbase;
    __syncthreads();
    int len = min(bincur[r * SUBP + p], BCAP);
    const unsigned* b = bins + (size_t)(r * SUBP + p) * BCAP;
    for (int i = tid; i < len; i += 256) {
        unsigned v = b[i];
        int pos = atomicAdd(&lcur[v >> 17], 1);
        if (pos < BCAP)   // safety clamp (cannot trigger with consistent counts)
            sstage[pos] = (int)(v & 0x1FFFFu);
    }
    __syncthreads();
    int* a = adj + (size_t)r * N_EDGES + rbase;
    for (int i = tid; i < len; i += 256) a[i] = sstage[i];
}

// ---------------------------------------------------------------------------
// x (fp32) -> xb (bf16), 8 elems/thread.
__global__ void xcast_kernel(const float* __restrict__ x, unsigned short* __restrict__ xb) {
    int idx = blockIdx.x * 256 + threadIdx.x;
    const float4* p = (const float4*)x + (size_t)idx * 2;
    float4 a = p[0], b = p[1];
    ushort8v o;
    o[0] = f2b(a.x); o[1] = f2b(a.y); o[2] = f2b(a.z); o[3] = f2b(a.w);
    o[4] = f2b(b.x); o[5] = f2b(b.y); o[6] = f2b(b.z); o[7] = f2b(b.w);
    *(ushort8v*)(xb + (size_t)idx * 8) = o;
}

// ---------------------------------------------------------------------------
// Pre-swizzle weights into MFMA B-fragment order.
__global__ void wprep_kernel(const float* __restrict__ Wl, const float* __restrict__ Wr,
                             const float* __restrict__ Wl_f, const float* __restrict__ Wr_f,
                             unsigned short* __restrict__ Wfrag, unsigned short* __restrict__ Wfrag2) {
    int idx = blockIdx.x * 256 + threadIdx.x;      // 448 blocks = 114688 threads
    int j = idx & 7, lane = (idx >> 3) & 63;
    int quad = lane >> 4, l16 = lane & 15;
    if (idx < 98304) {
        int t = (idx >> 9) & 1, s = (idx >> 10) & 7, w = (idx >> 13) & 3, r = idx >> 15;
        int k = s * 32 + quad * 8 + j;
        int n = w * 32 + t * 16 + l16;
        float v = (k < 128) ? Wl[((size_t)r * 128 + k) * 128 + n]
                            : Wr[((size_t)r * 128 + (k - 128)) * 128 + n];
        Wfrag[idx] = f2b(v);
    } else {
        int i2 = idx - 98304;
        if (i2 < 16384) {
            int t = (i2 >> 9) & 1, s = (i2 >> 10) & 3, w = (i2 >> 12) & 3;
            int k = s * 32 + quad * 8 + j;
            int n = w * 32 + t * 16 + l16;
            float v = (n < 64) ? Wl_f[(size_t)k * 64 + n] : Wr_f[(size_t)k * 64 + (n - 64)];
            Wfrag2[i2] = f2b(v);
        }
    }
}

// ---------------------------------------------------------------------------
// Gather-mean from bf16 rows (256 B/row): one wave/node, ushort2 per lane.
__global__ void gather128_kernel(const unsigned short* __restrict__ xb, const int* __restrict__ adj,
                                 const int* __restrict__ rowstart, const int* __restrict__ cnt,
                                 unsigned short* __restrict__ aggb) {
    int node = (blockIdx.x * blockDim.x + threadIdx.x) >> 6;
    int lane = threadIdx.x & 63;
    if (node >= N_NODES) return;
    int start = rowstart[node];
    int deg = cnt[node];
    float ax = 0.f, ay = 0.f;
    int j = 0;
    for (; j + 4 <= deg; j += 4) {
        int s0 = adj[start + j], s1 = adj[start + j + 1];
        int s2 = adj[start + j + 2], s3 = adj[start + j + 3];
        ushort2v v0 = *(const ushort2v*)(xb + (size_t)s0 * 128 + lane * 2);
        ushort2v v1 = *(const ushort2v*)(xb + (size_t)s1 * 128 + lane * 2);
        ushort2v v2 = *(const ushort2v*)(xb + (size_t)s2 * 128 + lane * 2);
        ushort2v v3 = *(const ushort2v*)(xb + (size_t)s3 * 128 + lane * 2);
        ax += b2f(v0.x) + b2f(v1.x) + b2f(v2.x) + b2f(v3.x);
        ay += b2f(v0.y) + b2f(v1.y) + b2f(v2.y) + b2f(v3.y);
    }
    for (; j < deg; j++) {
        int s = adj[start + j];
        ushort2v v = *(const ushort2v*)(xb + (size_t)s * 128 + lane * 2);
        ax += b2f(v.x); ay += b2f(v.y);
    }
    float inv = 1.0f / fmaxf((float)deg, 1.0f);
    ushort2v o; o.x = f2b(ax * inv); o.y = f2b(ay * inv);
    *(ushort2v*)(aggb + (size_t)node * 128 + lane * 2) = o;
}

// ---------------------------------------------------------------------------
// Layer-1 for one relation: hb (+)= relu([agg|x](K=256) @ W + bl) / 3  (bf16 RMW)
__global__ __launch_bounds__(256, 4) void layer1_kernel(
    const unsigned short* __restrict__ aggb, const unsigned short* __restrict__ xb,
    const unsigned short* __restrict__ Wfrag, const float* __restrict__ bl,
    unsigned short* __restrict__ hb, int first) {
    __shared__ unsigned short s_a[64 * LDS_STRIDE];
    __shared__ unsigned short s_x[64 * LDS_STRIDE];
    int tid = threadIdx.x, wave = tid >> 6, lane = tid & 63;
    int quad = lane >> 4, l16 = lane & 15;
    int rowbase = blockIdx.x * 64;

#pragma unroll
    for (int it = 0; it < 4; it++) {
        int idx = tid + it * 256;
        int row = idx >> 4, c = idx & 15;
        int grow = rowbase + row;
        short8 xv = {0, 0, 0, 0, 0, 0, 0, 0};
        if (grow < N_NODES) xv = *(const short8*)(xb + (size_t)grow * 128 + c * 8);
        *(short8*)&s_x[row * LDS_STRIDE + c * 8] = xv;
        short8 av = *(const short8*)(aggb + (size_t)(rowbase + row) * 128 + c * 8);
        *(short8*)&s_a[row * LDS_STRIDE + c * 8] = av;
    }
    __syncthreads();

    f32x4 acc[4][2];
#pragma unroll
    for (int g = 0; g < 4; g++) { acc[g][0] = (f32x4){0.f,0.f,0.f,0.f}; acc[g][1] = (f32x4){0.f,0.f,0.f,0.f}; }

    const unsigned short* W = Wfrag + wave * 8192;
#pragma unroll
    for (int s = 0; s < 8; s++) {
        short8 bf0 = *(const short8*)(W + s * 1024 + lane * 8);         // coalesced 1KB
        short8 bf1 = *(const short8*)(W + s * 1024 + 512 + lane * 8);
        const unsigned short* src = (s < 4) ? s_a : s_x;
        int ko = (s & 3) * 32 + quad * 8;
#pragma unroll
        for (int g = 0; g < 4; g++) {
            short8 af = *(const short8*)&src[(g * 16 + l16) * LDS_STRIDE + ko];
            acc[g][0] = __builtin_amdgcn_mfma_f32_16x16x32_bf16(af, bf0, acc[g][0], 0, 0, 0);
            acc[g][1] = __builtin_amdgcn_mfma_f32_16x16x32_bf16(af, bf1, acc[g][1], 0, 0, 0);
        }
    }

    float b0 = bl[wave * 32 + l16];
    float b1 = bl[wave * 32 + 16 + l16];
#pragma unroll
    for (int g = 0; g < 4; g++)
#pragma unroll
        for (int t = 0; t < 2; t++) {
            float bb = t ? b1 : b0;
            int col = wave * 32 + t * 16 + l16;
#pragma unroll
            for (int q = 0; q < 4; q++) {
                int row = rowbase + g * 16 + quad * 4 + q;
                if (row < N_NODES) {
                    float v = fmaxf(acc[g][t][q] + bb, 0.f) * (1.0f / 3.0f);
                    size_t o = (size_t)row * 128 + col;
                    if (!first) v += b2f(hb[o]);
                    hb[o] = f2b(v);
                }
            }
        }
}

// ---------------------------------------------------------------------------
// Layer-2: [hWl|hWr] = h @ Wf2 (K=128); hWl -> bf16 buffer, out = hWr + bl_f.
__global__ __launch_bounds__(256, 4) void layer2_kernel(
    const unsigned short* __restrict__ hb, const unsigned short* __restrict__ Wfrag2,
    const float* __restrict__ bl_f, unsigned short* __restrict__ hWlb,
    float* __restrict__ out) {
    __shared__ unsigned short s_h[64 * LDS_STRIDE];
    int tid = threadIdx.x, wave = tid >> 6, lane = tid & 63;
    int quad = lane >> 4, l16 = lane & 15;
    int rowbase = blockIdx.x * 64;

#pragma unroll
    for (int it = 0; it < 4; it++) {
        int idx = tid + it * 256;
        int row = idx >> 4, c = idx & 15;
        int grow = rowbase + row;
        short8 hv = {0, 0, 0, 0, 0, 0, 0, 0};
        if (grow < N_NODES) hv = *(const short8*)(hb + (size_t)grow * 128 + c * 8);
        *(short8*)&s_h[row * LDS_STRIDE + c * 8] = hv;
    }
    __syncthreads();

    f32x4 acc[4][2];
#pragma unroll
    for (int g = 0; g < 4; g++) { acc[g][0] = (f32x4){0.f,0.f,0.f,0.f}; acc[g][1] = (f32x4){0.f,0.f,0.f,0.f}; }

    const unsigned short* W = Wfrag2 + wave * 4096;
#pragma unroll
    for (int s = 0; s < 4; s++) {
        short8 bf0 = *(const short8*)(W + s * 1024 + lane * 8);
        short8 bf1 = *(const short8*)(W + s * 1024 + 512 + lane * 8);
        int ko = s * 32 + quad * 8;
#pragma unroll
        for (int g = 0; g < 4; g++) {
            short8 af = *(const short8*)&s_h[(g * 16 + l16) * LDS_STRIDE + ko];
            acc[g][0] = __builtin_amdgcn_mfma_f32_16x16x32_bf16(af, bf0, acc[g][0], 0, 0, 0);
            acc[g][1] = __builtin_amdgcn_mfma_f32_16x16x32_bf16(af, bf1, acc[g][1], 0, 0, 0);
        }
    }

#pragma unroll
    for (int g = 0; g < 4; g++)
#pragma unroll
        for (int t = 0; t < 2; t++) {
            int col = wave * 32 + t * 16 + l16;
#pragma unroll
            for (int q = 0; q < 4; q++) {
                int row = rowbase + g * 16 + quad * 4 + q;
                if (row < N_NODES) {
                    if (col < 64) hWlb[(size_t)row * 64 + col] = f2b(acc[g][t][q]);
                    else out[(size_t)row * 64 + (col - 64)] = acc[g][t][q] + bl_f[col - 64];
                }
            }
        }
}

// ---------------------------------------------------------------------------
// Gather-mean of hWl (bf16, 64 ch) + add into out (holds hWr + bl_f).
__global__ void gather64_kernel(const unsigned short* __restrict__ hWlb, const int* __restrict__ adj,
                                const int* __restrict__ rowstart, const int* __restrict__ cnt,
                                float* __restrict__ out) {
    int node = (blockIdx.x * blockDim.x + threadIdx.x) >> 6;
    int lane = threadIdx.x & 63;
    if (node >= N_NODES) return;
    int start = rowstart[node];
    int deg = cnt[node];
    float a = 0.f;
    int j = 0;
    for (; j + 4 <= deg; j += 4) {
        int s0 = adj[start + j], s1 = adj[start + j + 1];
        int s2 = adj[start + j + 2], s3 = adj[start + j + 3];
        a += b2f(hWlb[(size_t)s0 * 64 + lane]) + b2f(hWlb[(size_t)s1 * 64 + lane])
           + b2f(hWlb[(size_t)s2 * 64 + lane]) + b2f(hWlb[(size_t)s3 * 64 + lane]);
    }
    for (; j < deg; j++) a += b2f(hWlb[(size_t)adj[start + j] * 64 + lane]);
    out[(size_t)node * 64 + lane] += a / fmaxf((float)deg, 1.0f);
}

// ---------------------------------------------------------------------------
extern "C" void kernel_launch(void* const* d_in, const int* in_sizes, int n_in,
                              void* d_out, int out_size, void* d_ws, size_t ws_size,
                              hipStream_t stream) {
    const float* x    = (const float*)d_in[0];
    const float* Wl   = (const float*)d_in[1];
    const float* bl   = (const float*)d_in[2];
    const float* Wr   = (const float*)d_in[3];
    const float* Wl_f = (const float*)d_in[4];
    const float* bl_f = (const float*)d_in[5];
    const float* Wr_f = (const float*)d_in[6];
    const int* ei0 = (const int*)d_in[7];
    const int* ei1 = (const int*)d_in[8];
    const int* ei2 = (const int*)d_in[9];
    float* out = (float*)d_out;

    // workspace layout (offsets), total ~107 MB
    char* ws = (char*)d_ws;
    int* cnt               = (int*)(ws);                                   // 1.2 MB
    int* bincur            = (int*)(ws + 0x128000);                        // 1.5 KB
    int* rowstart          = (int*)(ws + ((size_t)4  << 20));              // 1.2 MB
    int* blocksum          = (int*)(ws + ((size_t)6  << 20));              // 1.2 KB
    unsigned short* Wfrag  = (unsigned short*)(ws + ((size_t)7  << 20));   // 192 KB
    unsigned short* Wfrag2 = (unsigned short*)(ws + ((size_t)15 << 19));   // 7.5MB, 32 KB
    int* adj               = (int*)(ws + ((size_t)8  << 20));              // 7.2 MB
    unsigned short* xb     = (unsigned short*)(ws + ((size_t)16 << 20));   // 25.6 MB
    unsigned short* aggb   = (unsigned short*)(ws + ((size_t)42 << 20));   // 25.6 MB
    unsigned short* hb     = (unsigned short*)(ws + ((size_t)68 << 20));   // 25.6 MB
    unsigned short* hWlb   = (unsigned short*)(ws + ((size_t)94 << 20));   // 12.8 MB
    // bins alias aggb: dead before gather128 writes aggb (stream-ordered)
    unsigned* bins         = (unsigned*)(ws + ((size_t)42 << 20));         // 9.4 MB

    hipMemsetAsync(bincur, 0, 3 * SUBP * sizeof(int), stream);

    bin_kernel<<<dim3(ACH, 3), 256, 0, stream>>>(ei0, ei1, ei2, bins, bincur);
    count_kernel<<<dim3(SUBP, 3), 256, 0, stream>>>(bins, bincur, cnt);
    scan1_kernel<<<dim3(NCHUNK, 3), 1024, 0, stream>>>(cnt, rowstart, blocksum);
    scan2_kernel<<<1, 128, 0, stream>>>(blocksum);
    scan3_kernel<<<dim3(392, 3), 256, 0, stream>>>(rowstart, blocksum);
    fill_kernel<<<dim3(SUBP, 3), 256, 0, stream>>>(bins, bincur, rowstart, adj);
    wprep_kernel<<<448, 256, 0, stream>>>(Wl, Wr, Wl_f, Wr_f, Wfrag, Wfrag2);
    xcast_kernel<<<(N_NODES * 128 / 8) / 256, 256, 0, stream>>>(x, xb);

    const int GATHER_BLOCKS = (N_NODES + 3) / 4;   // one wave per node
    const int TILE_BLOCKS = (N_NODES + 63) / 64;   // 1563
    for (int r = 0; r < 3; r++) {
        gather128_kernel<<<GATHER_BLOCKS, 256, 0, stream>>>(
            xb, adj + (size_t)r * N_EDGES, rowstart + r * N_NODES, cnt + r * N_NODES, aggb);
        layer1_kernel<<<TILE_BLOCKS, 256, 0, stream>>>(
            aggb, xb, Wfrag + (size_t)r * 32768, bl + r * 128, hb, r == 0 ? 1 : 0);
    }

    layer2_kernel<<<TILE_BLOCKS, 256, 0, stream>>>(hb, Wfrag2, bl_f, hWlb, out);
    gather64_kernel<<<GATHER_BLOCKS, 256, 0, stream>>>(hWlb, adj, rowstart, cnt, out);
}

// Round 5
// 426.638 us; speedup vs baseline: 1.3031x; 1.0025x over previous
//
#include <hip/hip_runtime.h>

#define N_NODES 100000
#define N_EDGES 600000
#define NCHUNK 98            // ceil(100000/1024)
#define LDS_STRIDE 136       // ushorts per row: 128 + 8 pad
#define SUBP 128             // dst sub-partitions
#define SUB_SZ 782           // nodes per sub-partition (128*782 = 100096 >= 100000)
#define ECHUNK 2048          // edges per bin_kernel block
#define ACH 293              // ceil(600000/2048)
#define BCAP 6144            // per (rel,subpart) bin capacity (mean 4687, +21 sigma)

typedef __attribute__((ext_vector_type(8))) short short8;
typedef __attribute__((ext_vector_type(4))) float f32x4;
typedef __attribute__((ext_vector_type(2))) unsigned short ushort2v;
typedef __attribute__((ext_vector_type(4))) unsigned short ushort4v;
typedef __attribute__((ext_vector_type(8))) unsigned short ushort8v;

__device__ __forceinline__ unsigned short f2b(float f) {   // fp32 -> bf16 RNE
    unsigned u = __builtin_bit_cast(unsigned, f);
    return (unsigned short)((u + 0x7fffu + ((u >> 16) & 1u)) >> 16);
}
__device__ __forceinline__ float b2f(unsigned short b) {
    return __builtin_bit_cast(float, (unsigned)b << 16);
}

// ---------------------------------------------------------------------------
// Pass A: 128-way counting sort of edges by dst sub-partition. Edge packed
// into 4B: src (17b) | local-dst (10b, <782). LDS-staged compaction ->
// line-granular global writes into per-(rel,subpart) bins.
__global__ __launch_bounds__(256) void bin_kernel(const int* __restrict__ e0,
                                                  const int* __restrict__ e1,
                                                  const int* __restrict__ e2,
                                                  unsigned* __restrict__ bins,
                                                  int* __restrict__ bincur) {
    int r = blockIdx.y;
    const int* ei = (r == 0) ? e0 : (r == 1 ? e1 : e2);
    int base = blockIdx.x * ECHUNK;
    int nhere = min(ECHUNK, N_EDGES - base);
    __shared__ int lhist[SUBP], lstart[SUBP], lcur[SUBP], gbase[SUBP];
    __shared__ unsigned led[ECHUNK];
    __shared__ unsigned char lbkt[ECHUNK];
    int tid = threadIdx.x;
    for (int i = tid; i < SUBP; i += 256) { lhist[i] = 0; lcur[i] = 0; }
    __syncthreads();

    unsigned pk[8]; int bn[8];
#pragma unroll
    for (int k = 0; k < 8; k++) {
        int i = tid + k * 256;
        bn[k] = -1;
        if (i < nhere) {
            int e = base + i;
            int s = ei[e], d = ei[N_EDGES + e];
            int b = d / SUB_SZ;
            int ld = d - b * SUB_SZ;
            pk[k] = (unsigned)s | ((unsigned)ld << 17);
            bn[k] = b;
            atomicAdd(&lhist[b], 1);
        }
    }
    __syncthreads();
    if (tid == 0) {
        int run = 0;
        for (int b = 0; b < SUBP; b++) { lstart[b] = run; run += lhist[b]; }
    }
    __syncthreads();
#pragma unroll
    for (int k = 0; k < 8; k++) {
        if (bn[k] >= 0) {
            int slot = atomicAdd(&lcur[bn[k]], 1);
            int p = lstart[bn[k]] + slot;
            led[p] = pk[k];
            lbkt[p] = (unsigned char)bn[k];
        }
    }
    if (tid < SUBP) gbase[tid] = atomicAdd(&bincur[r * SUBP + tid], lhist[tid]);
    __syncthreads();
    for (int i = tid; i < nhere; i += 256) {
        int b = lbkt[i];
        int dstidx = gbase[b] + (i - lstart[b]);
        if (dstidx < BCAP)   // safety clamp: drop (never fault) on overflow
            bins[(size_t)(r * SUBP + b) * BCAP + dstidx] = led[i];
    }
}

// ---------------------------------------------------------------------------
// Degree count: one block per (rel,subpart). LDS histogram, coalesced cnt out.
__global__ __launch_bounds__(256) void count_kernel(const unsigned* __restrict__ bins,
                                                    const int* __restrict__ bincur,
                                                    int* __restrict__ cnt) {
    int p = blockIdx.x, r = blockIdx.y;
    int n0 = p * SUB_SZ;
    int nodes = min(SUB_SZ, N_NODES - n0);
    __shared__ int hist[SUB_SZ];
    int tid = threadIdx.x;
    for (int i = tid; i < SUB_SZ; i += 256) hist[i] = 0;
    __syncthreads();
    int len = min(bincur[r * SUBP + p], BCAP);
    const unsigned* b = bins + (size_t)(r * SUBP + p) * BCAP;
    for (int i = tid; i < len; i += 256) atomicAdd(&hist[b[i] >> 17], 1);
    __syncthreads();
    for (int i = tid; i < nodes; i += 256) cnt[r * N_NODES + n0 + i] = hist[i];
}

// ---------------------------------------------------------------------------
__global__ __launch_bounds__(1024) void scan1_kernel(const int* __restrict__ cnt,
                                                     int* __restrict__ rowstart,
                                                     int* __restrict__ blocksum) {
    int r = blockIdx.y;
    int tid = threadIdx.x, lane = tid & 63, wid = tid >> 6;
    int i = blockIdx.x * 1024 + tid;
    __shared__ int wsum[16];
    int v = (i < N_NODES) ? cnt[r * N_NODES + i] : 0;
    int incl = v;
#pragma unroll
    for (int off = 1; off < 64; off <<= 1) {
        int t = __shfl_up(incl, off);
        if (lane >= off) incl += t;
    }
    if (lane == 63) wsum[wid] = incl;
    __syncthreads();
    if (wid == 0) {
        int wv = (lane < 16) ? wsum[lane] : 0;
#pragma unroll
        for (int off = 1; off < 16; off <<= 1) {
            int t = __shfl_up(wv, off);
            if (lane >= off) wv += t;
        }
        if (lane < 16) wsum[lane] = wv;
    }
    __syncthreads();
    int woff = (wid > 0) ? wsum[wid - 1] : 0;
    if (i < N_NODES) rowstart[r * N_NODES + i] = woff + incl - v;
    if (tid == 0) blocksum[r * NCHUNK + blockIdx.x] = wsum[15];
}

__global__ __launch_bounds__(128) void scan2_kernel(int* __restrict__ blocksum) {
    __shared__ int s[3 * NCHUNK];
    int tid = threadIdx.x;
    for (int i = tid; i < 3 * NCHUNK; i += 128) s[i] = blocksum[i];
    __syncthreads();
    if (tid < 3) {
        int run = 0;
        for (int j = 0; j < NCHUNK; j++) { int t = s[tid * NCHUNK + j]; s[tid * NCHUNK + j] = run; run += t; }
    }
    __syncthreads();
    for (int i = tid; i < 3 * NCHUNK; i += 128) blocksum[i] = s[i];
}

__global__ void scan3_kernel(int* __restrict__ rowstart, const int* __restrict__ blocksum) {
    int r = blockIdx.y;
    int i = blockIdx.x * 256 + threadIdx.x;
    if (i < N_NODES)
        rowstart[r * N_NODES + i] += blocksum[r * NCHUNK + (i >> 10)];
}

// ---------------------------------------------------------------------------
// CSR fill: one block per (rel,subpart). Local cursor + adj slice staged in
// LDS (LDS atomics only), then streamed out with coalesced sequential stores.
__global__ __launch_bounds__(256) void fill_kernel(const unsigned* __restrict__ bins,
                                                   const int* __restrict__ bincur,
                                                   const int* __restrict__ rowstart,
                                                   int* __restrict__ adj) {
    int p = blockIdx.x, r = blockIdx.y;
    int n0 = p * SUB_SZ;
    int nodes = min(SUB_SZ, N_NODES - n0);
    __shared__ int lcur[SUB_SZ];
    __shared__ int sstage[BCAP];
    int tid = threadIdx.x;
    const int* rs = rowstart + r * N_NODES + n0;
    int rbase = rs[0];
    for (int i = tid; i < nodes; i += 256) lcur[i] = rs[i] - rbase;
    __syncthreads();
    int len = min(bincur[r * SUBP + p], BCAP);
    const unsigned* b = bins + (size_t)(r * SUBP + p) * BCAP;
    for (int i = tid; i < len; i += 256) {
        unsigned v = b[i];
        int pos = atomicAdd(&lcur[v >> 17], 1);
        if (pos < BCAP)   // safety clamp (cannot trigger with consistent counts)
            sstage[pos] = (int)(v & 0x1FFFFu);
    }
    __syncthreads();
    int* a = adj + (size_t)r * N_EDGES + rbase;
    for (int i = tid; i < len; i += 256) a[i] = sstage[i];
}

// ---------------------------------------------------------------------------
// x (fp32) -> xb (bf16), 8 elems/thread.
__global__ void xcast_kernel(const float* __restrict__ x, unsigned short* __restrict__ xb) {
    int idx = blockIdx.x * 256 + threadIdx.x;
    const float4* p = (const float4*)x + (size_t)idx * 2;
    float4 a = p[0], b = p[1];
    ushort8v o;
    o[0] = f2b(a.x); o[1] = f2b(a.y); o[2] = f2b(a.z); o[3] = f2b(a.w);
    o[4] = f2b(b.x); o[5] = f2b(b.y); o[6] = f2b(b.z); o[7] = f2b(b.w);
    *(ushort8v*)(xb + (size_t)idx * 8) = o;
}

// ---------------------------------------------------------------------------
// Pre-swizzle weights into MFMA B-fragment order.
__global__ void wprep_kernel(const float* __restrict__ Wl, const float* __restrict__ Wr,
                             const float* __restrict__ Wl_f, const float* __restrict__ Wr_f,
                             unsigned short* __restrict__ Wfrag, unsigned short* __restrict__ Wfrag2) {
    int idx = blockIdx.x * 256 + threadIdx.x;      // 448 blocks = 114688 threads
    int j = idx & 7, lane = (idx >> 3) & 63;
    int quad = lane >> 4, l16 = lane & 15;
    if (idx < 98304) {
        int t = (idx >> 9) & 1, s = (idx >> 10) & 7, w = (idx >> 13) & 3, r = idx >> 15;
        int k = s * 32 + quad * 8 + j;
        int n = w * 32 + t * 16 + l16;
        float v = (k < 128) ? Wl[((size_t)r * 128 + k) * 128 + n]
                            : Wr[((size_t)r * 128 + (k - 128)) * 128 + n];
        Wfrag[idx] = f2b(v);
    } else {
        int i2 = idx - 98304;
        if (i2 < 16384) {
            int t = (i2 >> 9) & 1, s = (i2 >> 10) & 3, w = (i2 >> 12) & 3;
            int k = s * 32 + quad * 8 + j;
            int n = w * 32 + t * 16 + l16;
            float v = (n < 64) ? Wl_f[(size_t)k * 64 + n] : Wr_f[(size_t)k * 64 + (n - 64)];
            Wfrag2[i2] = f2b(v);
        }
    }
}

// ---------------------------------------------------------------------------
// Gather-mean from bf16 rows (256 B/row). One wave/node, split as 4 neighbor
// slots x 16 channel lanes: each lane loads ushort8 (16B) so one VMEM op
// covers 4 rows (1KB/wave); shfl_xor(16,32) folds the 4 neighbor partials.
__global__ void gather128_kernel(const unsigned short* __restrict__ xb, const int* __restrict__ adj,
                                 const int* __restrict__ rowstart, const int* __restrict__ cnt,
                                 unsigned short* __restrict__ aggb) {
    int node = (blockIdx.x * blockDim.x + threadIdx.x) >> 6;
    int lane = threadIdx.x & 63;
    if (node >= N_NODES) return;
    int nb = lane >> 4, c16 = lane & 15;
    int start = rowstart[node];
    int deg = cnt[node];
    float ac[8];
#pragma unroll
    for (int k = 0; k < 8; k++) ac[k] = 0.f;
    for (int j = 0; j < deg; j += 4) {
        int jn = j + nb;
        if (jn < deg) {
            int s = adj[start + jn];
            ushort8v v = *(const ushort8v*)(xb + (size_t)s * 128 + c16 * 8);
#pragma unroll
            for (int k = 0; k < 8; k++) ac[k] += b2f(v[k]);
        }
    }
#pragma unroll
    for (int k = 0; k < 8; k++) {
        ac[k] += __shfl_xor(ac[k], 16);
        ac[k] += __shfl_xor(ac[k], 32);
    }
    if (nb == 0) {
        float inv = 1.0f / fmaxf((float)deg, 1.0f);
        ushort8v o;
#pragma unroll
        for (int k = 0; k < 8; k++) o[k] = f2b(ac[k] * inv);
        *(ushort8v*)(aggb + (size_t)node * 128 + c16 * 8) = o;
    }
}

// ---------------------------------------------------------------------------
// Layer-1 for one relation: hb (+)= relu([agg|x](K=256) @ W + bl) / 3  (bf16 RMW)
__global__ __launch_bounds__(256, 4) void layer1_kernel(
    const unsigned short* __restrict__ aggb, const unsigned short* __restrict__ xb,
    const unsigned short* __restrict__ Wfrag, const float* __restrict__ bl,
    unsigned short* __restrict__ hb, int first) {
    __shared__ unsigned short s_a[64 * LDS_STRIDE];
    __shared__ unsigned short s_x[64 * LDS_STRIDE];
    int tid = threadIdx.x, wave = tid >> 6, lane = tid & 63;
    int quad = lane >> 4, l16 = lane & 15;
    int rowbase = blockIdx.x * 64;

#pragma unroll
    for (int it = 0; it < 4; it++) {
        int idx = tid + it * 256;
        int row = idx >> 4, c = idx & 15;
        int grow = rowbase + row;
        short8 xv = {0, 0, 0, 0, 0, 0, 0, 0};
        if (grow < N_NODES) xv = *(const short8*)(xb + (size_t)grow * 128 + c * 8);
        *(short8*)&s_x[row * LDS_STRIDE + c * 8] = xv;
        short8 av = *(const short8*)(aggb + (size_t)(rowbase + row) * 128 + c * 8);
        *(short8*)&s_a[row * LDS_STRIDE + c * 8] = av;
    }
    __syncthreads();

    f32x4 acc[4][2];
#pragma unroll
    for (int g = 0; g < 4; g++) { acc[g][0] = (f32x4){0.f,0.f,0.f,0.f}; acc[g][1] = (f32x4){0.f,0.f,0.f,0.f}; }

    const unsigned short* W = Wfrag + wave * 8192;
#pragma unroll
    for (int s = 0; s < 8; s++) {
        short8 bf0 = *(const short8*)(W + s * 1024 + lane * 8);         // coalesced 1KB
        short8 bf1 = *(const short8*)(W + s * 1024 + 512 + lane * 8);
        const unsigned short* src = (s < 4) ? s_a : s_x;
        int ko = (s & 3) * 32 + quad * 8;
#pragma unroll
        for (int g = 0; g < 4; g++) {
            short8 af = *(const short8*)&src[(g * 16 + l16) * LDS_STRIDE + ko];
            acc[g][0] = __builtin_amdgcn_mfma_f32_16x16x32_bf16(af, bf0, acc[g][0], 0, 0, 0);
            acc[g][1] = __builtin_amdgcn_mfma_f32_16x16x32_bf16(af, bf1, acc[g][1], 0, 0, 0);
        }
    }

    float b0 = bl[wave * 32 + l16];
    float b1 = bl[wave * 32 + 16 + l16];
#pragma unroll
    for (int g = 0; g < 4; g++)
#pragma unroll
        for (int t = 0; t < 2; t++) {
            float bb = t ? b1 : b0;
            int col = wave * 32 + t * 16 + l16;
#pragma unroll
            for (int q = 0; q < 4; q++) {
                int row = rowbase + g * 16 + quad * 4 + q;
                if (row < N_NODES) {
                    float v = fmaxf(acc[g][t][q] + bb, 0.f) * (1.0f / 3.0f);
                    size_t o = (size_t)row * 128 + col;
                    if (!first) v += b2f(hb[o]);
                    hb[o] = f2b(v);
                }
            }
        }
}

// ---------------------------------------------------------------------------
// Layer-2: [hWl|hWr] = h @ Wf2 (K=128); hWl -> bf16 buffer, out = hWr + bl_f.
__global__ __launch_bounds__(256, 4) void layer2_kernel(
    const unsigned short* __restrict__ hb, const unsigned short* __restrict__ Wfrag2,
    const float* __restrict__ bl_f, unsigned short* __restrict__ hWlb,
    float* __restrict__ out) {
    __shared__ unsigned short s_h[64 * LDS_STRIDE];
    int tid = threadIdx.x, wave = tid >> 6, lane = tid & 63;
    int quad = lane >> 4, l16 = lane & 15;
    int rowbase = blockIdx.x * 64;

#pragma unroll
    for (int it = 0; it < 4; it++) {
        int idx = tid + it * 256;
        int row = idx >> 4, c = idx & 15;
        int grow = rowbase + row;
        short8 hv = {0, 0, 0, 0, 0, 0, 0, 0};
        if (grow < N_NODES) hv = *(const short8*)(hb + (size_t)grow * 128 + c * 8);
        *(short8*)&s_h[row * LDS_STRIDE + c * 8] = hv;
    }
    __syncthreads();

    f32x4 acc[4][2];
#pragma unroll
    for (int g = 0; g < 4; g++) { acc[g][0] = (f32x4){0.f,0.f,0.f,0.f}; acc[g][1] = (f32x4){0.f,0.f,0.f,0.f}; }

    const unsigned short* W = Wfrag2 + wave * 4096;
#pragma unroll
    for (int s = 0; s < 4; s++) {
        short8 bf0 = *(const short8*)(W + s * 1024 + lane * 8);
        short8 bf1 = *(const short8*)(W + s * 1024 + 512 + lane * 8);
        int ko = s * 32 + quad * 8;
#pragma unroll
        for (int g = 0; g < 4; g++) {
            short8 af = *(const short8*)&s_h[(g * 16 + l16) * LDS_STRIDE + ko];
            acc[g][0] = __builtin_amdgcn_mfma_f32_16x16x32_bf16(af, bf0, acc[g][0], 0, 0, 0);
            acc[g][1] = __builtin_amdgcn_mfma_f32_16x16x32_bf16(af, bf1, acc[g][1], 0, 0, 0);
        }
    }

#pragma unroll
    for (int g = 0; g < 4; g++)
#pragma unroll
        for (int t = 0; t < 2; t++) {
            int col = wave * 32 + t * 16 + l16;
#pragma unroll
            for (int q = 0; q < 4; q++) {
                int row = rowbase + g * 16 + quad * 4 + q;
                if (row < N_NODES) {
                    if (col < 64) hWlb[(size_t)row * 64 + col] = f2b(acc[g][t][q]);
                    else out[(size_t)row * 64 + (col - 64)] = acc[g][t][q] + bl_f[col - 64];
                }
            }
        }
}

// ---------------------------------------------------------------------------
// Gather-mean of hWl (bf16, 64 ch) + add into out. Same 4x16 wave split:
// each lane loads ushort4 (8B) so one VMEM op covers 4 rows (512B/wave).
__global__ void gather64_kernel(const unsigned short* __restrict__ hWlb, const int* __restrict__ adj,
                                const int* __restrict__ rowstart, const int* __restrict__ cnt,
                                float* __restrict__ out) {
    int node = (blockIdx.x * blockDim.x + threadIdx.x) >> 6;
    int lane = threadIdx.x & 63;
    if (node >= N_NODES) return;
    int nb = lane >> 4, c16 = lane & 15;
    int start = rowstart[node];
    int deg = cnt[node];
    float a0 = 0.f, a1 = 0.f, a2 = 0.f, a3 = 0.f;
    for (int j = 0; j < deg; j += 4) {
        int jn = j + nb;
        if (jn < deg) {
            int s = adj[start + jn];
            ushort4v v = *(const ushort4v*)(hWlb + (size_t)s * 64 + c16 * 4);
            a0 += b2f(v.x); a1 += b2f(v.y); a2 += b2f(v.z); a3 += b2f(v.w);
        }
    }
    a0 += __shfl_xor(a0, 16); a0 += __shfl_xor(a0, 32);
    a1 += __shfl_xor(a1, 16); a1 += __shfl_xor(a1, 32);
    a2 += __shfl_xor(a2, 16); a2 += __shfl_xor(a2, 32);
    a3 += __shfl_xor(a3, 16); a3 += __shfl_xor(a3, 32);
    if (nb == 0) {
        float inv = 1.0f / fmaxf((float)deg, 1.0f);
        float4* o = (float4*)(out + (size_t)node * 64 + c16 * 4);
        float4 cur = *o;
        cur.x += a0 * inv; cur.y += a1 * inv; cur.z += a2 * inv; cur.w += a3 * inv;
        *o = cur;
    }
}

// ---------------------------------------------------------------------------
extern "C" void kernel_launch(void* const* d_in, const int* in_sizes, int n_in,
                              void* d_out, int out_size, void* d_ws, size_t ws_size,
                              hipStream_t stream) {
    const float* x    = (const float*)d_in[0];
    const float* Wl   = (const float*)d_in[1];
    const float* bl   = (const float*)d_in[2];
    const float* Wr   = (const float*)d_in[3];
    const float* Wl_f = (const float*)d_in[4];
    const float* bl_f = (const float*)d_in[5];
    const float* Wr_f = (const float*)d_in[6];
    const int* ei0 = (const int*)d_in[7];
    const int* ei1 = (const int*)d_in[8];
    const int* ei2 = (const int*)d_in[9];
    float* out = (float*)d_out;

    // workspace layout (offsets), total ~107 MB
    char* ws = (char*)d_ws;
    int* cnt               = (int*)(ws);                                   // 1.2 MB
    int* bincur            = (int*)(ws + 0x128000);                        // 1.5 KB
    int* rowstart          = (int*)(ws + ((size_t)4  << 20));              // 1.2 MB
    int* blocksum          = (int*)(ws + ((size_t)6  << 20));              // 1.2 KB
    unsigned short* Wfrag  = (unsigned short*)(ws + ((size_t)7  << 20));   // 192 KB
    unsigned short* Wfrag2 = (unsigned short*)(ws + ((size_t)15 << 19));   // 7.5MB, 32 KB
    int* adj               = (int*)(ws + ((size_t)8  << 20));              // 7.2 MB
    unsigned short* xb     = (unsigned short*)(ws + ((size_t)16 << 20));   // 25.6 MB
    unsigned short* aggb   = (unsigned short*)(ws + ((size_t)42 << 20));   // 25.6 MB
    unsigned short* hb     = (unsigned short*)(ws + ((size_t)68 << 20));   // 25.6 MB
    unsigned short* hWlb   = (unsigned short*)(ws + ((size_t)94 << 20));   // 12.8 MB
    // bins alias aggb: dead before gather128 writes aggb (stream-ordered)
    unsigned* bins         = (unsigned*)(ws + ((size_t)42 << 20));         // 9.4 MB

    hipMemsetAsync(bincur, 0, 3 * SUBP * sizeof(int), stream);

    bin_kernel<<<dim3(ACH, 3), 256, 0, stream>>>(ei0, ei1, ei2, bins, bincur);
    count_kernel<<<dim3(SUBP, 3), 256, 0, stream>>>(bins, bincur, cnt);
    scan1_kernel<<<dim3(NCHUNK, 3), 1024, 0, stream>>>(cnt, rowstart, blocksum);
    scan2_kernel<<<1, 128, 0, stream>>>(blocksum);
    scan3_kernel<<<dim3(392, 3), 256, 0, stream>>>(rowstart, blocksum);
    fill_kernel<<<dim3(SUBP, 3), 256, 0, stream>>>(bins, bincur, rowstart, adj);
    wprep_kernel<<<448, 256, 0, stream>>>(Wl, Wr, Wl_f, Wr_f, Wfrag, Wfrag2);
    xcast_kernel<<<(N_NODES * 128 / 8) / 256, 256, 0, stream>>>(x, xb);

    const int GATHER_BLOCKS = (N_NODES + 3) / 4;   // one wave per node
    const int TILE_BLOCKS = (N_NODES + 63) / 64;   // 1563
    for (int r = 0; r < 3; r++) {
        gather128_kernel<<<GATHER_BLOCKS, 256, 0, stream>>>(
            xb, adj + (size_t)r * N_EDGES, rowstart + r * N_NODES, cnt + r * N_NODES, aggb);
        layer1_kernel<<<TILE_BLOCKS, 256, 0, stream>>>(
            aggb, xb, Wfrag + (size_t)r * 32768, bl + r * 128, hb, r == 0 ? 1 : 0);
    }

    layer2_kernel<<<TILE_BLOCKS, 256, 0, stream>>>(hb, Wfrag2, bl_f, hWlb, out);
    gather64_kernel<<<GATHER_BLOCKS, 256, 0, stream>>>(hWlb, adj, rowstart, cnt, out);
}

// Round 6
// 396.740 us; speedup vs baseline: 1.4012x; 1.0754x over previous
//
#include <hip/hip_runtime.h>

#define N_NODES 100000
#define N_EDGES 600000
#define NCHUNK 98            // ceil(100000/1024)
#define LDS_STRIDE 136       // ushorts per row: 128 + 8 pad
#define SUBP 128             // dst sub-partitions
#define SUB_SZ 782           // nodes per sub-partition (128*782 = 100096 >= 100000)
#define ECHUNK 2048          // edges per bin_kernel block
#define ACH 293              // ceil(600000/2048)
#define BCAP 6144            // per (rel,subpart) bin capacity (mean 4687, +21 sigma)

typedef __attribute__((ext_vector_type(8))) short short8;
typedef __attribute__((ext_vector_type(4))) float f32x4;
typedef __attribute__((ext_vector_type(2))) unsigned short ushort2v;
typedef __attribute__((ext_vector_type(4))) unsigned short ushort4v;
typedef __attribute__((ext_vector_type(8))) unsigned short ushort8v;

__device__ __forceinline__ unsigned short f2b(float f) {   // fp32 -> bf16 RNE
    unsigned u = __builtin_bit_cast(unsigned, f);
    return (unsigned short)((u + 0x7fffu + ((u >> 16) & 1u)) >> 16);
}
__device__ __forceinline__ float b2f(unsigned short b) {
    return __builtin_bit_cast(float, (unsigned)b << 16);
}

// ---------------------------------------------------------------------------
// Pass A: 128-way counting sort of edges by dst sub-partition. Edge packed
// into 4B: src (17b) | local-dst (10b, <782). LDS-staged compaction ->
// line-granular global writes into per-(rel,subpart) bins.
__global__ __launch_bounds__(256) void bin_kernel(const int* __restrict__ e0,
                                                  const int* __restrict__ e1,
                                                  const int* __restrict__ e2,
                                                  unsigned* __restrict__ bins,
                                                  int* __restrict__ bincur) {
    int r = blockIdx.y;
    const int* ei = (r == 0) ? e0 : (r == 1 ? e1 : e2);
    int base = blockIdx.x * ECHUNK;
    int nhere = min(ECHUNK, N_EDGES - base);
    __shared__ int lhist[SUBP], lstart[SUBP], lcur[SUBP], gbase[SUBP];
    __shared__ unsigned led[ECHUNK];
    __shared__ unsigned char lbkt[ECHUNK];
    int tid = threadIdx.x;
    for (int i = tid; i < SUBP; i += 256) { lhist[i] = 0; lcur[i] = 0; }
    __syncthreads();

    unsigned pk[8]; int bn[8];
#pragma unroll
    for (int k = 0; k < 8; k++) {
        int i = tid + k * 256;
        bn[k] = -1;
        if (i < nhere) {
            int e = base + i;
            int s = ei[e], d = ei[N_EDGES + e];
            int b = d / SUB_SZ;
            int ld = d - b * SUB_SZ;
            pk[k] = (unsigned)s | ((unsigned)ld << 17);
            bn[k] = b;
            atomicAdd(&lhist[b], 1);
        }
    }
    __syncthreads();
    if (tid == 0) {
        int run = 0;
        for (int b = 0; b < SUBP; b++) { lstart[b] = run; run += lhist[b]; }
    }
    __syncthreads();
#pragma unroll
    for (int k = 0; k < 8; k++) {
        if (bn[k] >= 0) {
            int slot = atomicAdd(&lcur[bn[k]], 1);
            int p = lstart[bn[k]] + slot;
            led[p] = pk[k];
            lbkt[p] = (unsigned char)bn[k];
        }
    }
    if (tid < SUBP) gbase[tid] = atomicAdd(&bincur[r * SUBP + tid], lhist[tid]);
    __syncthreads();
    for (int i = tid; i < nhere; i += 256) {
        int b = lbkt[i];
        int dstidx = gbase[b] + (i - lstart[b]);
        if (dstidx < BCAP)   // safety clamp: drop (never fault) on overflow
            bins[(size_t)(r * SUBP + b) * BCAP + dstidx] = led[i];
    }
}

// ---------------------------------------------------------------------------
// Degree count: one block per (rel,subpart). LDS histogram, coalesced cnt out.
__global__ __launch_bounds__(256) void count_kernel(const unsigned* __restrict__ bins,
                                                    const int* __restrict__ bincur,
                                                    int* __restrict__ cnt) {
    int p = blockIdx.x, r = blockIdx.y;
    int n0 = p * SUB_SZ;
    int nodes = min(SUB_SZ, N_NODES - n0);
    __shared__ int hist[SUB_SZ];
    int tid = threadIdx.x;
    for (int i = tid; i < SUB_SZ; i += 256) hist[i] = 0;
    __syncthreads();
    int len = min(bincur[r * SUBP + p], BCAP);
    const unsigned* b = bins + (size_t)(r * SUBP + p) * BCAP;
    for (int i = tid; i < len; i += 256) atomicAdd(&hist[b[i] >> 17], 1);
    __syncthreads();
    for (int i = tid; i < nodes; i += 256) cnt[r * N_NODES + n0 + i] = hist[i];
}

// ---------------------------------------------------------------------------
__global__ __launch_bounds__(1024) void scan1_kernel(const int* __restrict__ cnt,
                                                     int* __restrict__ rowstart,
                                                     int* __restrict__ blocksum) {
    int r = blockIdx.y;
    int tid = threadIdx.x, lane = tid & 63, wid = tid >> 6;
    int i = blockIdx.x * 1024 + tid;
    __shared__ int wsum[16];
    int v = (i < N_NODES) ? cnt[r * N_NODES + i] : 0;
    int incl = v;
#pragma unroll
    for (int off = 1; off < 64; off <<= 1) {
        int t = __shfl_up(incl, off);
        if (lane >= off) incl += t;
    }
    if (lane == 63) wsum[wid] = incl;
    __syncthreads();
    if (wid == 0) {
        int wv = (lane < 16) ? wsum[lane] : 0;
#pragma unroll
        for (int off = 1; off < 16; off <<= 1) {
            int t = __shfl_up(wv, off);
            if (lane >= off) wv += t;
        }
        if (lane < 16) wsum[lane] = wv;
    }
    __syncthreads();
    int woff = (wid > 0) ? wsum[wid - 1] : 0;
    if (i < N_NODES) rowstart[r * N_NODES + i] = woff + incl - v;
    if (tid == 0) blocksum[r * NCHUNK + blockIdx.x] = wsum[15];
}

__global__ __launch_bounds__(128) void scan2_kernel(int* __restrict__ blocksum) {
    __shared__ int s[3 * NCHUNK];
    int tid = threadIdx.x;
    for (int i = tid; i < 3 * NCHUNK; i += 128) s[i] = blocksum[i];
    __syncthreads();
    if (tid < 3) {
        int run = 0;
        for (int j = 0; j < NCHUNK; j++) { int t = s[tid * NCHUNK + j]; s[tid * NCHUNK + j] = run; run += t; }
    }
    __syncthreads();
    for (int i = tid; i < 3 * NCHUNK; i += 128) blocksum[i] = s[i];
}

__global__ void scan3_kernel(int* __restrict__ rowstart, const int* __restrict__ blocksum) {
    int r = blockIdx.y;
    int i = blockIdx.x * 256 + threadIdx.x;
    if (i < N_NODES)
        rowstart[r * N_NODES + i] += blocksum[r * NCHUNK + (i >> 10)];
}

// ---------------------------------------------------------------------------
// CSR fill: one block per (rel,subpart). Local cursor + adj slice staged in
// LDS (LDS atomics only), then streamed out with coalesced sequential stores.
__global__ __launch_bounds__(256) void fill_kernel(const unsigned* __restrict__ bins,
                                                   const int* __restrict__ bincur,
                                                   const int* __restrict__ rowstart,
                                                   int* __restrict__ adj) {
    int p = blockIdx.x, r = blockIdx.y;
    int n0 = p * SUB_SZ;
    int nodes = min(SUB_SZ, N_NODES - n0);
    __shared__ int lcur[SUB_SZ];
    __shared__ int sstage[BCAP];
    int tid = threadIdx.x;
    const int* rs = rowstart + r * N_NODES + n0;
    int rbase = rs[0];
    for (int i = tid; i < nodes; i += 256) lcur[i] = rs[i] - rbase;
    __syncthreads();
    int len = min(bincur[r * SUBP + p], BCAP);
    const unsigned* b = bins + (size_t)(r * SUBP + p) * BCAP;
    for (int i = tid; i < len; i += 256) {
        unsigned v = b[i];
        int pos = atomicAdd(&lcur[v >> 17], 1);
        if (pos < BCAP)   // safety clamp (cannot trigger with consistent counts)
            sstage[pos] = (int)(v & 0x1FFFFu);
    }
    __syncthreads();
    int* a = adj + (size_t)r * N_EDGES + rbase;
    for (int i = tid; i < len; i += 256) a[i] = sstage[i];
}

// ---------------------------------------------------------------------------
// x (fp32) -> xb (bf16), 8 elems/thread.
__global__ void xcast_kernel(const float* __restrict__ x, unsigned short* __restrict__ xb) {
    int idx = blockIdx.x * 256 + threadIdx.x;
    const float4* p = (const float4*)x + (size_t)idx * 2;
    float4 a = p[0], b = p[1];
    ushort8v o;
    o[0] = f2b(a.x); o[1] = f2b(a.y); o[2] = f2b(a.z); o[3] = f2b(a.w);
    o[4] = f2b(b.x); o[5] = f2b(b.y); o[6] = f2b(b.z); o[7] = f2b(b.w);
    *(ushort8v*)(xb + (size_t)idx * 8) = o;
}

// ---------------------------------------------------------------------------
// Pre-swizzle weights into MFMA B-fragment order.
__global__ void wprep_kernel(const float* __restrict__ Wl, const float* __restrict__ Wr,
                             const float* __restrict__ Wl_f, const float* __restrict__ Wr_f,
                             unsigned short* __restrict__ Wfrag, unsigned short* __restrict__ Wfrag2) {
    int idx = blockIdx.x * 256 + threadIdx.x;      // 448 blocks = 114688 threads
    int j = idx & 7, lane = (idx >> 3) & 63;
    int quad = lane >> 4, l16 = lane & 15;
    if (idx < 98304) {
        int t = (idx >> 9) & 1, s = (idx >> 10) & 7, w = (idx >> 13) & 3, r = idx >> 15;
        int k = s * 32 + quad * 8 + j;
        int n = w * 32 + t * 16 + l16;
        float v = (k < 128) ? Wl[((size_t)r * 128 + k) * 128 + n]
                            : Wr[((size_t)r * 128 + (k - 128)) * 128 + n];
        Wfrag[idx] = f2b(v);
    } else {
        int i2 = idx - 98304;
        if (i2 < 16384) {
            int t = (i2 >> 9) & 1, s = (i2 >> 10) & 3, w = (i2 >> 12) & 3;
            int k = s * 32 + quad * 8 + j;
            int n = w * 32 + t * 16 + l16;
            float v = (n < 64) ? Wl_f[(size_t)k * 64 + n] : Wr_f[(size_t)k * 64 + (n - 64)];
            Wfrag2[i2] = f2b(v);
        }
    }
}

// ---------------------------------------------------------------------------
// Gather-mean from bf16 rows (256 B/row). One wave/node, 4 neighbor slots x
// 16 channel lanes. Latency fix: ONE coalesced load prefetches up to 64
// neighbor indices (lane l gets adj[start+l]); row indices then come from
// __shfl (register-only), and two independent 4-row loads issue per
// iteration -> 8 rows in flight, no per-iteration adj->row round trip.
__global__ void gather128_kernel(const unsigned short* __restrict__ xb, const int* __restrict__ adj,
                                 const int* __restrict__ rowstart, const int* __restrict__ cnt,
                                 unsigned short* __restrict__ aggb) {
    int node = (blockIdx.x * blockDim.x + threadIdx.x) >> 6;
    int lane = threadIdx.x & 63;
    if (node >= N_NODES) return;
    int nb = lane >> 4, c16 = lane & 15;
    int start = rowstart[node];
    int deg = cnt[node];
    int jmax = min(deg, 64);
    int myidx = (lane < jmax) ? adj[start + lane] : 0;   // single coalesced idx load
    float ac[8];
#pragma unroll
    for (int k = 0; k < 8; k++) ac[k] = 0.f;
    for (int j = 0; j < jmax; j += 8) {
        int jn0 = j + nb, jn1 = j + nb + 4;
        int s0 = __shfl(myidx, jn0 < jmax ? jn0 : 0);
        int s1 = __shfl(myidx, jn1 < jmax ? jn1 : 0);
        if (jn1 < jmax) {
            ushort8v v0 = *(const ushort8v*)(xb + (size_t)s0 * 128 + c16 * 8);
            ushort8v v1 = *(const ushort8v*)(xb + (size_t)s1 * 128 + c16 * 8);
#pragma unroll
            for (int k = 0; k < 8; k++) ac[k] += b2f(v0[k]) + b2f(v1[k]);
        } else if (jn0 < jmax) {
            ushort8v v0 = *(const ushort8v*)(xb + (size_t)s0 * 128 + c16 * 8);
#pragma unroll
            for (int k = 0; k < 8; k++) ac[k] += b2f(v0[k]);
        }
    }
    for (int j = 64 + nb; j < deg; j += 4) {             // rare deg>64 tail
        int s = adj[start + j];
        ushort8v v = *(const ushort8v*)(xb + (size_t)s * 128 + c16 * 8);
#pragma unroll
        for (int k = 0; k < 8; k++) ac[k] += b2f(v[k]);
    }
#pragma unroll
    for (int k = 0; k < 8; k++) {
        ac[k] += __shfl_xor(ac[k], 16);
        ac[k] += __shfl_xor(ac[k], 32);
    }
    if (nb == 0) {
        float inv = 1.0f / fmaxf((float)deg, 1.0f);
        ushort8v o;
#pragma unroll
        for (int k = 0; k < 8; k++) o[k] = f2b(ac[k] * inv);
        *(ushort8v*)(aggb + (size_t)node * 128 + c16 * 8) = o;
    }
}

// ---------------------------------------------------------------------------
// Layer-1 for one relation: hb (+)= relu([agg|x](K=256) @ W + bl) / 3  (bf16 RMW)
__global__ __launch_bounds__(256, 4) void layer1_kernel(
    const unsigned short* __restrict__ aggb, const unsigned short* __restrict__ xb,
    const unsigned short* __restrict__ Wfrag, const float* __restrict__ bl,
    unsigned short* __restrict__ hb, int first) {
    __shared__ unsigned short s_a[64 * LDS_STRIDE];
    __shared__ unsigned short s_x[64 * LDS_STRIDE];
    int tid = threadIdx.x, wave = tid >> 6, lane = tid & 63;
    int quad = lane >> 4, l16 = lane & 15;
    int rowbase = blockIdx.x * 64;

#pragma unroll
    for (int it = 0; it < 4; it++) {
        int idx = tid + it * 256;
        int row = idx >> 4, c = idx & 15;
        int grow = rowbase + row;
        short8 xv = {0, 0, 0, 0, 0, 0, 0, 0};
        if (grow < N_NODES) xv = *(const short8*)(xb + (size_t)grow * 128 + c * 8);
        *(short8*)&s_x[row * LDS_STRIDE + c * 8] = xv;
        short8 av = *(const short8*)(aggb + (size_t)(rowbase + row) * 128 + c * 8);
        *(short8*)&s_a[row * LDS_STRIDE + c * 8] = av;
    }
    __syncthreads();

    f32x4 acc[4][2];
#pragma unroll
    for (int g = 0; g < 4; g++) { acc[g][0] = (f32x4){0.f,0.f,0.f,0.f}; acc[g][1] = (f32x4){0.f,0.f,0.f,0.f}; }

    const unsigned short* W = Wfrag + wave * 8192;
#pragma unroll
    for (int s = 0; s < 8; s++) {
        short8 bf0 = *(const short8*)(W + s * 1024 + lane * 8);         // coalesced 1KB
        short8 bf1 = *(const short8*)(W + s * 1024 + 512 + lane * 8);
        const unsigned short* src = (s < 4) ? s_a : s_x;
        int ko = (s & 3) * 32 + quad * 8;
#pragma unroll
        for (int g = 0; g < 4; g++) {
            short8 af = *(const short8*)&src[(g * 16 + l16) * LDS_STRIDE + ko];
            acc[g][0] = __builtin_amdgcn_mfma_f32_16x16x32_bf16(af, bf0, acc[g][0], 0, 0, 0);
            acc[g][1] = __builtin_amdgcn_mfma_f32_16x16x32_bf16(af, bf1, acc[g][1], 0, 0, 0);
        }
    }

    float b0 = bl[wave * 32 + l16];
    float b1 = bl[wave * 32 + 16 + l16];
#pragma unroll
    for (int g = 0; g < 4; g++)
#pragma unroll
        for (int t = 0; t < 2; t++) {
            float bb = t ? b1 : b0;
            int col = wave * 32 + t * 16 + l16;
#pragma unroll
            for (int q = 0; q < 4; q++) {
                int row = rowbase + g * 16 + quad * 4 + q;
                if (row < N_NODES) {
                    float v = fmaxf(acc[g][t][q] + bb, 0.f) * (1.0f / 3.0f);
                    size_t o = (size_t)row * 128 + col;
                    if (!first) v += b2f(hb[o]);
                    hb[o] = f2b(v);
                }
            }
        }
}

// ---------------------------------------------------------------------------
// Layer-2: [hWl|hWr] = h @ Wf2 (K=128); hWl -> bf16 buffer, out = hWr + bl_f.
__global__ __launch_bounds__(256, 4) void layer2_kernel(
    const unsigned short* __restrict__ hb, const unsigned short* __restrict__ Wfrag2,
    const float* __restrict__ bl_f, unsigned short* __restrict__ hWlb,
    float* __restrict__ out) {
    __shared__ unsigned short s_h[64 * LDS_STRIDE];
    int tid = threadIdx.x, wave = tid >> 6, lane = tid & 63;
    int quad = lane >> 4, l16 = lane & 15;
    int rowbase = blockIdx.x * 64;

#pragma unroll
    for (int it = 0; it < 4; it++) {
        int idx = tid + it * 256;
        int row = idx >> 4, c = idx & 15;
        int grow = rowbase + row;
        short8 hv = {0, 0, 0, 0, 0, 0, 0, 0};
        if (grow < N_NODES) hv = *(const short8*)(hb + (size_t)grow * 128 + c * 8);
        *(short8*)&s_h[row * LDS_STRIDE + c * 8] = hv;
    }
    __syncthreads();

    f32x4 acc[4][2];
#pragma unroll
    for (int g = 0; g < 4; g++) { acc[g][0] = (f32x4){0.f,0.f,0.f,0.f}; acc[g][1] = (f32x4){0.f,0.f,0.f,0.f}; }

    const unsigned short* W = Wfrag2 + wave * 4096;
#pragma unroll
    for (int s = 0; s < 4; s++) {
        short8 bf0 = *(const short8*)(W + s * 1024 + lane * 8);
        short8 bf1 = *(const short8*)(W + s * 1024 + 512 + lane * 8);
        int ko = s * 32 + quad * 8;
#pragma unroll
        for (int g = 0; g < 4; g++) {
            short8 af = *(const short8*)&s_h[(g * 16 + l16) * LDS_STRIDE + ko];
            acc[g][0] = __builtin_amdgcn_mfma_f32_16x16x32_bf16(af, bf0, acc[g][0], 0, 0, 0);
            acc[g][1] = __builtin_amdgcn_mfma_f32_16x16x32_bf16(af, bf1, acc[g][1], 0, 0, 0);
        }
    }

#pragma unroll
    for (int g = 0; g < 4; g++)
#pragma unroll
        for (int t = 0; t < 2; t++) {
            int col = wave * 32 + t * 16 + l16;
#pragma unroll
            for (int q = 0; q < 4; q++) {
                int row = rowbase + g * 16 + quad * 4 + q;
                if (row < N_NODES) {
                    if (col < 64) hWlb[(size_t)row * 64 + col] = f2b(acc[g][t][q]);
                    else out[(size_t)row * 64 + (col - 64)] = acc[g][t][q] + bl_f[col - 64];
                }
            }
        }
}

// ---------------------------------------------------------------------------
// Gather-mean of hWl (bf16, 64 ch) + add into out. Same idx-prefetch + paired
// independent loads; 16 lanes x ushort4 = one 128B row per slot.
__global__ void gather64_kernel(const unsigned short* __restrict__ hWlb, const int* __restrict__ adj,
                                const int* __restrict__ rowstart, const int* __restrict__ cnt,
                                float* __restrict__ out) {
    int node = (blockIdx.x * blockDim.x + threadIdx.x) >> 6;
    int lane = threadIdx.x & 63;
    if (node >= N_NODES) return;
    int nb = lane >> 4, c16 = lane & 15;
    int start = rowstart[node];
    int deg = cnt[node];
    int jmax = min(deg, 64);
    int myidx = (lane < jmax) ? adj[start + lane] : 0;
    float a0 = 0.f, a1 = 0.f, a2 = 0.f, a3 = 0.f;
    for (int j = 0; j < jmax; j += 8) {
        int jn0 = j + nb, jn1 = j + nb + 4;
        int s0 = __shfl(myidx, jn0 < jmax ? jn0 : 0);
        int s1 = __shfl(myidx, jn1 < jmax ? jn1 : 0);
        if (jn1 < jmax) {
            ushort4v v0 = *(const ushort4v*)(hWlb + (size_t)s0 * 64 + c16 * 4);
            ushort4v v1 = *(const ushort4v*)(hWlb + (size_t)s1 * 64 + c16 * 4);
            a0 += b2f(v0.x) + b2f(v1.x); a1 += b2f(v0.y) + b2f(v1.y);
            a2 += b2f(v0.z) + b2f(v1.z); a3 += b2f(v0.w) + b2f(v1.w);
        } else if (jn0 < jmax) {
            ushort4v v0 = *(const ushort4v*)(hWlb + (size_t)s0 * 64 + c16 * 4);
            a0 += b2f(v0.x); a1 += b2f(v0.y); a2 += b2f(v0.z); a3 += b2f(v0.w);
        }
    }
    for (int j = 64 + nb; j < deg; j += 4) {             // rare deg>64 tail
        int s = adj[start + j];
        ushort4v v = *(const ushort4v*)(hWlb + (size_t)s * 64 + c16 * 4);
        a0 += b2f(v.x); a1 += b2f(v.y); a2 += b2f(v.z); a3 += b2f(v.w);
    }
    a0 += __shfl_xor(a0, 16); a0 += __shfl_xor(a0, 32);
    a1 += __shfl_xor(a1, 16); a1 += __shfl_xor(a1, 32);
    a2 += __shfl_xor(a2, 16); a2 += __shfl_xor(a2, 32);
    a3 += __shfl_xor(a3, 16); a3 += __shfl_xor(a3, 32);
    if (nb == 0) {
        float inv = 1.0f / fmaxf((float)deg, 1.0f);
        float4* o = (float4*)(out + (size_t)node * 64 + c16 * 4);
        float4 cur = *o;
        cur.x += a0 * inv; cur.y += a1 * inv; cur.z += a2 * inv; cur.w += a3 * inv;
        *o = cur;
    }
}

// ---------------------------------------------------------------------------
extern "C" void kernel_launch(void* const* d_in, const int* in_sizes, int n_in,
                              void* d_out, int out_size, void* d_ws, size_t ws_size,
                              hipStream_t stream) {
    const float* x    = (const float*)d_in[0];
    const float* Wl   = (const float*)d_in[1];
    const float* bl   = (const float*)d_in[2];
    const float* Wr   = (const float*)d_in[3];
    const float* Wl_f = (const float*)d_in[4];
    const float* bl_f = (const float*)d_in[5];
    const float* Wr_f = (const float*)d_in[6];
    const int* ei0 = (const int*)d_in[7];
    const int* ei1 = (const int*)d_in[8];
    const int* ei2 = (const int*)d_in[9];
    float* out = (float*)d_out;

    // workspace layout (offsets), total ~107 MB
    char* ws = (char*)d_ws;
    int* cnt               = (int*)(ws);                                   // 1.2 MB
    int* bincur            = (int*)(ws + 0x128000);                        // 1.5 KB
    int* rowstart          = (int*)(ws + ((size_t)4  << 20));              // 1.2 MB
    int* blocksum          = (int*)(ws + ((size_t)6  << 20));              // 1.2 KB
    unsigned short* Wfrag  = (unsigned short*)(ws + ((size_t)7  << 20));   // 192 KB
    unsigned short* Wfrag2 = (unsigned short*)(ws + ((size_t)15 << 19));   // 7.5MB, 32 KB
    int* adj               = (int*)(ws + ((size_t)8  << 20));              // 7.2 MB
    unsigned short* xb     = (unsigned short*)(ws + ((size_t)16 << 20));   // 25.6 MB
    unsigned short* aggb   = (unsigned short*)(ws + ((size_t)42 << 20));   // 25.6 MB
    unsigned short* hb     = (unsigned short*)(ws + ((size_t)68 << 20));   // 25.6 MB
    unsigned short* hWlb   = (unsigned short*)(ws + ((size_t)94 << 20));   // 12.8 MB
    // bins alias aggb: dead before gather128 writes aggb (stream-ordered)
    unsigned* bins         = (unsigned*)(ws + ((size_t)42 << 20));         // 9.4 MB

    hipMemsetAsync(bincur, 0, 3 * SUBP * sizeof(int), stream);

    bin_kernel<<<dim3(ACH, 3), 256, 0, stream>>>(ei0, ei1, ei2, bins, bincur);
    count_kernel<<<dim3(SUBP, 3), 256, 0, stream>>>(bins, bincur, cnt);
    scan1_kernel<<<dim3(NCHUNK, 3), 1024, 0, stream>>>(cnt, rowstart, blocksum);
    scan2_kernel<<<1, 128, 0, stream>>>(blocksum);
    scan3_kernel<<<dim3(392, 3), 256, 0, stream>>>(rowstart, blocksum);
    fill_kernel<<<dim3(SUBP, 3), 256, 0, stream>>>(bins, bincur, rowstart, adj);
    wprep_kernel<<<448, 256, 0, stream>>>(Wl, Wr, Wl_f, Wr_f, Wfrag, Wfrag2);
    xcast_kernel<<<(N_NODES * 128 / 8) / 256, 256, 0, stream>>>(x, xb);

    const int GATHER_BLOCKS = (N_NODES + 3) / 4;   // one wave per node
    const int TILE_BLOCKS = (N_NODES + 63) / 64;   // 1563
    for (int r = 0; r < 3; r++) {
        gather128_kernel<<<GATHER_BLOCKS, 256, 0, stream>>>(
            xb, adj + (size_t)r * N_EDGES, rowstart + r * N_NODES, cnt + r * N_NODES, aggb);
        layer1_kernel<<<TILE_BLOCKS, 256, 0, stream>>>(
            aggb, xb, Wfrag + (size_t)r * 32768, bl + r * 128, hb, r == 0 ? 1 : 0);
    }

    layer2_kernel<<<TILE_BLOCKS, 256, 0, stream>>>(hb, Wfrag2, bl_f, hWlb, out);
    gather64_kernel<<<GATHER_BLOCKS, 256, 0, stream>>>(hWlb, adj, rowstart, cnt, out);
}

// Round 7
// 373.972 us; speedup vs baseline: 1.4866x; 1.0609x over previous
//
#include <hip/hip_runtime.h>

#define N_NODES 100000
#define N_EDGES 600000
#define NCHUNK 98            // ceil(100000/1024)
#define LDS_STRIDE 136       // ushorts per row: 128 + 8 pad
#define SUBP 128             // dst sub-partitions
#define SUB_SZ 782           // nodes per sub-partition (128*782 = 100096 >= 100000)
#define ECHUNK 2048          // edges per bin_kernel block
#define ACH 293              // ceil(600000/2048)
#define BCAP 6144            // per (rel,subpart) bin capacity (mean 4687, +21 sigma)

typedef __attribute__((ext_vector_type(8))) short short8;
typedef __attribute__((ext_vector_type(4))) float f32x4;
typedef __attribute__((ext_vector_type(2))) unsigned short ushort2v;
typedef __attribute__((ext_vector_type(4))) unsigned short ushort4v;
typedef __attribute__((ext_vector_type(8))) unsigned short ushort8v;

__device__ __forceinline__ unsigned short f2b(float f) {   // fp32 -> bf16 RNE
    unsigned u = __builtin_bit_cast(unsigned, f);
    return (unsigned short)((u + 0x7fffu + ((u >> 16) & 1u)) >> 16);
}
__device__ __forceinline__ float b2f(unsigned short b) {
    return __builtin_bit_cast(float, (unsigned)b << 16);
}

// ---------------------------------------------------------------------------
// Pass A: 128-way counting sort of edges by dst sub-partition. Edge packed
// into 4B: src (17b) | local-dst (10b, <782). LDS-staged compaction ->
// line-granular global writes into per-(rel,subpart) bins.
__global__ __launch_bounds__(256) void bin_kernel(const int* __restrict__ e0,
                                                  const int* __restrict__ e1,
                                                  const int* __restrict__ e2,
                                                  unsigned* __restrict__ bins,
                                                  int* __restrict__ bincur) {
    int r = blockIdx.y;
    const int* ei = (r == 0) ? e0 : (r == 1 ? e1 : e2);
    int base = blockIdx.x * ECHUNK;
    int nhere = min(ECHUNK, N_EDGES - base);
    __shared__ int lhist[SUBP], lstart[SUBP], lcur[SUBP], gbase[SUBP];
    __shared__ unsigned led[ECHUNK];
    __shared__ unsigned char lbkt[ECHUNK];
    int tid = threadIdx.x;
    for (int i = tid; i < SUBP; i += 256) { lhist[i] = 0; lcur[i] = 0; }
    __syncthreads();

    unsigned pk[8]; int bn[8];
#pragma unroll
    for (int k = 0; k < 8; k++) {
        int i = tid + k * 256;
        bn[k] = -1;
        if (i < nhere) {
            int e = base + i;
            int s = ei[e], d = ei[N_EDGES + e];
            int b = d / SUB_SZ;
            int ld = d - b * SUB_SZ;
            pk[k] = (unsigned)s | ((unsigned)ld << 17);
            bn[k] = b;
            atomicAdd(&lhist[b], 1);
        }
    }
    __syncthreads();
    if (tid == 0) {
        int run = 0;
        for (int b = 0; b < SUBP; b++) { lstart[b] = run; run += lhist[b]; }
    }
    __syncthreads();
#pragma unroll
    for (int k = 0; k < 8; k++) {
        if (bn[k] >= 0) {
            int slot = atomicAdd(&lcur[bn[k]], 1);
            int p = lstart[bn[k]] + slot;
            led[p] = pk[k];
            lbkt[p] = (unsigned char)bn[k];
        }
    }
    if (tid < SUBP) gbase[tid] = atomicAdd(&bincur[r * SUBP + tid], lhist[tid]);
    __syncthreads();
    for (int i = tid; i < nhere; i += 256) {
        int b = lbkt[i];
        int dstidx = gbase[b] + (i - lstart[b]);
        if (dstidx < BCAP)   // safety clamp: drop (never fault) on overflow
            bins[(size_t)(r * SUBP + b) * BCAP + dstidx] = led[i];
    }
}

// ---------------------------------------------------------------------------
// Degree count: one block per (rel,subpart). LDS histogram, coalesced cnt out.
__global__ __launch_bounds__(256) void count_kernel(const unsigned* __restrict__ bins,
                                                    const int* __restrict__ bincur,
                                                    int* __restrict__ cnt) {
    int p = blockIdx.x, r = blockIdx.y;
    int n0 = p * SUB_SZ;
    int nodes = min(SUB_SZ, N_NODES - n0);
    __shared__ int hist[SUB_SZ];
    int tid = threadIdx.x;
    for (int i = tid; i < SUB_SZ; i += 256) hist[i] = 0;
    __syncthreads();
    int len = min(bincur[r * SUBP + p], BCAP);
    const unsigned* b = bins + (size_t)(r * SUBP + p) * BCAP;
    for (int i = tid; i < len; i += 256) atomicAdd(&hist[b[i] >> 17], 1);
    __syncthreads();
    for (int i = tid; i < nodes; i += 256) cnt[r * N_NODES + n0 + i] = hist[i];
}

// ---------------------------------------------------------------------------
__global__ __launch_bounds__(1024) void scan1_kernel(const int* __restrict__ cnt,
                                                     int* __restrict__ rowstart,
                                                     int* __restrict__ blocksum) {
    int r = blockIdx.y;
    int tid = threadIdx.x, lane = tid & 63, wid = tid >> 6;
    int i = blockIdx.x * 1024 + tid;
    __shared__ int wsum[16];
    int v = (i < N_NODES) ? cnt[r * N_NODES + i] : 0;
    int incl = v;
#pragma unroll
    for (int off = 1; off < 64; off <<= 1) {
        int t = __shfl_up(incl, off);
        if (lane >= off) incl += t;
    }
    if (lane == 63) wsum[wid] = incl;
    __syncthreads();
    if (wid == 0) {
        int wv = (lane < 16) ? wsum[lane] : 0;
#pragma unroll
        for (int off = 1; off < 16; off <<= 1) {
            int t = __shfl_up(wv, off);
            if (lane >= off) wv += t;
        }
        if (lane < 16) wsum[lane] = wv;
    }
    __syncthreads();
    int woff = (wid > 0) ? wsum[wid - 1] : 0;
    if (i < N_NODES) rowstart[r * N_NODES + i] = woff + incl - v;
    if (tid == 0) blocksum[r * NCHUNK + blockIdx.x] = wsum[15];
}

__global__ __launch_bounds__(128) void scan2_kernel(int* __restrict__ blocksum) {
    __shared__ int s[3 * NCHUNK];
    int tid = threadIdx.x;
    for (int i = tid; i < 3 * NCHUNK; i += 128) s[i] = blocksum[i];
    __syncthreads();
    if (tid < 3) {
        int run = 0;
        for (int j = 0; j < NCHUNK; j++) { int t = s[tid * NCHUNK + j]; s[tid * NCHUNK + j] = run; run += t; }
    }
    __syncthreads();
    for (int i = tid; i < 3 * NCHUNK; i += 128) blocksum[i] = s[i];
}

__global__ void scan3_kernel(int* __restrict__ rowstart, const int* __restrict__ blocksum) {
    int r = blockIdx.y;
    int i = blockIdx.x * 256 + threadIdx.x;
    if (i < N_NODES)
        rowstart[r * N_NODES + i] += blocksum[r * NCHUNK + (i >> 10)];
}

// ---------------------------------------------------------------------------
// CSR fill: one block per (rel,subpart). Local cursor + adj slice staged in
// LDS (LDS atomics only), then streamed out with coalesced sequential stores.
__global__ __launch_bounds__(256) void fill_kernel(const unsigned* __restrict__ bins,
                                                   const int* __restrict__ bincur,
                                                   const int* __restrict__ rowstart,
                                                   int* __restrict__ adj) {
    int p = blockIdx.x, r = blockIdx.y;
    int n0 = p * SUB_SZ;
    int nodes = min(SUB_SZ, N_NODES - n0);
    __shared__ int lcur[SUB_SZ];
    __shared__ int sstage[BCAP];
    int tid = threadIdx.x;
    const int* rs = rowstart + r * N_NODES + n0;
    int rbase = rs[0];
    for (int i = tid; i < nodes; i += 256) lcur[i] = rs[i] - rbase;
    __syncthreads();
    int len = min(bincur[r * SUBP + p], BCAP);
    const unsigned* b = bins + (size_t)(r * SUBP + p) * BCAP;
    for (int i = tid; i < len; i += 256) {
        unsigned v = b[i];
        int pos = atomicAdd(&lcur[v >> 17], 1);
        if (pos < BCAP)   // safety clamp (cannot trigger with consistent counts)
            sstage[pos] = (int)(v & 0x1FFFFu);
    }
    __syncthreads();
    int* a = adj + (size_t)r * N_EDGES + rbase;
    for (int i = tid; i < len; i += 256) a[i] = sstage[i];
}

// ---------------------------------------------------------------------------
// x (fp32) -> xb (bf16), 8 elems/thread.
__global__ void xcast_kernel(const float* __restrict__ x, unsigned short* __restrict__ xb) {
    int idx = blockIdx.x * 256 + threadIdx.x;
    const float4* p = (const float4*)x + (size_t)idx * 2;
    float4 a = p[0], b = p[1];
    ushort8v o;
    o[0] = f2b(a.x); o[1] = f2b(a.y); o[2] = f2b(a.z); o[3] = f2b(a.w);
    o[4] = f2b(b.x); o[5] = f2b(b.y); o[6] = f2b(b.z); o[7] = f2b(b.w);
    *(ushort8v*)(xb + (size_t)idx * 8) = o;
}

// ---------------------------------------------------------------------------
// Pre-swizzle weights into MFMA B-fragment order.
__global__ void wprep_kernel(const float* __restrict__ Wl, const float* __restrict__ Wr,
                             const float* __restrict__ Wl_f, const float* __restrict__ Wr_f,
                             unsigned short* __restrict__ Wfrag, unsigned short* __restrict__ Wfrag2) {
    int idx = blockIdx.x * 256 + threadIdx.x;      // 448 blocks = 114688 threads
    int j = idx & 7, lane = (idx >> 3) & 63;
    int quad = lane >> 4, l16 = lane & 15;
    if (idx < 98304) {
        int t = (idx >> 9) & 1, s = (idx >> 10) & 7, w = (idx >> 13) & 3, r = idx >> 15;
        int k = s * 32 + quad * 8 + j;
        int n = w * 32 + t * 16 + l16;
        float v = (k < 128) ? Wl[((size_t)r * 128 + k) * 128 + n]
                            : Wr[((size_t)r * 128 + (k - 128)) * 128 + n];
        Wfrag[idx] = f2b(v);
    } else {
        int i2 = idx - 98304;
        if (i2 < 16384) {
            int t = (i2 >> 9) & 1, s = (i2 >> 10) & 3, w = (i2 >> 12) & 3;
            int k = s * 32 + quad * 8 + j;
            int n = w * 32 + t * 16 + l16;
            float v = (n < 64) ? Wl_f[(size_t)k * 64 + n] : Wr_f[(size_t)k * 64 + (n - 64)];
            Wfrag2[i2] = f2b(v);
        }
    }
}

// ---------------------------------------------------------------------------
// Gather-mean from bf16 rows (256 B/row). FOUR nodes per wave, one per
// 16-lane slot: a slot's 16 lanes cover a full row (16 x ushort8 = 256 B),
// so each lane accumulates its own channel slice -> NO cross-lane reduce.
// Per slot: one coalesced 16-index prefetch, then rows via intra-slot shfl,
// 2 rows in flight per slot (8/wave). Per-wave fixed latency amortized 4x.
__global__ void gather128_kernel(const unsigned short* __restrict__ xb, const int* __restrict__ adj,
                                 const int* __restrict__ rowstart, const int* __restrict__ cnt,
                                 unsigned short* __restrict__ aggb) {
    int wv = (blockIdx.x * blockDim.x + threadIdx.x) >> 6;   // global wave id
    int lane = threadIdx.x & 63;
    int nb = lane >> 4, c16 = lane & 15;
    int node = wv * 4 + nb;
    bool valid = node < N_NODES;
    int start = 0, deg = 0;
    if (valid) { start = rowstart[node]; deg = cnt[node]; }
    int jcap = min(deg, 16);
    int myidx = (valid && c16 < jcap) ? adj[start + c16] : 0;   // 16-idx prefetch/slot
    int dmax = jcap;
    dmax = max(dmax, __shfl_xor(dmax, 16));
    dmax = max(dmax, __shfl_xor(dmax, 32));
    float ac[8];
#pragma unroll
    for (int k = 0; k < 8; k++) ac[k] = 0.f;
    int sb = nb * 16;
    for (int j = 0; j < dmax; j += 2) {
        int s0 = __shfl(myidx, sb + j);
        int s1 = __shfl(myidx, sb + min(j + 1, 15));
        bool a0 = j < jcap, a1 = (j + 1) < jcap;
        ushort8v v0, v1;
        if (a0) v0 = *(const ushort8v*)(xb + (size_t)s0 * 128 + c16 * 8);
        if (a1) v1 = *(const ushort8v*)(xb + (size_t)s1 * 128 + c16 * 8);
        if (a0) {
#pragma unroll
            for (int k = 0; k < 8; k++) ac[k] += b2f(v0[k]);
        }
        if (a1) {
#pragma unroll
            for (int k = 0; k < 8; k++) ac[k] += b2f(v1[k]);
        }
    }
    for (int j = 16; j < deg; j++) {        // rare deg>16 tail (broadcast idx)
        int s = adj[start + j];
        ushort8v v = *(const ushort8v*)(xb + (size_t)s * 128 + c16 * 8);
#pragma unroll
        for (int k = 0; k < 8; k++) ac[k] += b2f(v[k]);
    }
    if (valid) {
        float inv = 1.0f / fmaxf((float)deg, 1.0f);
        ushort8v o;
#pragma unroll
        for (int k = 0; k < 8; k++) o[k] = f2b(ac[k] * inv);
        *(ushort8v*)(aggb + (size_t)node * 128 + c16 * 8) = o;
    }
}

// ---------------------------------------------------------------------------
// Layer-1 for one relation: hb (+)= relu([agg|x](K=256) @ W + bl) / 3  (bf16 RMW)
__global__ __launch_bounds__(256, 4) void layer1_kernel(
    const unsigned short* __restrict__ aggb, const unsigned short* __restrict__ xb,
    const unsigned short* __restrict__ Wfrag, const float* __restrict__ bl,
    unsigned short* __restrict__ hb, int first) {
    __shared__ unsigned short s_a[64 * LDS_STRIDE];
    __shared__ unsigned short s_x[64 * LDS_STRIDE];
    int tid = threadIdx.x, wave = tid >> 6, lane = tid & 63;
    int quad = lane >> 4, l16 = lane & 15;
    int rowbase = blockIdx.x * 64;

#pragma unroll
    for (int it = 0; it < 4; it++) {
        int idx = tid + it * 256;
        int row = idx >> 4, c = idx & 15;
        int grow = rowbase + row;
        short8 xv = {0, 0, 0, 0, 0, 0, 0, 0};
        if (grow < N_NODES) xv = *(const short8*)(xb + (size_t)grow * 128 + c * 8);
        *(short8*)&s_x[row * LDS_STRIDE + c * 8] = xv;
        short8 av = *(const short8*)(aggb + (size_t)(rowbase + row) * 128 + c * 8);
        *(short8*)&s_a[row * LDS_STRIDE + c * 8] = av;
    }
    __syncthreads();

    f32x4 acc[4][2];
#pragma unroll
    for (int g = 0; g < 4; g++) { acc[g][0] = (f32x4){0.f,0.f,0.f,0.f}; acc[g][1] = (f32x4){0.f,0.f,0.f,0.f}; }

    const unsigned short* W = Wfrag + wave * 8192;
#pragma unroll
    for (int s = 0; s < 8; s++) {
        short8 bf0 = *(const short8*)(W + s * 1024 + lane * 8);         // coalesced 1KB
        short8 bf1 = *(const short8*)(W + s * 1024 + 512 + lane * 8);
        const unsigned short* src = (s < 4) ? s_a : s_x;
        int ko = (s & 3) * 32 + quad * 8;
#pragma unroll
        for (int g = 0; g < 4; g++) {
            short8 af = *(const short8*)&src[(g * 16 + l16) * LDS_STRIDE + ko];
            acc[g][0] = __builtin_amdgcn_mfma_f32_16x16x32_bf16(af, bf0, acc[g][0], 0, 0, 0);
            acc[g][1] = __builtin_amdgcn_mfma_f32_16x16x32_bf16(af, bf1, acc[g][1], 0, 0, 0);
        }
    }

    float b0 = bl[wave * 32 + l16];
    float b1 = bl[wave * 32 + 16 + l16];
#pragma unroll
    for (int g = 0; g < 4; g++)
#pragma unroll
        for (int t = 0; t < 2; t++) {
            float bb = t ? b1 : b0;
            int col = wave * 32 + t * 16 + l16;
#pragma unroll
            for (int q = 0; q < 4; q++) {
                int row = rowbase + g * 16 + quad * 4 + q;
                if (row < N_NODES) {
                    float v = fmaxf(acc[g][t][q] + bb, 0.f) * (1.0f / 3.0f);
                    size_t o = (size_t)row * 128 + col;
                    if (!first) v += b2f(hb[o]);
                    hb[o] = f2b(v);
                }
            }
        }
}

// ---------------------------------------------------------------------------
// Layer-2: [hWl|hWr] = h @ Wf2 (K=128); hWl -> bf16 buffer, out = hWr + bl_f.
__global__ __launch_bounds__(256, 4) void layer2_kernel(
    const unsigned short* __restrict__ hb, const unsigned short* __restrict__ Wfrag2,
    const float* __restrict__ bl_f, unsigned short* __restrict__ hWlb,
    float* __restrict__ out) {
    __shared__ unsigned short s_h[64 * LDS_STRIDE];
    int tid = threadIdx.x, wave = tid >> 6, lane = tid & 63;
    int quad = lane >> 4, l16 = lane & 15;
    int rowbase = blockIdx.x * 64;

#pragma unroll
    for (int it = 0; it < 4; it++) {
        int idx = tid + it * 256;
        int row = idx >> 4, c = idx & 15;
        int grow = rowbase + row;
        short8 hv = {0, 0, 0, 0, 0, 0, 0, 0};
        if (grow < N_NODES) hv = *(const short8*)(hb + (size_t)grow * 128 + c * 8);
        *(short8*)&s_h[row * LDS_STRIDE + c * 8] = hv;
    }
    __syncthreads();

    f32x4 acc[4][2];
#pragma unroll
    for (int g = 0; g < 4; g++) { acc[g][0] = (f32x4){0.f,0.f,0.f,0.f}; acc[g][1] = (f32x4){0.f,0.f,0.f,0.f}; }

    const unsigned short* W = Wfrag2 + wave * 4096;
#pragma unroll
    for (int s = 0; s < 4; s++) {
        short8 bf0 = *(const short8*)(W + s * 1024 + lane * 8);
        short8 bf1 = *(const short8*)(W + s * 1024 + 512 + lane * 8);
        int ko = s * 32 + quad * 8;
#pragma unroll
        for (int g = 0; g < 4; g++) {
            short8 af = *(const short8*)&s_h[(g * 16 + l16) * LDS_STRIDE + ko];
            acc[g][0] = __builtin_amdgcn_mfma_f32_16x16x32_bf16(af, bf0, acc[g][0], 0, 0, 0);
            acc[g][1] = __builtin_amdgcn_mfma_f32_16x16x32_bf16(af, bf1, acc[g][1], 0, 0, 0);
        }
    }

#pragma unroll
    for (int g = 0; g < 4; g++)
#pragma unroll
        for (int t = 0; t < 2; t++) {
            int col = wave * 32 + t * 16 + l16;
#pragma unroll
            for (int q = 0; q < 4; q++) {
                int row = rowbase + g * 16 + quad * 4 + q;
                if (row < N_NODES) {
                    if (col < 64) hWlb[(size_t)row * 64 + col] = f2b(acc[g][t][q]);
                    else out[(size_t)row * 64 + (col - 64)] = acc[g][t][q] + bl_f[col - 64];
                }
            }
        }
}

// ---------------------------------------------------------------------------
// Gather-mean of hWl (bf16, 64 ch = 128 B row = 16 x ushort4) + add into out.
// Same 4-nodes-per-wave slot structure as gather128; no cross-lane reduce.
__global__ void gather64_kernel(const unsigned short* __restrict__ hWlb, const int* __restrict__ adj,
                                const int* __restrict__ rowstart, const int* __restrict__ cnt,
                                float* __restrict__ out) {
    int wv = (blockIdx.x * blockDim.x + threadIdx.x) >> 6;
    int lane = threadIdx.x & 63;
    int nb = lane >> 4, c16 = lane & 15;
    int node = wv * 4 + nb;
    bool valid = node < N_NODES;
    int start = 0, deg = 0;
    if (valid) { start = rowstart[node]; deg = cnt[node]; }
    int jcap = min(deg, 16);
    int myidx = (valid && c16 < jcap) ? adj[start + c16] : 0;
    int dmax = jcap;
    dmax = max(dmax, __shfl_xor(dmax, 16));
    dmax = max(dmax, __shfl_xor(dmax, 32));
    float a0 = 0.f, a1 = 0.f, a2 = 0.f, a3 = 0.f;
    int sb = nb * 16;
    for (int j = 0; j < dmax; j += 2) {
        int s0 = __shfl(myidx, sb + j);
        int s1 = __shfl(myidx, sb + min(j + 1, 15));
        bool c0 = j < jcap, c1 = (j + 1) < jcap;
        ushort4v v0, v1;
        if (c0) v0 = *(const ushort4v*)(hWlb + (size_t)s0 * 64 + c16 * 4);
        if (c1) v1 = *(const ushort4v*)(hWlb + (size_t)s1 * 64 + c16 * 4);
        if (c0) { a0 += b2f(v0.x); a1 += b2f(v0.y); a2 += b2f(v0.z); a3 += b2f(v0.w); }
        if (c1) { a0 += b2f(v1.x); a1 += b2f(v1.y); a2 += b2f(v1.z); a3 += b2f(v1.w); }
    }
    for (int j = 16; j < deg; j++) {        // rare deg>16 tail
        int s = adj[start + j];
        ushort4v v = *(const ushort4v*)(hWlb + (size_t)s * 64 + c16 * 4);
        a0 += b2f(v.x); a1 += b2f(v.y); a2 += b2f(v.z); a3 += b2f(v.w);
    }
    if (valid) {
        float inv = 1.0f / fmaxf((float)deg, 1.0f);
        float4* o = (float4*)(out + (size_t)node * 64 + c16 * 4);
        float4 cur = *o;
        cur.x += a0 * inv; cur.y += a1 * inv; cur.z += a2 * inv; cur.w += a3 * inv;
        *o = cur;
    }
}

// ---------------------------------------------------------------------------
extern "C" void kernel_launch(void* const* d_in, const int* in_sizes, int n_in,
                              void* d_out, int out_size, void* d_ws, size_t ws_size,
                              hipStream_t stream) {
    const float* x    = (const float*)d_in[0];
    const float* Wl   = (const float*)d_in[1];
    const float* bl   = (const float*)d_in[2];
    const float* Wr   = (const float*)d_in[3];
    const float* Wl_f = (const float*)d_in[4];
    const float* bl_f = (const float*)d_in[5];
    const float* Wr_f = (const float*)d_in[6];
    const int* ei0 = (const int*)d_in[7];
    const int* ei1 = (const int*)d_in[8];
    const int* ei2 = (const int*)d_in[9];
    float* out = (float*)d_out;

    // workspace layout (offsets), total ~107 MB
    char* ws = (char*)d_ws;
    int* cnt               = (int*)(ws);                                   // 1.2 MB
    int* bincur            = (int*)(ws + 0x128000);                        // 1.5 KB
    int* rowstart          = (int*)(ws + ((size_t)4  << 20));              // 1.2 MB
    int* blocksum          = (int*)(ws + ((size_t)6  << 20));              // 1.2 KB
    unsigned short* Wfrag  = (unsigned short*)(ws + ((size_t)7  << 20));   // 192 KB
    unsigned short* Wfrag2 = (unsigned short*)(ws + ((size_t)15 << 19));   // 7.5MB, 32 KB
    int* adj               = (int*)(ws + ((size_t)8  << 20));              // 7.2 MB
    unsigned short* xb     = (unsigned short*)(ws + ((size_t)16 << 20));   // 25.6 MB
    unsigned short* aggb   = (unsigned short*)(ws + ((size_t)42 << 20));   // 25.6 MB
    unsigned short* hb     = (unsigned short*)(ws + ((size_t)68 << 20));   // 25.6 MB
    unsigned short* hWlb   = (unsigned short*)(ws + ((size_t)94 << 20));   // 12.8 MB
    // bins alias aggb: dead before gather128 writes aggb (stream-ordered)
    unsigned* bins         = (unsigned*)(ws + ((size_t)42 << 20));         // 9.4 MB

    hipMemsetAsync(bincur, 0, 3 * SUBP * sizeof(int), stream);

    bin_kernel<<<dim3(ACH, 3), 256, 0, stream>>>(ei0, ei1, ei2, bins, bincur);
    count_kernel<<<dim3(SUBP, 3), 256, 0, stream>>>(bins, bincur, cnt);
    scan1_kernel<<<dim3(NCHUNK, 3), 1024, 0, stream>>>(cnt, rowstart, blocksum);
    scan2_kernel<<<1, 128, 0, stream>>>(blocksum);
    scan3_kernel<<<dim3(392, 3), 256, 0, stream>>>(rowstart, blocksum);
    fill_kernel<<<dim3(SUBP, 3), 256, 0, stream>>>(bins, bincur, rowstart, adj);
    wprep_kernel<<<448, 256, 0, stream>>>(Wl, Wr, Wl_f, Wr_f, Wfrag, Wfrag2);
    xcast_kernel<<<(N_NODES * 128 / 8) / 256, 256, 0, stream>>>(x, xb);

    const int GATHER_BLOCKS = (N_NODES + 15) / 16;   // 4 waves/block x 4 nodes/wave
    const int TILE_BLOCKS = (N_NODES + 63) / 64;     // 1563
    for (int r = 0; r < 3; r++) {
        gather128_kernel<<<GATHER_BLOCKS, 256, 0, stream>>>(
            xb, adj + (size_t)r * N_EDGES, rowstart + r * N_NODES, cnt + r * N_NODES, aggb);
        layer1_kernel<<<TILE_BLOCKS, 256, 0, stream>>>(
            aggb, xb, Wfrag + (size_t)r * 32768, bl + r * 128, hb, r == 0 ? 1 : 0);
    }

    layer2_kernel<<<TILE_BLOCKS, 256, 0, stream>>>(hb, Wfrag2, bl_f, hWlb, out);
    gather64_kernel<<<GATHER_BLOCKS, 256, 0, stream>>>(hWlb, adj, rowstart, cnt, out);
}

// Round 8
// 322.845 us; speedup vs baseline: 1.7220x; 1.1584x over previous
//
#include <hip/hip_runtime.h>

#define N_NODES 100000
#define N_EDGES 600000
#define NCHUNK 98            // ceil(100000/1024)
#define LDS_STRIDE 136       // ushorts per row: 128 + 8 pad
#define SUBP 128             // dst sub-partitions
#define SUB_SZ 782           // nodes per sub-partition (128*782 = 100096 >= 100000)
#define ECHUNK 2048          // edges per bin_kernel block
#define ACH 293              // ceil(600000/2048)
#define BCAP 6144            // per (rel,subpart) bin capacity (mean 4687, +21 sigma)

typedef __attribute__((ext_vector_type(8))) short short8;
typedef __attribute__((ext_vector_type(4))) float f32x4;
typedef __attribute__((ext_vector_type(4))) unsigned short ushort4v;
typedef __attribute__((ext_vector_type(8))) unsigned short ushort8v;

__device__ __forceinline__ unsigned short f2b(float f) {   // fp32 -> bf16 RNE
    unsigned u = __builtin_bit_cast(unsigned, f);
    return (unsigned short)((u + 0x7fffu + ((u >> 16) & 1u)) >> 16);
}
__device__ __forceinline__ float b2f(unsigned short b) {
    return __builtin_bit_cast(float, (unsigned)b << 16);
}

// ---------------------------------------------------------------------------
// Pass A: 128-way counting sort of edges by dst sub-partition. Edge packed
// into 4B: src (17b) | local-dst (10b, <782). LDS-staged compaction ->
// line-granular global writes into per-(rel,subpart) bins.
__global__ __launch_bounds__(256) void bin_kernel(const int* __restrict__ e0,
                                                  const int* __restrict__ e1,
                                                  const int* __restrict__ e2,
                                                  unsigned* __restrict__ bins,
                                                  int* __restrict__ bincur) {
    int r = blockIdx.y;
    const int* ei = (r == 0) ? e0 : (r == 1 ? e1 : e2);
    int base = blockIdx.x * ECHUNK;
    int nhere = min(ECHUNK, N_EDGES - base);
    __shared__ int lhist[SUBP], lstart[SUBP], lcur[SUBP], gbase[SUBP];
    __shared__ unsigned led[ECHUNK];
    __shared__ unsigned char lbkt[ECHUNK];
    int tid = threadIdx.x;
    for (int i = tid; i < SUBP; i += 256) { lhist[i] = 0; lcur[i] = 0; }
    __syncthreads();

    unsigned pk[8]; int bn[8];
#pragma unroll
    for (int k = 0; k < 8; k++) {
        int i = tid + k * 256;
        bn[k] = -1;
        if (i < nhere) {
            int e = base + i;
            int s = ei[e], d = ei[N_EDGES + e];
            int b = d / SUB_SZ;
            int ld = d - b * SUB_SZ;
            pk[k] = (unsigned)s | ((unsigned)ld << 17);
            bn[k] = b;
            atomicAdd(&lhist[b], 1);
        }
    }
    __syncthreads();
    if (tid == 0) {
        int run = 0;
        for (int b = 0; b < SUBP; b++) { lstart[b] = run; run += lhist[b]; }
    }
    __syncthreads();
#pragma unroll
    for (int k = 0; k < 8; k++) {
        if (bn[k] >= 0) {
            int slot = atomicAdd(&lcur[bn[k]], 1);
            int p = lstart[bn[k]] + slot;
            led[p] = pk[k];
            lbkt[p] = (unsigned char)bn[k];
        }
    }
    if (tid < SUBP) gbase[tid] = atomicAdd(&bincur[r * SUBP + tid], lhist[tid]);
    __syncthreads();
    for (int i = tid; i < nhere; i += 256) {
        int b = lbkt[i];
        int dstidx = gbase[b] + (i - lstart[b]);
        if (dstidx < BCAP)   // safety clamp: drop (never fault) on overflow
            bins[(size_t)(r * SUBP + b) * BCAP + dstidx] = led[i];
    }
}

// ---------------------------------------------------------------------------
// Degree count: one block per (rel,subpart). LDS histogram, coalesced cnt out.
__global__ __launch_bounds__(256) void count_kernel(const unsigned* __restrict__ bins,
                                                    const int* __restrict__ bincur,
                                                    int* __restrict__ cnt) {
    int p = blockIdx.x, r = blockIdx.y;
    int n0 = p * SUB_SZ;
    int nodes = min(SUB_SZ, N_NODES - n0);
    __shared__ int hist[SUB_SZ];
    int tid = threadIdx.x;
    for (int i = tid; i < SUB_SZ; i += 256) hist[i] = 0;
    __syncthreads();
    int len = min(bincur[r * SUBP + p], BCAP);
    const unsigned* b = bins + (size_t)(r * SUBP + p) * BCAP;
    for (int i = tid; i < len; i += 256) atomicAdd(&hist[b[i] >> 17], 1);
    __syncthreads();
    for (int i = tid; i < nodes; i += 256) cnt[r * N_NODES + n0 + i] = hist[i];
}

// ---------------------------------------------------------------------------
__global__ __launch_bounds__(1024) void scan1_kernel(const int* __restrict__ cnt,
                                                     int* __restrict__ rowstart,
                                                     int* __restrict__ blocksum) {
    int r = blockIdx.y;
    int tid = threadIdx.x, lane = tid & 63, wid = tid >> 6;
    int i = blockIdx.x * 1024 + tid;
    __shared__ int wsum[16];
    int v = (i < N_NODES) ? cnt[r * N_NODES + i] : 0;
    int incl = v;
#pragma unroll
    for (int off = 1; off < 64; off <<= 1) {
        int t = __shfl_up(incl, off);
        if (lane >= off) incl += t;
    }
    if (lane == 63) wsum[wid] = incl;
    __syncthreads();
    if (wid == 0) {
        int wv = (lane < 16) ? wsum[lane] : 0;
#pragma unroll
        for (int off = 1; off < 16; off <<= 1) {
            int t = __shfl_up(wv, off);
            if (lane >= off) wv += t;
        }
        if (lane < 16) wsum[lane] = wv;
    }
    __syncthreads();
    int woff = (wid > 0) ? wsum[wid - 1] : 0;
    if (i < N_NODES) rowstart[r * N_NODES + i] = woff + incl - v;
    if (tid == 0) blocksum[r * NCHUNK + blockIdx.x] = wsum[15];
}

__global__ __launch_bounds__(128) void scan2_kernel(int* __restrict__ blocksum) {
    __shared__ int s[3 * NCHUNK];
    int tid = threadIdx.x;
    for (int i = tid; i < 3 * NCHUNK; i += 128) s[i] = blocksum[i];
    __syncthreads();
    if (tid < 3) {
        int run = 0;
        for (int j = 0; j < NCHUNK; j++) { int t = s[tid * NCHUNK + j]; s[tid * NCHUNK + j] = run; run += t; }
    }
    __syncthreads();
    for (int i = tid; i < 3 * NCHUNK; i += 128) blocksum[i] = s[i];
}

__global__ void scan3_kernel(int* __restrict__ rowstart, const int* __restrict__ blocksum) {
    int r = blockIdx.y;
    int i = blockIdx.x * 256 + threadIdx.x;
    if (i < N_NODES)
        rowstart[r * N_NODES + i] += blocksum[r * NCHUNK + (i >> 10)];
}

// ---------------------------------------------------------------------------
// CSR fill: one block per (rel,subpart). Local cursor + adj slice staged in
// LDS (LDS atomics only), then streamed out with coalesced sequential stores.
__global__ __launch_bounds__(256) void fill_kernel(const unsigned* __restrict__ bins,
                                                   const int* __restrict__ bincur,
                                                   const int* __restrict__ rowstart,
                                                   int* __restrict__ adj) {
    int p = blockIdx.x, r = blockIdx.y;
    int n0 = p * SUB_SZ;
    int nodes = min(SUB_SZ, N_NODES - n0);
    __shared__ int lcur[SUB_SZ];
    __shared__ int sstage[BCAP];
    int tid = threadIdx.x;
    const int* rs = rowstart + r * N_NODES + n0;
    int rbase = rs[0];
    for (int i = tid; i < nodes; i += 256) lcur[i] = rs[i] - rbase;
    __syncthreads();
    int len = min(bincur[r * SUBP + p], BCAP);
    const unsigned* b = bins + (size_t)(r * SUBP + p) * BCAP;
    for (int i = tid; i < len; i += 256) {
        unsigned v = b[i];
        int pos = atomicAdd(&lcur[v >> 17], 1);
        if (pos < BCAP)   // safety clamp (cannot trigger with consistent counts)
            sstage[pos] = (int)(v & 0x1FFFFu);
    }
    __syncthreads();
    int* a = adj + (size_t)r * N_EDGES + rbase;
    for (int i = tid; i < len; i += 256) a[i] = sstage[i];
}

// ---------------------------------------------------------------------------
// x (fp32) -> xb (bf16), 8 elems/thread.
__global__ void xcast_kernel(const float* __restrict__ x, unsigned short* __restrict__ xb) {
    int idx = blockIdx.x * 256 + threadIdx.x;
    const float4* p = (const float4*)x + (size_t)idx * 2;
    float4 a = p[0], b = p[1];
    ushort8v o;
    o[0] = f2b(a.x); o[1] = f2b(a.y); o[2] = f2b(a.z); o[3] = f2b(a.w);
    o[4] = f2b(b.x); o[5] = f2b(b.y); o[6] = f2b(b.z); o[7] = f2b(b.w);
    *(ushort8v*)(xb + (size_t)idx * 8) = o;
}

// ---------------------------------------------------------------------------
// Pre-swizzle weights into MFMA B-fragment order.
__global__ void wprep_kernel(const float* __restrict__ Wl, const float* __restrict__ Wr,
                             const float* __restrict__ Wl_f, const float* __restrict__ Wr_f,
                             unsigned short* __restrict__ Wfrag, unsigned short* __restrict__ Wfrag2) {
    int idx = blockIdx.x * 256 + threadIdx.x;      // 448 blocks = 114688 threads
    int j = idx & 7, lane = (idx >> 3) & 63;
    int quad = lane >> 4, l16 = lane & 15;
    if (idx < 98304) {
        int t = (idx >> 9) & 1, s = (idx >> 10) & 7, w = (idx >> 13) & 3, r = idx >> 15;
        int k = s * 32 + quad * 8 + j;
        int n = w * 32 + t * 16 + l16;
        float v = (k < 128) ? Wl[((size_t)r * 128 + k) * 128 + n]
                            : Wr[((size_t)r * 128 + (k - 128)) * 128 + n];
        Wfrag[idx] = f2b(v);
    } else {
        int i2 = idx - 98304;
        if (i2 < 16384) {
            int t = (i2 >> 9) & 1, s = (i2 >> 10) & 3, w = (i2 >> 12) & 3;
            int k = s * 32 + quad * 8 + j;
            int n = w * 32 + t * 16 + l16;
            float v = (n < 64) ? Wl_f[(size_t)k * 64 + n] : Wr_f[(size_t)k * 64 + (n - 64)];
            Wfrag2[i2] = f2b(v);
        }
    }
}

// ---------------------------------------------------------------------------
// FUSED layer-1: per block of 64 nodes, stage x rows once; for each relation
// gather agg rows straight into LDS (4-nodes-per-wave slot structure, 16
// lanes cover a 256B row -> lane-private accumulation, no cross-lane reduce),
// then MFMA [agg|x] @ W, accumulating relu(.+bl)/3 in fp32 regs. hb written
// once (no bf16 RMW), aggb buffer eliminated, 6 launches -> 1.
__global__ __launch_bounds__(256, 4) void fused1_kernel(
    const unsigned short* __restrict__ xb, const int* __restrict__ adj,
    const int* __restrict__ rowstart, const int* __restrict__ cnt,
    const unsigned short* __restrict__ Wfrag, const float* __restrict__ bl,
    unsigned short* __restrict__ hb) {
    __shared__ unsigned short s_x[64 * LDS_STRIDE];
    __shared__ unsigned short s_a[64 * LDS_STRIDE];
    int tid = threadIdx.x, wave = tid >> 6, lane = tid & 63;
    int quad = lane >> 4, l16 = lane & 15;       // quad==slot id, l16==chan lane
    int rowbase = blockIdx.x * 64;

    // stage x rows (once for all 3 relations)
#pragma unroll
    for (int it = 0; it < 4; it++) {
        int idx = tid + it * 256;
        int row = idx >> 4, c = idx & 15;
        int grow = rowbase + row;
        short8 xv = {0, 0, 0, 0, 0, 0, 0, 0};
        if (grow < N_NODES) xv = *(const short8*)(xb + (size_t)grow * 128 + c * 8);
        *(short8*)&s_x[row * LDS_STRIDE + c * 8] = xv;
    }

    f32x4 hsum[4][2];
#pragma unroll
    for (int g = 0; g < 4; g++) { hsum[g][0] = (f32x4){0.f,0.f,0.f,0.f}; hsum[g][1] = (f32x4){0.f,0.f,0.f,0.f}; }

    for (int r = 0; r < 3; r++) {
        const int* rs = rowstart + r * N_NODES;
        const int* ct = cnt + r * N_NODES;
        const int* aj = adj + (size_t)r * N_EDGES;

        // gather this relation's agg rows for 16 nodes/wave into s_a
        for (int g4 = 0; g4 < 4; g4++) {
            int nl = wave * 16 + g4 * 4 + quad;      // local row [0,64)
            int node = rowbase + nl;
            bool valid = node < N_NODES;
            int start = 0, deg = 0;
            if (valid) { start = rs[node]; deg = ct[node]; }
            int jcap = min(deg, 16);
            int myidx = (valid && l16 < jcap) ? aj[start + l16] : 0;  // 16-idx prefetch
            int dmax = jcap;
            dmax = max(dmax, __shfl_xor(dmax, 16));
            dmax = max(dmax, __shfl_xor(dmax, 32));
            float ac[8];
#pragma unroll
            for (int k = 0; k < 8; k++) ac[k] = 0.f;
            int sb = quad * 16;
            for (int j = 0; j < dmax; j += 2) {
                int s0 = __shfl(myidx, sb + j);
                int s1 = __shfl(myidx, sb + min(j + 1, 15));
                bool a0 = j < jcap, a1 = (j + 1) < jcap;
                ushort8v v0, v1;
                if (a0) v0 = *(const ushort8v*)(xb + (size_t)s0 * 128 + l16 * 8);
                if (a1) v1 = *(const ushort8v*)(xb + (size_t)s1 * 128 + l16 * 8);
                if (a0) {
#pragma unroll
                    for (int k = 0; k < 8; k++) ac[k] += b2f(v0[k]);
                }
                if (a1) {
#pragma unroll
                    for (int k = 0; k < 8; k++) ac[k] += b2f(v1[k]);
                }
            }
            for (int j = 16; j < deg; j++) {         // rare deg>16 tail
                int s = aj[start + j];
                ushort8v v = *(const ushort8v*)(xb + (size_t)s * 128 + l16 * 8);
#pragma unroll
                for (int k = 0; k < 8; k++) ac[k] += b2f(v[k]);
            }
            float inv = 1.0f / fmaxf((float)deg, 1.0f);
            ushort8v o;
#pragma unroll
            for (int k = 0; k < 8; k++) o[k] = f2b(ac[k] * inv);   // invalid -> zeros
            *(ushort8v*)&s_a[nl * LDS_STRIDE + l16 * 8] = o;
        }
        __syncthreads();

        f32x4 acc[4][2];
#pragma unroll
        for (int g = 0; g < 4; g++) { acc[g][0] = (f32x4){0.f,0.f,0.f,0.f}; acc[g][1] = (f32x4){0.f,0.f,0.f,0.f}; }

        const unsigned short* W = Wfrag + r * 32768 + wave * 8192;
#pragma unroll
        for (int s = 0; s < 8; s++) {
            short8 bf0 = *(const short8*)(W + s * 1024 + lane * 8);
            short8 bf1 = *(const short8*)(W + s * 1024 + 512 + lane * 8);
            const unsigned short* src = (s < 4) ? s_a : s_x;
            int ko = (s & 3) * 32 + quad * 8;
#pragma unroll
            for (int g = 0; g < 4; g++) {
                short8 af = *(const short8*)&src[(g * 16 + l16) * LDS_STRIDE + ko];
                acc[g][0] = __builtin_amdgcn_mfma_f32_16x16x32_bf16(af, bf0, acc[g][0], 0, 0, 0);
                acc[g][1] = __builtin_amdgcn_mfma_f32_16x16x32_bf16(af, bf1, acc[g][1], 0, 0, 0);
            }
        }

        float b0 = bl[r * 128 + wave * 32 + l16];
        float b1 = bl[r * 128 + wave * 32 + 16 + l16];
#pragma unroll
        for (int g = 0; g < 4; g++)
#pragma unroll
            for (int t = 0; t < 2; t++) {
                float bb = t ? b1 : b0;
#pragma unroll
                for (int q = 0; q < 4; q++)
                    hsum[g][t][q] += fmaxf(acc[g][t][q] + bb, 0.f) * (1.0f / 3.0f);
            }
        __syncthreads();   // before next relation's gather overwrites s_a
    }

    // single hb write (fp32-accumulated, one bf16 round)
#pragma unroll
    for (int g = 0; g < 4; g++)
#pragma unroll
        for (int t = 0; t < 2; t++) {
            int col = wave * 32 + t * 16 + l16;
#pragma unroll
            for (int q = 0; q < 4; q++) {
                int row = rowbase + g * 16 + quad * 4 + q;
                if (row < N_NODES)
                    hb[(size_t)row * 128 + col] = f2b(hsum[g][t][q]);
            }
        }
}

// ---------------------------------------------------------------------------
// Layer-2: [hWl|hWr] = h @ Wf2 (K=128); hWl -> bf16 buffer, out = hWr + bl_f.
__global__ __launch_bounds__(256, 4) void layer2_kernel(
    const unsigned short* __restrict__ hb, const unsigned short* __restrict__ Wfrag2,
    const float* __restrict__ bl_f, unsigned short* __restrict__ hWlb,
    float* __restrict__ out) {
    __shared__ unsigned short s_h[64 * LDS_STRIDE];
    int tid = threadIdx.x, wave = tid >> 6, lane = tid & 63;
    int quad = lane >> 4, l16 = lane & 15;
    int rowbase = blockIdx.x * 64;

#pragma unroll
    for (int it = 0; it < 4; it++) {
        int idx = tid + it * 256;
        int row = idx >> 4, c = idx & 15;
        int grow = rowbase + row;
        short8 hv = {0, 0, 0, 0, 0, 0, 0, 0};
        if (grow < N_NODES) hv = *(const short8*)(hb + (size_t)grow * 128 + c * 8);
        *(short8*)&s_h[row * LDS_STRIDE + c * 8] = hv;
    }
    __syncthreads();

    f32x4 acc[4][2];
#pragma unroll
    for (int g = 0; g < 4; g++) { acc[g][0] = (f32x4){0.f,0.f,0.f,0.f}; acc[g][1] = (f32x4){0.f,0.f,0.f,0.f}; }

    const unsigned short* W = Wfrag2 + wave * 4096;
#pragma unroll
    for (int s = 0; s < 4; s++) {
        short8 bf0 = *(const short8*)(W + s * 1024 + lane * 8);
        short8 bf1 = *(const short8*)(W + s * 1024 + 512 + lane * 8);
        int ko = s * 32 + quad * 8;
#pragma unroll
        for (int g = 0; g < 4; g++) {
            short8 af = *(const short8*)&s_h[(g * 16 + l16) * LDS_STRIDE + ko];
            acc[g][0] = __builtin_amdgcn_mfma_f32_16x16x32_bf16(af, bf0, acc[g][0], 0, 0, 0);
            acc[g][1] = __builtin_amdgcn_mfma_f32_16x16x32_bf16(af, bf1, acc[g][1], 0, 0, 0);
        }
    }

#pragma unroll
    for (int g = 0; g < 4; g++)
#pragma unroll
        for (int t = 0; t < 2; t++) {
            int col = wave * 32 + t * 16 + l16;
#pragma unroll
            for (int q = 0; q < 4; q++) {
                int row = rowbase + g * 16 + quad * 4 + q;
                if (row < N_NODES) {
                    if (col < 64) hWlb[(size_t)row * 64 + col] = f2b(acc[g][t][q]);
                    else out[(size_t)row * 64 + (col - 64)] = acc[g][t][q] + bl_f[col - 64];
                }
            }
        }
}

// ---------------------------------------------------------------------------
// Gather-mean of hWl (bf16, 64 ch = 128 B row = 16 x ushort4) + add into out.
// 4-nodes-per-wave slot structure; no cross-lane reduce.
__global__ void gather64_kernel(const unsigned short* __restrict__ hWlb, const int* __restrict__ adj,
                                const int* __restrict__ rowstart, const int* __restrict__ cnt,
                                float* __restrict__ out) {
    int wv = (blockIdx.x * blockDim.x + threadIdx.x) >> 6;
    int lane = threadIdx.x & 63;
    int nb = lane >> 4, c16 = lane & 15;
    int node = wv * 4 + nb;
    bool valid = node < N_NODES;
    int start = 0, deg = 0;
    if (valid) { start = rowstart[node]; deg = cnt[node]; }
    int jcap = min(deg, 16);
    int myidx = (valid && c16 < jcap) ? adj[start + c16] : 0;
    int dmax = jcap;
    dmax = max(dmax, __shfl_xor(dmax, 16));
    dmax = max(dmax, __shfl_xor(dmax, 32));
    float a0 = 0.f, a1 = 0.f, a2 = 0.f, a3 = 0.f;
    int sb = nb * 16;
    for (int j = 0; j < dmax; j += 2) {
        int s0 = __shfl(myidx, sb + j);
        int s1 = __shfl(myidx, sb + min(j + 1, 15));
        bool c0 = j < jcap, c1 = (j + 1) < jcap;
        ushort4v v0, v1;
        if (c0) v0 = *(const ushort4v*)(hWlb + (size_t)s0 * 64 + c16 * 4);
        if (c1) v1 = *(const ushort4v*)(hWlb + (size_t)s1 * 64 + c16 * 4);
        if (c0) { a0 += b2f(v0.x); a1 += b2f(v0.y); a2 += b2f(v0.z); a3 += b2f(v0.w); }
        if (c1) { a0 += b2f(v1.x); a1 += b2f(v1.y); a2 += b2f(v1.z); a3 += b2f(v1.w); }
    }
    for (int j = 16; j < deg; j++) {        // rare deg>16 tail
        int s = adj[start + j];
        ushort4v v = *(const ushort4v*)(hWlb + (size_t)s * 64 + c16 * 4);
        a0 += b2f(v.x); a1 += b2f(v.y); a2 += b2f(v.z); a3 += b2f(v.w);
    }
    if (valid) {
        float inv = 1.0f / fmaxf((float)deg, 1.0f);
        float4* o = (float4*)(out + (size_t)node * 64 + c16 * 4);
        float4 cur = *o;
        cur.x += a0 * inv; cur.y += a1 * inv; cur.z += a2 * inv; cur.w += a3 * inv;
        *o = cur;
    }
}

// ---------------------------------------------------------------------------
extern "C" void kernel_launch(void* const* d_in, const int* in_sizes, int n_in,
                              void* d_out, int out_size, void* d_ws, size_t ws_size,
                              hipStream_t stream) {
    const float* x    = (const float*)d_in[0];
    const float* Wl   = (const float*)d_in[1];
    const float* bl   = (const float*)d_in[2];
    const float* Wr   = (const float*)d_in[3];
    const float* Wl_f = (const float*)d_in[4];
    const float* bl_f = (const float*)d_in[5];
    const float* Wr_f = (const float*)d_in[6];
    const int* ei0 = (const int*)d_in[7];
    const int* ei1 = (const int*)d_in[8];
    const int* ei2 = (const int*)d_in[9];
    float* out = (float*)d_out;

    // workspace layout (offsets), total ~107 MB
    char* ws = (char*)d_ws;
    int* cnt               = (int*)(ws);                                   // 1.2 MB
    int* bincur            = (int*)(ws + 0x128000);                        // 1.5 KB
    int* rowstart          = (int*)(ws + ((size_t)4  << 20));              // 1.2 MB
    int* blocksum          = (int*)(ws + ((size_t)6  << 20));              // 1.2 KB
    unsigned short* Wfrag  = (unsigned short*)(ws + ((size_t)7  << 20));   // 192 KB
    unsigned short* Wfrag2 = (unsigned short*)(ws + ((size_t)15 << 19));   // 7.5MB, 32 KB
    int* adj               = (int*)(ws + ((size_t)8  << 20));              // 7.2 MB
    unsigned short* xb     = (unsigned short*)(ws + ((size_t)16 << 20));   // 25.6 MB
    unsigned short* hb     = (unsigned short*)(ws + ((size_t)68 << 20));   // 25.6 MB
    unsigned short* hWlb   = (unsigned short*)(ws + ((size_t)94 << 20));   // 12.8 MB
    unsigned* bins         = (unsigned*)(ws + ((size_t)42 << 20));         // 9.4 MB

    hipMemsetAsync(bincur, 0, 3 * SUBP * sizeof(int), stream);

    bin_kernel<<<dim3(ACH, 3), 256, 0, stream>>>(ei0, ei1, ei2, bins, bincur);
    count_kernel<<<dim3(SUBP, 3), 256, 0, stream>>>(bins, bincur, cnt);
    scan1_kernel<<<dim3(NCHUNK, 3), 1024, 0, stream>>>(cnt, rowstart, blocksum);
    scan2_kernel<<<1, 128, 0, stream>>>(blocksum);
    scan3_kernel<<<dim3(392, 3), 256, 0, stream>>>(rowstart, blocksum);
    fill_kernel<<<dim3(SUBP, 3), 256, 0, stream>>>(bins, bincur, rowstart, adj);
    wprep_kernel<<<448, 256, 0, stream>>>(Wl, Wr, Wl_f, Wr_f, Wfrag, Wfrag2);
    xcast_kernel<<<(N_NODES * 128 / 8) / 256, 256, 0, stream>>>(x, xb);

    const int TILE_BLOCKS = (N_NODES + 63) / 64;     // 1563
    fused1_kernel<<<TILE_BLOCKS, 256, 0, stream>>>(xb, adj, rowstart, cnt, Wfrag, bl, hb);
    layer2_kernel<<<TILE_BLOCKS, 256, 0, stream>>>(hb, Wfrag2, bl_f, hWlb, out);

    const int GATHER_BLOCKS = (N_NODES + 15) / 16;   // 4 waves/block x 4 nodes/wave
    gather64_kernel<<<GATHER_BLOCKS, 256, 0, stream>>>(hWlb, adj, rowstart, cnt, out);
}

// Round 9
// 320.848 us; speedup vs baseline: 1.7327x; 1.0062x over previous
//
#include <hip/hip_runtime.h>

#define N_NODES 100000
#define N_EDGES 600000
#define NCHUNK 98            // ceil(100000/1024)
#define LDS_STRIDE 136       // ushorts per row: 128 + 8 pad
#define SUBP 128             // dst sub-partitions
#define SUB_SZ 782           // nodes per sub-partition (128*782 = 100096 >= 100000)
#define ECHUNK 2048          // edges per bin_kernel block
#define ACH 293              // ceil(600000/2048)
#define BCAP 6144            // per (rel,subpart) bin capacity (mean 4687, +21 sigma)

typedef __attribute__((ext_vector_type(8))) short short8;
typedef __attribute__((ext_vector_type(4))) float f32x4;
typedef __attribute__((ext_vector_type(4))) unsigned short ushort4v;
typedef __attribute__((ext_vector_type(8))) unsigned short ushort8v;

__device__ __forceinline__ unsigned short f2b(float f) {   // fp32 -> bf16 RNE
    unsigned u = __builtin_bit_cast(unsigned, f);
    return (unsigned short)((u + 0x7fffu + ((u >> 16) & 1u)) >> 16);
}
__device__ __forceinline__ float b2f(unsigned short b) {
    return __builtin_bit_cast(float, (unsigned)b << 16);
}

// ---------------------------------------------------------------------------
// Pass A: 128-way counting sort of edges by dst sub-partition. Edge packed
// into 4B: src (17b) | local-dst (10b, <782). LDS-staged compaction ->
// line-granular global writes into per-(rel,subpart) bins.
__global__ __launch_bounds__(256) void bin_kernel(const int* __restrict__ e0,
                                                  const int* __restrict__ e1,
                                                  const int* __restrict__ e2,
                                                  unsigned* __restrict__ bins,
                                                  int* __restrict__ bincur) {
    int r = blockIdx.y;
    const int* ei = (r == 0) ? e0 : (r == 1 ? e1 : e2);
    int base = blockIdx.x * ECHUNK;
    int nhere = min(ECHUNK, N_EDGES - base);
    __shared__ int lhist[SUBP], lstart[SUBP], lcur[SUBP], gbase[SUBP];
    __shared__ unsigned led[ECHUNK];
    __shared__ unsigned char lbkt[ECHUNK];
    int tid = threadIdx.x;
    for (int i = tid; i < SUBP; i += 256) { lhist[i] = 0; lcur[i] = 0; }
    __syncthreads();

    unsigned pk[8]; int bn[8];
#pragma unroll
    for (int k = 0; k < 8; k++) {
        int i = tid + k * 256;
        bn[k] = -1;
        if (i < nhere) {
            int e = base + i;
            int s = ei[e], d = ei[N_EDGES + e];
            int b = d / SUB_SZ;
            int ld = d - b * SUB_SZ;
            pk[k] = (unsigned)s | ((unsigned)ld << 17);
            bn[k] = b;
            atomicAdd(&lhist[b], 1);
        }
    }
    __syncthreads();
    if (tid == 0) {
        int run = 0;
        for (int b = 0; b < SUBP; b++) { lstart[b] = run; run += lhist[b]; }
    }
    __syncthreads();
#pragma unroll
    for (int k = 0; k < 8; k++) {
        if (bn[k] >= 0) {
            int slot = atomicAdd(&lcur[bn[k]], 1);
            int p = lstart[bn[k]] + slot;
            led[p] = pk[k];
            lbkt[p] = (unsigned char)bn[k];
        }
    }
    if (tid < SUBP) gbase[tid] = atomicAdd(&bincur[r * SUBP + tid], lhist[tid]);
    __syncthreads();
    for (int i = tid; i < nhere; i += 256) {
        int b = lbkt[i];
        int dstidx = gbase[b] + (i - lstart[b]);
        if (dstidx < BCAP)   // safety clamp: drop (never fault) on overflow
            bins[(size_t)(r * SUBP + b) * BCAP + dstidx] = led[i];
    }
}

// ---------------------------------------------------------------------------
// Degree count: one block per (rel,subpart). LDS histogram, coalesced cnt out.
__global__ __launch_bounds__(256) void count_kernel(const unsigned* __restrict__ bins,
                                                    const int* __restrict__ bincur,
                                                    int* __restrict__ cnt) {
    int p = blockIdx.x, r = blockIdx.y;
    int n0 = p * SUB_SZ;
    int nodes = min(SUB_SZ, N_NODES - n0);
    __shared__ int hist[SUB_SZ];
    int tid = threadIdx.x;
    for (int i = tid; i < SUB_SZ; i += 256) hist[i] = 0;
    __syncthreads();
    int len = min(bincur[r * SUBP + p], BCAP);
    const unsigned* b = bins + (size_t)(r * SUBP + p) * BCAP;
    for (int i = tid; i < len; i += 256) atomicAdd(&hist[b[i] >> 17], 1);
    __syncthreads();
    for (int i = tid; i < nodes; i += 256) cnt[r * N_NODES + n0 + i] = hist[i];
}

// ---------------------------------------------------------------------------
__global__ __launch_bounds__(1024) void scan1_kernel(const int* __restrict__ cnt,
                                                     int* __restrict__ rowstart,
                                                     int* __restrict__ blocksum) {
    int r = blockIdx.y;
    int tid = threadIdx.x, lane = tid & 63, wid = tid >> 6;
    int i = blockIdx.x * 1024 + tid;
    __shared__ int wsum[16];
    int v = (i < N_NODES) ? cnt[r * N_NODES + i] : 0;
    int incl = v;
#pragma unroll
    for (int off = 1; off < 64; off <<= 1) {
        int t = __shfl_up(incl, off);
        if (lane >= off) incl += t;
    }
    if (lane == 63) wsum[wid] = incl;
    __syncthreads();
    if (wid == 0) {
        int wv = (lane < 16) ? wsum[lane] : 0;
#pragma unroll
        for (int off = 1; off < 16; off <<= 1) {
            int t = __shfl_up(wv, off);
            if (lane >= off) wv += t;
        }
        if (lane < 16) wsum[lane] = wv;
    }
    __syncthreads();
    int woff = (wid > 0) ? wsum[wid - 1] : 0;
    if (i < N_NODES) rowstart[r * N_NODES + i] = woff + incl - v;
    if (tid == 0) blocksum[r * NCHUNK + blockIdx.x] = wsum[15];
}

__global__ __launch_bounds__(128) void scan2_kernel(int* __restrict__ blocksum) {
    __shared__ int s[3 * NCHUNK];
    int tid = threadIdx.x;
    for (int i = tid; i < 3 * NCHUNK; i += 128) s[i] = blocksum[i];
    __syncthreads();
    if (tid < 3) {
        int run = 0;
        for (int j = 0; j < NCHUNK; j++) { int t = s[tid * NCHUNK + j]; s[tid * NCHUNK + j] = run; run += t; }
    }
    __syncthreads();
    for (int i = tid; i < 3 * NCHUNK; i += 128) blocksum[i] = s[i];
}

__global__ void scan3_kernel(int* __restrict__ rowstart, const int* __restrict__ blocksum) {
    int r = blockIdx.y;
    int i = blockIdx.x * 256 + threadIdx.x;
    if (i < N_NODES)
        rowstart[r * N_NODES + i] += blocksum[r * NCHUNK + (i >> 10)];
}

// ---------------------------------------------------------------------------
// CSR fill: one block per (rel,subpart). Local cursor + adj slice staged in
// LDS (LDS atomics only), then streamed out with coalesced sequential stores.
__global__ __launch_bounds__(256) void fill_kernel(const unsigned* __restrict__ bins,
                                                   const int* __restrict__ bincur,
                                                   const int* __restrict__ rowstart,
                                                   int* __restrict__ adj) {
    int p = blockIdx.x, r = blockIdx.y;
    int n0 = p * SUB_SZ;
    int nodes = min(SUB_SZ, N_NODES - n0);
    __shared__ int lcur[SUB_SZ];
    __shared__ int sstage[BCAP];
    int tid = threadIdx.x;
    const int* rs = rowstart + r * N_NODES + n0;
    int rbase = rs[0];
    for (int i = tid; i < nodes; i += 256) lcur[i] = rs[i] - rbase;
    __syncthreads();
    int len = min(bincur[r * SUBP + p], BCAP);
    const unsigned* b = bins + (size_t)(r * SUBP + p) * BCAP;
    for (int i = tid; i < len; i += 256) {
        unsigned v = b[i];
        int pos = atomicAdd(&lcur[v >> 17], 1);
        if (pos < BCAP)   // safety clamp (cannot trigger with consistent counts)
            sstage[pos] = (int)(v & 0x1FFFFu);
    }
    __syncthreads();
    int* a = adj + (size_t)r * N_EDGES + rbase;
    for (int i = tid; i < len; i += 256) a[i] = sstage[i];
}

// ---------------------------------------------------------------------------
// x (fp32) -> xb (bf16), 8 elems/thread.
__global__ void xcast_kernel(const float* __restrict__ x, unsigned short* __restrict__ xb) {
    int idx = blockIdx.x * 256 + threadIdx.x;
    const float4* p = (const float4*)x + (size_t)idx * 2;
    float4 a = p[0], b = p[1];
    ushort8v o;
    o[0] = f2b(a.x); o[1] = f2b(a.y); o[2] = f2b(a.z); o[3] = f2b(a.w);
    o[4] = f2b(b.x); o[5] = f2b(b.y); o[6] = f2b(b.z); o[7] = f2b(b.w);
    *(ushort8v*)(xb + (size_t)idx * 8) = o;
}

// ---------------------------------------------------------------------------
// Pre-swizzle weights into MFMA B-fragment order.
__global__ void wprep_kernel(const float* __restrict__ Wl, const float* __restrict__ Wr,
                             const float* __restrict__ Wl_f, const float* __restrict__ Wr_f,
                             unsigned short* __restrict__ Wfrag, unsigned short* __restrict__ Wfrag2) {
    int idx = blockIdx.x * 256 + threadIdx.x;      // 448 blocks = 114688 threads
    int j = idx & 7, lane = (idx >> 3) & 63;
    int quad = lane >> 4, l16 = lane & 15;
    if (idx < 98304) {
        int t = (idx >> 9) & 1, s = (idx >> 10) & 7, w = (idx >> 13) & 3, r = idx >> 15;
        int k = s * 32 + quad * 8 + j;
        int n = w * 32 + t * 16 + l16;
        float v = (k < 128) ? Wl[((size_t)r * 128 + k) * 128 + n]
                            : Wr[((size_t)r * 128 + (k - 128)) * 128 + n];
        Wfrag[idx] = f2b(v);
    } else {
        int i2 = idx - 98304;
        if (i2 < 16384) {
            int t = (i2 >> 9) & 1, s = (i2 >> 10) & 3, w = (i2 >> 12) & 3;
            int k = s * 32 + quad * 8 + j;
            int n = w * 32 + t * 16 + l16;
            float v = (n < 64) ? Wl_f[(size_t)k * 64 + n] : Wr_f[(size_t)k * 64 + (n - 64)];
            Wfrag2[i2] = f2b(v);
        }
    }
}

// ---------------------------------------------------------------------------
// FUSED layer-1 with software-pipelined gather: per wave, the 4 gather
// rounds' rowstart/cnt loads issue together, the 4 index prefetches issue
// together, and ONE combined j-loop interleaves row loads of all 4 slots
// (up to 8 rows in flight) into ac[4][8]. Collapses 4 serial dependent
// chains into 1 chain with 4x MLP.
__global__ __launch_bounds__(256, 4) void fused1_kernel(
    const unsigned short* __restrict__ xb, const int* __restrict__ adj,
    const int* __restrict__ rowstart, const int* __restrict__ cnt,
    const unsigned short* __restrict__ Wfrag, const float* __restrict__ bl,
    unsigned short* __restrict__ hb) {
    __shared__ unsigned short s_x[64 * LDS_STRIDE];
    __shared__ unsigned short s_a[64 * LDS_STRIDE];
    int tid = threadIdx.x, wave = tid >> 6, lane = tid & 63;
    int quad = lane >> 4, l16 = lane & 15;       // quad==slot id, l16==chan lane
    int rowbase = blockIdx.x * 64;

    // stage x rows (once for all 3 relations)
#pragma unroll
    for (int it = 0; it < 4; it++) {
        int idx = tid + it * 256;
        int row = idx >> 4, c = idx & 15;
        int grow = rowbase + row;
        short8 xv = {0, 0, 0, 0, 0, 0, 0, 0};
        if (grow < N_NODES) xv = *(const short8*)(xb + (size_t)grow * 128 + c * 8);
        *(short8*)&s_x[row * LDS_STRIDE + c * 8] = xv;
    }

    f32x4 hsum[4][2];
#pragma unroll
    for (int g = 0; g < 4; g++) { hsum[g][0] = (f32x4){0.f,0.f,0.f,0.f}; hsum[g][1] = (f32x4){0.f,0.f,0.f,0.f}; }

    for (int r = 0; r < 3; r++) {
        const int* rs = rowstart + r * N_NODES;
        const int* ct = cnt + r * N_NODES;
        const int* aj = adj + (size_t)r * N_EDGES;

        // phase 1: all 4 rounds' rowstart/cnt loads (independent)
        int startv[4], degv[4], jcapv[4], idxv[4];
#pragma unroll
        for (int g4 = 0; g4 < 4; g4++) {
            int node = rowbase + wave * 16 + g4 * 4 + quad;
            bool valid = node < N_NODES;
            startv[g4] = valid ? rs[node] : 0;
            degv[g4]   = valid ? ct[node] : 0;
        }
        // phase 2: all 4 rounds' 16-index prefetches (independent)
#pragma unroll
        for (int g4 = 0; g4 < 4; g4++) {
            jcapv[g4] = min(degv[g4], 16);
            idxv[g4] = (l16 < jcapv[g4]) ? aj[startv[g4] + l16] : 0;
        }
        // wave-wide max rounds
        int m = max(max(jcapv[0], jcapv[1]), max(jcapv[2], jcapv[3]));
        m = max(m, __shfl_xor(m, 16));
        m = max(m, __shfl_xor(m, 32));

        float ac[4][8];
#pragma unroll
        for (int g4 = 0; g4 < 4; g4++)
#pragma unroll
            for (int k = 0; k < 8; k++) ac[g4][k] = 0.f;

        int sb = quad * 16;
        // phase 3: combined j-loop, 8 row loads in flight across 4 slots
        for (int j = 0; j < m; j += 2) {
#pragma unroll
            for (int g4 = 0; g4 < 4; g4++) {
                int s0 = __shfl(idxv[g4], sb + j);
                int s1 = __shfl(idxv[g4], sb + min(j + 1, 15));
                bool a0 = j < jcapv[g4], a1 = (j + 1) < jcapv[g4];
                ushort8v v0, v1;
                if (a0) v0 = *(const ushort8v*)(xb + (size_t)s0 * 128 + l16 * 8);
                if (a1) v1 = *(const ushort8v*)(xb + (size_t)s1 * 128 + l16 * 8);
                if (a0) {
#pragma unroll
                    for (int k = 0; k < 8; k++) ac[g4][k] += b2f(v0[k]);
                }
                if (a1) {
#pragma unroll
                    for (int k = 0; k < 8; k++) ac[g4][k] += b2f(v1[k]);
                }
            }
        }
        // rare deg>16 tails
#pragma unroll
        for (int g4 = 0; g4 < 4; g4++) {
            for (int j = 16; j < degv[g4]; j++) {
                int s = aj[startv[g4] + j];
                ushort8v v = *(const ushort8v*)(xb + (size_t)s * 128 + l16 * 8);
#pragma unroll
                for (int k = 0; k < 8; k++) ac[g4][k] += b2f(v[k]);
            }
        }
        // write all 4 agg rows to LDS
#pragma unroll
        for (int g4 = 0; g4 < 4; g4++) {
            int nl = wave * 16 + g4 * 4 + quad;
            float inv = 1.0f / fmaxf((float)degv[g4], 1.0f);
            ushort8v o;
#pragma unroll
            for (int k = 0; k < 8; k++) o[k] = f2b(ac[g4][k] * inv);
            *(ushort8v*)&s_a[nl * LDS_STRIDE + l16 * 8] = o;
        }
        __syncthreads();

        f32x4 acc[4][2];
#pragma unroll
        for (int g = 0; g < 4; g++) { acc[g][0] = (f32x4){0.f,0.f,0.f,0.f}; acc[g][1] = (f32x4){0.f,0.f,0.f,0.f}; }

        const unsigned short* W = Wfrag + r * 32768 + wave * 8192;
#pragma unroll
        for (int s = 0; s < 8; s++) {
            short8 bf0 = *(const short8*)(W + s * 1024 + lane * 8);
            short8 bf1 = *(const short8*)(W + s * 1024 + 512 + lane * 8);
            const unsigned short* src = (s < 4) ? s_a : s_x;
            int ko = (s & 3) * 32 + quad * 8;
#pragma unroll
            for (int g = 0; g < 4; g++) {
                short8 af = *(const short8*)&src[(g * 16 + l16) * LDS_STRIDE + ko];
                acc[g][0] = __builtin_amdgcn_mfma_f32_16x16x32_bf16(af, bf0, acc[g][0], 0, 0, 0);
                acc[g][1] = __builtin_amdgcn_mfma_f32_16x16x32_bf16(af, bf1, acc[g][1], 0, 0, 0);
            }
        }

        float b0 = bl[r * 128 + wave * 32 + l16];
        float b1 = bl[r * 128 + wave * 32 + 16 + l16];
#pragma unroll
        for (int g = 0; g < 4; g++)
#pragma unroll
            for (int t = 0; t < 2; t++) {
                float bb = t ? b1 : b0;
#pragma unroll
                for (int q = 0; q < 4; q++)
                    hsum[g][t][q] += fmaxf(acc[g][t][q] + bb, 0.f) * (1.0f / 3.0f);
            }
        __syncthreads();   // before next relation's gather overwrites s_a
    }

    // single hb write (fp32-accumulated, one bf16 round)
#pragma unroll
    for (int g = 0; g < 4; g++)
#pragma unroll
        for (int t = 0; t < 2; t++) {
            int col = wave * 32 + t * 16 + l16;
#pragma unroll
            for (int q = 0; q < 4; q++) {
                int row = rowbase + g * 16 + quad * 4 + q;
                if (row < N_NODES)
                    hb[(size_t)row * 128 + col] = f2b(hsum[g][t][q]);
            }
        }
}

// ---------------------------------------------------------------------------
// Layer-2: [hWl|hWr] = h @ Wf2 (K=128); hWl -> bf16 buffer, out = hWr + bl_f.
__global__ __launch_bounds__(256, 4) void layer2_kernel(
    const unsigned short* __restrict__ hb, const unsigned short* __restrict__ Wfrag2,
    const float* __restrict__ bl_f, unsigned short* __restrict__ hWlb,
    float* __restrict__ out) {
    __shared__ unsigned short s_h[64 * LDS_STRIDE];
    int tid = threadIdx.x, wave = tid >> 6, lane = tid & 63;
    int quad = lane >> 4, l16 = lane & 15;
    int rowbase = blockIdx.x * 64;

#pragma unroll
    for (int it = 0; it < 4; it++) {
        int idx = tid + it * 256;
        int row = idx >> 4, c = idx & 15;
        int grow = rowbase + row;
        short8 hv = {0, 0, 0, 0, 0, 0, 0, 0};
        if (grow < N_NODES) hv = *(const short8*)(hb + (size_t)grow * 128 + c * 8);
        *(short8*)&s_h[row * LDS_STRIDE + c * 8] = hv;
    }
    __syncthreads();

    f32x4 acc[4][2];
#pragma unroll
    for (int g = 0; g < 4; g++) { acc[g][0] = (f32x4){0.f,0.f,0.f,0.f}; acc[g][1] = (f32x4){0.f,0.f,0.f,0.f}; }

    const unsigned short* W = Wfrag2 + wave * 4096;
#pragma unroll
    for (int s = 0; s < 4; s++) {
        short8 bf0 = *(const short8*)(W + s * 1024 + lane * 8);
        short8 bf1 = *(const short8*)(W + s * 1024 + 512 + lane * 8);
        int ko = s * 32 + quad * 8;
#pragma unroll
        for (int g = 0; g < 4; g++) {
            short8 af = *(const short8*)&s_h[(g * 16 + l16) * LDS_STRIDE + ko];
            acc[g][0] = __builtin_amdgcn_mfma_f32_16x16x32_bf16(af, bf0, acc[g][0], 0, 0, 0);
            acc[g][1] = __builtin_amdgcn_mfma_f32_16x16x32_bf16(af, bf1, acc[g][1], 0, 0, 0);
        }
    }

#pragma unroll
    for (int g = 0; g < 4; g++)
#pragma unroll
        for (int t = 0; t < 2; t++) {
            int col = wave * 32 + t * 16 + l16;
#pragma unroll
            for (int q = 0; q < 4; q++) {
                int row = rowbase + g * 16 + quad * 4 + q;
                if (row < N_NODES) {
                    if (col < 64) hWlb[(size_t)row * 64 + col] = f2b(acc[g][t][q]);
                    else out[(size_t)row * 64 + (col - 64)] = acc[g][t][q] + bl_f[col - 64];
                }
            }
        }
}

// ---------------------------------------------------------------------------
// Gather-mean of hWl (bf16, 64 ch = 128 B row = 16 x ushort4) + add into out.
// 4-nodes-per-wave slot structure; no cross-lane reduce.
__global__ void gather64_kernel(const unsigned short* __restrict__ hWlb, const int* __restrict__ adj,
                                const int* __restrict__ rowstart, const int* __restrict__ cnt,
                                float* __restrict__ out) {
    int wv = (blockIdx.x * blockDim.x + threadIdx.x) >> 6;
    int lane = threadIdx.x & 63;
    int nb = lane >> 4, c16 = lane & 15;
    int node = wv * 4 + nb;
    bool valid = node < N_NODES;
    int start = 0, deg = 0;
    if (valid) { start = rowstart[node]; deg = cnt[node]; }
    int jcap = min(deg, 16);
    int myidx = (valid && c16 < jcap) ? adj[start + c16] : 0;
    int dmax = jcap;
    dmax = max(dmax, __shfl_xor(dmax, 16));
    dmax = max(dmax, __shfl_xor(dmax, 32));
    float a0 = 0.f, a1 = 0.f, a2 = 0.f, a3 = 0.f;
    int sb = nb * 16;
    for (int j = 0; j < dmax; j += 2) {
        int s0 = __shfl(myidx, sb + j);
        int s1 = __shfl(myidx, sb + min(j + 1, 15));
        bool c0 = j < jcap, c1 = (j + 1) < jcap;
        ushort4v v0, v1;
        if (c0) v0 = *(const ushort4v*)(hWlb + (size_t)s0 * 64 + c16 * 4);
        if (c1) v1 = *(const ushort4v*)(hWlb + (size_t)s1 * 64 + c16 * 4);
        if (c0) { a0 += b2f(v0.x); a1 += b2f(v0.y); a2 += b2f(v0.z); a3 += b2f(v0.w); }
        if (c1) { a0 += b2f(v1.x); a1 += b2f(v1.y); a2 += b2f(v1.z); a3 += b2f(v1.w); }
    }
    for (int j = 16; j < deg; j++) {        // rare deg>16 tail
        int s = adj[start + j];
        ushort4v v = *(const ushort4v*)(hWlb + (size_t)s * 64 + c16 * 4);
        a0 += b2f(v.x); a1 += b2f(v.y); a2 += b2f(v.z); a3 += b2f(v.w);
    }
    if (valid) {
        float inv = 1.0f / fmaxf((float)deg, 1.0f);
        float4* o = (float4*)(out + (size_t)node * 64 + c16 * 4);
        float4 cur = *o;
        cur.x += a0 * inv; cur.y += a1 * inv; cur.z += a2 * inv; cur.w += a3 * inv;
        *o = cur;
    }
}

// ---------------------------------------------------------------------------
extern "C" void kernel_launch(void* const* d_in, const int* in_sizes, int n_in,
                              void* d_out, int out_size, void* d_ws, size_t ws_size,
                              hipStream_t stream) {
    const float* x    = (const float*)d_in[0];
    const float* Wl   = (const float*)d_in[1];
    const float* bl   = (const float*)d_in[2];
    const float* Wr   = (const float*)d_in[3];
    const float* Wl_f = (const float*)d_in[4];
    const float* bl_f = (const float*)d_in[5];
    const float* Wr_f = (const float*)d_in[6];
    const int* ei0 = (const int*)d_in[7];
    const int* ei1 = (const int*)d_in[8];
    const int* ei2 = (const int*)d_in[9];
    float* out = (float*)d_out;

    // workspace layout (offsets), total ~107 MB
    char* ws = (char*)d_ws;
    int* cnt               = (int*)(ws);                                   // 1.2 MB
    int* bincur            = (int*)(ws + 0x128000);                        // 1.5 KB
    int* rowstart          = (int*)(ws + ((size_t)4  << 20));              // 1.2 MB
    int* blocksum          = (int*)(ws + ((size_t)6  << 20));              // 1.2 KB
    unsigned short* Wfrag  = (unsigned short*)(ws + ((size_t)7  << 20));   // 192 KB
    unsigned short* Wfrag2 = (unsigned short*)(ws + ((size_t)15 << 19));   // 7.5MB, 32 KB
    int* adj               = (int*)(ws + ((size_t)8  << 20));              // 7.2 MB
    unsigned short* xb     = (unsigned short*)(ws + ((size_t)16 << 20));   // 25.6 MB
    unsigned short* hb     = (unsigned short*)(ws + ((size_t)68 << 20));   // 25.6 MB
    unsigned short* hWlb   = (unsigned short*)(ws + ((size_t)94 << 20));   // 12.8 MB
    unsigned* bins         = (unsigned*)(ws + ((size_t)42 << 20));         // 9.4 MB

    hipMemsetAsync(bincur, 0, 3 * SUBP * sizeof(int), stream);

    bin_kernel<<<dim3(ACH, 3), 256, 0, stream>>>(ei0, ei1, ei2, bins, bincur);
    count_kernel<<<dim3(SUBP, 3), 256, 0, stream>>>(bins, bincur, cnt);
    scan1_kernel<<<dim3(NCHUNK, 3), 1024, 0, stream>>>(cnt, rowstart, blocksum);
    scan2_kernel<<<1, 128, 0, stream>>>(blocksum);
    scan3_kernel<<<dim3(392, 3), 256, 0, stream>>>(rowstart, blocksum);
    fill_kernel<<<dim3(SUBP, 3), 256, 0, stream>>>(bins, bincur, rowstart, adj);
    wprep_kernel<<<448, 256, 0, stream>>>(Wl, Wr, Wl_f, Wr_f, Wfrag, Wfrag2);
    xcast_kernel<<<(N_NODES * 128 / 8) / 256, 256, 0, stream>>>(x, xb);

    const int TILE_BLOCKS = (N_NODES + 63) / 64;     // 1563
    fused1_kernel<<<TILE_BLOCKS, 256, 0, stream>>>(xb, adj, rowstart, cnt, Wfrag, bl, hb);
    layer2_kernel<<<TILE_BLOCKS, 256, 0, stream>>>(hb, Wfrag2, bl_f, hWlb, out);

    const int GATHER_BLOCKS = (N_NODES + 15) / 16;   // 4 waves/block x 4 nodes/wave
    gather64_kernel<<<GATHER_BLOCKS, 256, 0, stream>>>(hWlb, adj, rowstart, cnt, out);
}

// Round 10
// 279.024 us; speedup vs baseline: 1.9924x; 1.1499x over previous
//
#include <hip/hip_runtime.h>

#define N_NODES 100000
#define N_EDGES 600000
#define ZROW N_NODES         // sentinel zero-row index (xb/hWlb have N_NODES+1 rows)
#define NCHUNK 98            // ceil(100000/1024)
#define LDS_STRIDE 136       // ushorts per row: 128 + 8 pad
#define SUBP 128             // dst sub-partitions
#define SUB_SZ 782           // nodes per sub-partition (128*782 = 100096 >= 100000)
#define ECHUNK 2048          // edges per bin_kernel block
#define ACH 293              // ceil(600000/2048)
#define BCAP 6144            // per (rel,subpart) bin capacity (mean 4687, +21 sigma)

typedef __attribute__((ext_vector_type(8))) short short8;
typedef __attribute__((ext_vector_type(4))) float f32x4;
typedef __attribute__((ext_vector_type(4))) unsigned short ushort4v;
typedef __attribute__((ext_vector_type(8))) unsigned short ushort8v;

__device__ __forceinline__ unsigned short f2b(float f) {   // fp32 -> bf16 RNE
    unsigned u = __builtin_bit_cast(unsigned, f);
    return (unsigned short)((u + 0x7fffu + ((u >> 16) & 1u)) >> 16);
}
__device__ __forceinline__ float b2f(unsigned short b) {
    return __builtin_bit_cast(float, (unsigned)b << 16);
}

// ---------------------------------------------------------------------------
// Pass A: 128-way counting sort of edges by dst sub-partition. Edge packed
// into 4B: src (17b) | local-dst (10b, <782). LDS-staged compaction ->
// line-granular global writes into per-(rel,subpart) bins.
__global__ __launch_bounds__(256) void bin_kernel(const int* __restrict__ e0,
                                                  const int* __restrict__ e1,
                                                  const int* __restrict__ e2,
                                                  unsigned* __restrict__ bins,
                                                  int* __restrict__ bincur) {
    int r = blockIdx.y;
    const int* ei = (r == 0) ? e0 : (r == 1 ? e1 : e2);
    int base = blockIdx.x * ECHUNK;
    int nhere = min(ECHUNK, N_EDGES - base);
    __shared__ int lhist[SUBP], lstart[SUBP], lcur[SUBP], gbase[SUBP];
    __shared__ unsigned led[ECHUNK];
    __shared__ unsigned char lbkt[ECHUNK];
    int tid = threadIdx.x;
    for (int i = tid; i < SUBP; i += 256) { lhist[i] = 0; lcur[i] = 0; }
    __syncthreads();

    unsigned pk[8]; int bn[8];
#pragma unroll
    for (int k = 0; k < 8; k++) {
        int i = tid + k * 256;
        bn[k] = -1;
        if (i < nhere) {
            int e = base + i;
            int s = ei[e], d = ei[N_EDGES + e];
            int b = d / SUB_SZ;
            int ld = d - b * SUB_SZ;
            pk[k] = (unsigned)s | ((unsigned)ld << 17);
            bn[k] = b;
            atomicAdd(&lhist[b], 1);
        }
    }
    __syncthreads();
    if (tid == 0) {
        int run = 0;
        for (int b = 0; b < SUBP; b++) { lstart[b] = run; run += lhist[b]; }
    }
    __syncthreads();
#pragma unroll
    for (int k = 0; k < 8; k++) {
        if (bn[k] >= 0) {
            int slot = atomicAdd(&lcur[bn[k]], 1);
            int p = lstart[bn[k]] + slot;
            led[p] = pk[k];
            lbkt[p] = (unsigned char)bn[k];
        }
    }
    if (tid < SUBP) gbase[tid] = atomicAdd(&bincur[r * SUBP + tid], lhist[tid]);
    __syncthreads();
    for (int i = tid; i < nhere; i += 256) {
        int b = lbkt[i];
        int dstidx = gbase[b] + (i - lstart[b]);
        if (dstidx < BCAP)   // safety clamp: drop (never fault) on overflow
            bins[(size_t)(r * SUBP + b) * BCAP + dstidx] = led[i];
    }
}

// ---------------------------------------------------------------------------
// Degree count: one block per (rel,subpart). LDS histogram, coalesced cnt out.
__global__ __launch_bounds__(256) void count_kernel(const unsigned* __restrict__ bins,
                                                    const int* __restrict__ bincur,
                                                    int* __restrict__ cnt) {
    int p = blockIdx.x, r = blockIdx.y;
    int n0 = p * SUB_SZ;
    int nodes = min(SUB_SZ, N_NODES - n0);
    __shared__ int hist[SUB_SZ];
    int tid = threadIdx.x;
    for (int i = tid; i < SUB_SZ; i += 256) hist[i] = 0;
    __syncthreads();
    int len = min(bincur[r * SUBP + p], BCAP);
    const unsigned* b = bins + (size_t)(r * SUBP + p) * BCAP;
    for (int i = tid; i < len; i += 256) atomicAdd(&hist[b[i] >> 17], 1);
    __syncthreads();
    for (int i = tid; i < nodes; i += 256) cnt[r * N_NODES + n0 + i] = hist[i];
}

// ---------------------------------------------------------------------------
__global__ __launch_bounds__(1024) void scan1_kernel(const int* __restrict__ cnt,
                                                     int* __restrict__ rowstart,
                                                     int* __restrict__ blocksum) {
    int r = blockIdx.y;
    int tid = threadIdx.x, lane = tid & 63, wid = tid >> 6;
    int i = blockIdx.x * 1024 + tid;
    __shared__ int wsum[16];
    int v = (i < N_NODES) ? cnt[r * N_NODES + i] : 0;
    int incl = v;
#pragma unroll
    for (int off = 1; off < 64; off <<= 1) {
        int t = __shfl_up(incl, off);
        if (lane >= off) incl += t;
    }
    if (lane == 63) wsum[wid] = incl;
    __syncthreads();
    if (wid == 0) {
        int wv = (lane < 16) ? wsum[lane] : 0;
#pragma unroll
        for (int off = 1; off < 16; off <<= 1) {
            int t = __shfl_up(wv, off);
            if (lane >= off) wv += t;
        }
        if (lane < 16) wsum[lane] = wv;
    }
    __syncthreads();
    int woff = (wid > 0) ? wsum[wid - 1] : 0;
    if (i < N_NODES) rowstart[r * N_NODES + i] = woff + incl - v;
    if (tid == 0) blocksum[r * NCHUNK + blockIdx.x] = wsum[15];
}

__global__ __launch_bounds__(128) void scan2_kernel(int* __restrict__ blocksum) {
    __shared__ int s[3 * NCHUNK];
    int tid = threadIdx.x;
    for (int i = tid; i < 3 * NCHUNK; i += 128) s[i] = blocksum[i];
    __syncthreads();
    if (tid < 3) {
        int run = 0;
        for (int j = 0; j < NCHUNK; j++) { int t = s[tid * NCHUNK + j]; s[tid * NCHUNK + j] = run; run += t; }
    }
    __syncthreads();
    for (int i = tid; i < 3 * NCHUNK; i += 128) blocksum[i] = s[i];
}

__global__ void scan3_kernel(int* __restrict__ rowstart, const int* __restrict__ blocksum) {
    int r = blockIdx.y;
    int i = blockIdx.x * 256 + threadIdx.x;
    if (i < N_NODES)
        rowstart[r * N_NODES + i] += blocksum[r * NCHUNK + (i >> 10)];
}

// ---------------------------------------------------------------------------
// CSR fill: one block per (rel,subpart). Local cursor + adj slice staged in
// LDS (LDS atomics only), then streamed out with coalesced sequential stores.
__global__ __launch_bounds__(256) void fill_kernel(const unsigned* __restrict__ bins,
                                                   const int* __restrict__ bincur,
                                                   const int* __restrict__ rowstart,
                                                   int* __restrict__ adj) {
    int p = blockIdx.x, r = blockIdx.y;
    int n0 = p * SUB_SZ;
    int nodes = min(SUB_SZ, N_NODES - n0);
    __shared__ int lcur[SUB_SZ];
    __shared__ int sstage[BCAP];
    int tid = threadIdx.x;
    const int* rs = rowstart + r * N_NODES + n0;
    int rbase = rs[0];
    for (int i = tid; i < nodes; i += 256) lcur[i] = rs[i] - rbase;
    __syncthreads();
    int len = min(bincur[r * SUBP + p], BCAP);
    const unsigned* b = bins + (size_t)(r * SUBP + p) * BCAP;
    for (int i = tid; i < len; i += 256) {
        unsigned v = b[i];
        int pos = atomicAdd(&lcur[v >> 17], 1);
        if (pos < BCAP)   // safety clamp (cannot trigger with consistent counts)
            sstage[pos] = (int)(v & 0x1FFFFu);
    }
    __syncthreads();
    int* a = adj + (size_t)r * N_EDGES + rbase;
    for (int i = tid; i < len; i += 256) a[i] = sstage[i];
}

// ---------------------------------------------------------------------------
// x (fp32) -> xb (bf16), 8 elems/thread.
__global__ void xcast_kernel(const float* __restrict__ x, unsigned short* __restrict__ xb) {
    int idx = blockIdx.x * 256 + threadIdx.x;
    const float4* p = (const float4*)x + (size_t)idx * 2;
    float4 a = p[0], b = p[1];
    ushort8v o;
    o[0] = f2b(a.x); o[1] = f2b(a.y); o[2] = f2b(a.z); o[3] = f2b(a.w);
    o[4] = f2b(b.x); o[5] = f2b(b.y); o[6] = f2b(b.z); o[7] = f2b(b.w);
    *(ushort8v*)(xb + (size_t)idx * 8) = o;
}

// ---------------------------------------------------------------------------
// Pre-swizzle weights into MFMA B-fragment order.
__global__ void wprep_kernel(const float* __restrict__ Wl, const float* __restrict__ Wr,
                             const float* __restrict__ Wl_f, const float* __restrict__ Wr_f,
                             unsigned short* __restrict__ Wfrag, unsigned short* __restrict__ Wfrag2) {
    int idx = blockIdx.x * 256 + threadIdx.x;      // 448 blocks = 114688 threads
    int j = idx & 7, lane = (idx >> 3) & 63;
    int quad = lane >> 4, l16 = lane & 15;
    if (idx < 98304) {
        int t = (idx >> 9) & 1, s = (idx >> 10) & 7, w = (idx >> 13) & 3, r = idx >> 15;
        int k = s * 32 + quad * 8 + j;
        int n = w * 32 + t * 16 + l16;
        float v = (k < 128) ? Wl[((size_t)r * 128 + k) * 128 + n]
                            : Wr[((size_t)r * 128 + (k - 128)) * 128 + n];
        Wfrag[idx] = f2b(v);
    } else {
        int i2 = idx - 98304;
        if (i2 < 16384) {
            int t = (i2 >> 9) & 1, s = (i2 >> 10) & 3, w = (i2 >> 12) & 3;
            int k = s * 32 + quad * 8 + j;
            int n = w * 32 + t * 16 + l16;
            float v = (n < 64) ? Wl_f[(size_t)k * 64 + n] : Wr_f[(size_t)k * 64 + (n - 64)];
            Wfrag2[i2] = f2b(v);
        }
    }
}

// ---------------------------------------------------------------------------
// FUSED layer-1 with BRANCH-FREE pipelined gather: out-of-degree prefetch
// lanes hold ZROW (a zeroed sentinel row), so every row load in the j-loop
// is unconditional and independent -> the scheduler batches 4-8 loads in
// flight across the 4 slots (true MLP, no exec-mask serialization).
__global__ __launch_bounds__(256, 4) void fused1_kernel(
    const unsigned short* __restrict__ xb, const int* __restrict__ adj,
    const int* __restrict__ rowstart, const int* __restrict__ cnt,
    const unsigned short* __restrict__ Wfrag, const float* __restrict__ bl,
    unsigned short* __restrict__ hb) {
    __shared__ unsigned short s_x[64 * LDS_STRIDE];
    __shared__ unsigned short s_a[64 * LDS_STRIDE];
    int tid = threadIdx.x, wave = tid >> 6, lane = tid & 63;
    int quad = lane >> 4, l16 = lane & 15;       // quad==slot id, l16==chan lane
    int rowbase = blockIdx.x * 64;

    // stage x rows (once for all 3 relations)
#pragma unroll
    for (int it = 0; it < 4; it++) {
        int idx = tid + it * 256;
        int row = idx >> 4, c = idx & 15;
        int grow = rowbase + row;
        short8 xv = {0, 0, 0, 0, 0, 0, 0, 0};
        if (grow < N_NODES) xv = *(const short8*)(xb + (size_t)grow * 128 + c * 8);
        *(short8*)&s_x[row * LDS_STRIDE + c * 8] = xv;
    }

    f32x4 hsum[4][2];
#pragma unroll
    for (int g = 0; g < 4; g++) { hsum[g][0] = (f32x4){0.f,0.f,0.f,0.f}; hsum[g][1] = (f32x4){0.f,0.f,0.f,0.f}; }

    for (int r = 0; r < 3; r++) {
        const int* rs = rowstart + r * N_NODES;
        const int* ct = cnt + r * N_NODES;
        const int* aj = adj + (size_t)r * N_EDGES;

        // phase 1: all 4 rounds' rowstart/cnt loads (independent)
        int startv[4], degv[4], jcapv[4], idxv[4];
#pragma unroll
        for (int g4 = 0; g4 < 4; g4++) {
            int node = rowbase + wave * 16 + g4 * 4 + quad;
            bool valid = node < N_NODES;
            startv[g4] = valid ? rs[node] : 0;
            degv[g4]   = valid ? ct[node] : 0;
        }
        // phase 2: 16-index prefetches; out-of-degree lanes -> ZROW sentinel
#pragma unroll
        for (int g4 = 0; g4 < 4; g4++) {
            jcapv[g4] = min(degv[g4], 16);
            idxv[g4] = (l16 < jcapv[g4]) ? aj[startv[g4] + l16] : ZROW;
        }
        // wave-wide max rounds
        int m = max(max(jcapv[0], jcapv[1]), max(jcapv[2], jcapv[3]));
        m = max(m, __shfl_xor(m, 16));
        m = max(m, __shfl_xor(m, 32));

        float ac[4][8];
#pragma unroll
        for (int g4 = 0; g4 < 4; g4++)
#pragma unroll
            for (int k = 0; k < 8; k++) ac[g4][k] = 0.f;

        int sb = quad * 16;
        // phase 3: branch-free j-loop — all loads unconditional & batched
        for (int j = 0; j < m; j += 2) {
            int s0[4], s1[4];
#pragma unroll
            for (int g4 = 0; g4 < 4; g4++) {
                s0[g4] = __shfl(idxv[g4], sb + j);
                s1[g4] = __shfl(idxv[g4], sb + min(j + 1, 15));
            }
            ushort8v v0[4], v1[4];
#pragma unroll
            for (int g4 = 0; g4 < 4; g4++)
                v0[g4] = *(const ushort8v*)(xb + (size_t)s0[g4] * 128 + l16 * 8);
#pragma unroll
            for (int g4 = 0; g4 < 4; g4++)
                v1[g4] = *(const ushort8v*)(xb + (size_t)s1[g4] * 128 + l16 * 8);
#pragma unroll
            for (int g4 = 0; g4 < 4; g4++)
#pragma unroll
                for (int k = 0; k < 8; k++) ac[g4][k] += b2f(v0[g4][k]);
#pragma unroll
            for (int g4 = 0; g4 < 4; g4++)
#pragma unroll
                for (int k = 0; k < 8; k++) ac[g4][k] += b2f(v1[g4][k]);
        }
        // rare deg>16 tails
#pragma unroll
        for (int g4 = 0; g4 < 4; g4++) {
            for (int j = 16; j < degv[g4]; j++) {
                int s = aj[startv[g4] + j];
                ushort8v v = *(const ushort8v*)(xb + (size_t)s * 128 + l16 * 8);
#pragma unroll
                for (int k = 0; k < 8; k++) ac[g4][k] += b2f(v[k]);
            }
        }
        // write all 4 agg rows to LDS
#pragma unroll
        for (int g4 = 0; g4 < 4; g4++) {
            int nl = wave * 16 + g4 * 4 + quad;
            float inv = 1.0f / fmaxf((float)degv[g4], 1.0f);
            ushort8v o;
#pragma unroll
            for (int k = 0; k < 8; k++) o[k] = f2b(ac[g4][k] * inv);
            *(ushort8v*)&s_a[nl * LDS_STRIDE + l16 * 8] = o;
        }
        __syncthreads();

        f32x4 acc[4][2];
#pragma unroll
        for (int g = 0; g < 4; g++) { acc[g][0] = (f32x4){0.f,0.f,0.f,0.f}; acc[g][1] = (f32x4){0.f,0.f,0.f,0.f}; }

        const unsigned short* W = Wfrag + r * 32768 + wave * 8192;
#pragma unroll
        for (int s = 0; s < 8; s++) {
            short8 bf0 = *(const short8*)(W + s * 1024 + lane * 8);
            short8 bf1 = *(const short8*)(W + s * 1024 + 512 + lane * 8);
            const unsigned short* src = (s < 4) ? s_a : s_x;
            int ko = (s & 3) * 32 + quad * 8;
#pragma unroll
            for (int g = 0; g < 4; g++) {
                short8 af = *(const short8*)&src[(g * 16 + l16) * LDS_STRIDE + ko];
                acc[g][0] = __builtin_amdgcn_mfma_f32_16x16x32_bf16(af, bf0, acc[g][0], 0, 0, 0);
                acc[g][1] = __builtin_amdgcn_mfma_f32_16x16x32_bf16(af, bf1, acc[g][1], 0, 0, 0);
            }
        }

        float b0 = bl[r * 128 + wave * 32 + l16];
        float b1 = bl[r * 128 + wave * 32 + 16 + l16];
#pragma unroll
        for (int g = 0; g < 4; g++)
#pragma unroll
            for (int t = 0; t < 2; t++) {
                float bb = t ? b1 : b0;
#pragma unroll
                for (int q = 0; q < 4; q++)
                    hsum[g][t][q] += fmaxf(acc[g][t][q] + bb, 0.f) * (1.0f / 3.0f);
            }
        __syncthreads();   // before next relation's gather overwrites s_a
    }

    // single hb write (fp32-accumulated, one bf16 round)
#pragma unroll
    for (int g = 0; g < 4; g++)
#pragma unroll
        for (int t = 0; t < 2; t++) {
            int col = wave * 32 + t * 16 + l16;
#pragma unroll
            for (int q = 0; q < 4; q++) {
                int row = rowbase + g * 16 + quad * 4 + q;
                if (row < N_NODES)
                    hb[(size_t)row * 128 + col] = f2b(hsum[g][t][q]);
            }
        }
}

// ---------------------------------------------------------------------------
// Layer-2: [hWl|hWr] = h @ Wf2 (K=128); hWl -> bf16 buffer, out = hWr + bl_f.
__global__ __launch_bounds__(256, 4) void layer2_kernel(
    const unsigned short* __restrict__ hb, const unsigned short* __restrict__ Wfrag2,
    const float* __restrict__ bl_f, unsigned short* __restrict__ hWlb,
    float* __restrict__ out) {
    __shared__ unsigned short s_h[64 * LDS_STRIDE];
    int tid = threadIdx.x, wave = tid >> 6, lane = tid & 63;
    int quad = lane >> 4, l16 = lane & 15;
    int rowbase = blockIdx.x * 64;

#pragma unroll
    for (int it = 0; it < 4; it++) {
        int idx = tid + it * 256;
        int row = idx >> 4, c = idx & 15;
        int grow = rowbase + row;
        short8 hv = {0, 0, 0, 0, 0, 0, 0, 0};
        if (grow < N_NODES) hv = *(const short8*)(hb + (size_t)grow * 128 + c * 8);
        *(short8*)&s_h[row * LDS_STRIDE + c * 8] = hv;
    }
    __syncthreads();

    f32x4 acc[4][2];
#pragma unroll
    for (int g = 0; g < 4; g++) { acc[g][0] = (f32x4){0.f,0.f,0.f,0.f}; acc[g][1] = (f32x4){0.f,0.f,0.f,0.f}; }

    const unsigned short* W = Wfrag2 + wave * 4096;
#pragma unroll
    for (int s = 0; s < 4; s++) {
        short8 bf0 = *(const short8*)(W + s * 1024 + lane * 8);
        short8 bf1 = *(const short8*)(W + s * 1024 + 512 + lane * 8);
        int ko = s * 32 + quad * 8;
#pragma unroll
        for (int g = 0; g < 4; g++) {
            short8 af = *(const short8*)&s_h[(g * 16 + l16) * LDS_STRIDE + ko];
            acc[g][0] = __builtin_amdgcn_mfma_f32_16x16x32_bf16(af, bf0, acc[g][0], 0, 0, 0);
            acc[g][1] = __builtin_amdgcn_mfma_f32_16x16x32_bf16(af, bf1, acc[g][1], 0, 0, 0);
        }
    }

#pragma unroll
    for (int g = 0; g < 4; g++)
#pragma unroll
        for (int t = 0; t < 2; t++) {
            int col = wave * 32 + t * 16 + l16;
#pragma unroll
            for (int q = 0; q < 4; q++) {
                int row = rowbase + g * 16 + quad * 4 + q;
                if (row < N_NODES) {
                    if (col < 64) hWlb[(size_t)row * 64 + col] = f2b(acc[g][t][q]);
                    else out[(size_t)row * 64 + (col - 64)] = acc[g][t][q] + bl_f[col - 64];
                }
            }
        }
}

// ---------------------------------------------------------------------------
// Gather-mean of hWl (bf16, 64 ch = 128 B row = 16 x ushort4) + add into out.
// Branch-free via ZROW sentinel; 4-nodes-per-wave slots, no cross-lane reduce.
__global__ void gather64_kernel(const unsigned short* __restrict__ hWlb, const int* __restrict__ adj,
                                const int* __restrict__ rowstart, const int* __restrict__ cnt,
                                float* __restrict__ out) {
    int wv = (blockIdx.x * blockDim.x + threadIdx.x) >> 6;
    int lane = threadIdx.x & 63;
    int nb = lane >> 4, c16 = lane & 15;
    int node = wv * 4 + nb;
    bool valid = node < N_NODES;
    int start = 0, deg = 0;
    if (valid) { start = rowstart[node]; deg = cnt[node]; }
    int jcap = min(deg, 16);
    int myidx = (valid && c16 < jcap) ? adj[start + c16] : ZROW;
    int dmax = jcap;
    dmax = max(dmax, __shfl_xor(dmax, 16));
    dmax = max(dmax, __shfl_xor(dmax, 32));
    float a0 = 0.f, a1 = 0.f, a2 = 0.f, a3 = 0.f;
    int sb = nb * 16;
    for (int j = 0; j < dmax; j += 2) {
        int s0 = __shfl(myidx, sb + j);
        int s1 = __shfl(myidx, sb + min(j + 1, 15));
        ushort4v v0 = *(const ushort4v*)(hWlb + (size_t)s0 * 64 + c16 * 4);
        ushort4v v1 = *(const ushort4v*)(hWlb + (size_t)s1 * 64 + c16 * 4);
        a0 += b2f(v0.x) + b2f(v1.x); a1 += b2f(v0.y) + b2f(v1.y);
        a2 += b2f(v0.z) + b2f(v1.z); a3 += b2f(v0.w) + b2f(v1.w);
    }
    for (int j = 16; j < deg; j++) {        // rare deg>16 tail
        int s = adj[start + j];
        ushort4v v = *(const ushort4v*)(hWlb + (size_t)s * 64 + c16 * 4);
        a0 += b2f(v.x); a1 += b2f(v.y); a2 += b2f(v.z); a3 += b2f(v.w);
    }
    if (valid) {
        float inv = 1.0f / fmaxf((float)deg, 1.0f);
        float4* o = (float4*)(out + (size_t)node * 64 + c16 * 4);
        float4 cur = *o;
        cur.x += a0 * inv; cur.y += a1 * inv; cur.z += a2 * inv; cur.w += a3 * inv;
        *o = cur;
    }
}

// ---------------------------------------------------------------------------
extern "C" void kernel_launch(void* const* d_in, const int* in_sizes, int n_in,
                              void* d_out, int out_size, void* d_ws, size_t ws_size,
                              hipStream_t stream) {
    const float* x    = (const float*)d_in[0];
    const float* Wl   = (const float*)d_in[1];
    const float* bl   = (const float*)d_in[2];
    const float* Wr   = (const float*)d_in[3];
    const float* Wl_f = (const float*)d_in[4];
    const float* bl_f = (const float*)d_in[5];
    const float* Wr_f = (const float*)d_in[6];
    const int* ei0 = (const int*)d_in[7];
    const int* ei1 = (const int*)d_in[8];
    const int* ei2 = (const int*)d_in[9];
    float* out = (float*)d_out;

    // workspace layout (offsets), total ~107 MB
    char* ws = (char*)d_ws;
    int* cnt               = (int*)(ws);                                   // 1.2 MB
    int* bincur            = (int*)(ws + 0x128000);                        // 1.5 KB
    int* rowstart          = (int*)(ws + ((size_t)4  << 20));              // 1.2 MB
    int* blocksum          = (int*)(ws + ((size_t)6  << 20));              // 1.2 KB
    unsigned short* Wfrag  = (unsigned short*)(ws + ((size_t)7  << 20));   // 192 KB
    unsigned short* Wfrag2 = (unsigned short*)(ws + ((size_t)15 << 19));   // 7.5MB, 32 KB
    int* adj               = (int*)(ws + ((size_t)8  << 20));              // 7.2 MB
    unsigned short* xb     = (unsigned short*)(ws + ((size_t)16 << 20));   // 25.6 MB (+ zero row)
    unsigned short* hb     = (unsigned short*)(ws + ((size_t)68 << 20));   // 25.6 MB
    unsigned short* hWlb   = (unsigned short*)(ws + ((size_t)94 << 20));   // 12.8 MB (+ zero row)
    unsigned* bins         = (unsigned*)(ws + ((size_t)42 << 20));         // 9.4 MB

    hipMemsetAsync(bincur, 0, 3 * SUBP * sizeof(int), stream);
    hipMemsetAsync(xb + (size_t)ZROW * 128, 0, 128 * sizeof(unsigned short), stream);   // zero row
    hipMemsetAsync(hWlb + (size_t)ZROW * 64, 0, 64 * sizeof(unsigned short), stream);   // zero row

    bin_kernel<<<dim3(ACH, 3), 256, 0, stream>>>(ei0, ei1, ei2, bins, bincur);
    count_kernel<<<dim3(SUBP, 3), 256, 0, stream>>>(bins, bincur, cnt);
    scan1_kernel<<<dim3(NCHUNK, 3), 1024, 0, stream>>>(cnt, rowstart, blocksum);
    scan2_kernel<<<1, 128, 0, stream>>>(blocksum);
    scan3_kernel<<<dim3(392, 3), 256, 0, stream>>>(rowstart, blocksum);
    fill_kernel<<<dim3(SUBP, 3), 256, 0, stream>>>(bins, bincur, rowstart, adj);
    wprep_kernel<<<448, 256, 0, stream>>>(Wl, Wr, Wl_f, Wr_f, Wfrag, Wfrag2);
    xcast_kernel<<<(N_NODES * 128 / 8) / 256, 256, 0, stream>>>(x, xb);

    const int TILE_BLOCKS = (N_NODES + 63) / 64;     // 1563
    fused1_kernel<<<TILE_BLOCKS, 256, 0, stream>>>(xb, adj, rowstart, cnt, Wfrag, bl, hb);
    layer2_kernel<<<TILE_BLOCKS, 256, 0, stream>>>(hb, Wfrag2, bl_f, hWlb, out);

    const int GATHER_BLOCKS = (N_NODES + 15) / 16;   // 4 waves/block x 4 nodes/wave
    gather64_kernel<<<GATHER_BLOCKS, 256, 0, stream>>>(hWlb, adj, rowstart, cnt, out);
}

// Round 11
// 274.928 us; speedup vs baseline: 2.0221x; 1.0149x over previous
//
#include <hip/hip_runtime.h>

#define N_NODES 100000
#define N_EDGES 600000
#define ZROW N_NODES         // sentinel zero-row index (xb/hb have N_NODES+1 rows)
#define LDS_STRIDE 136       // ushorts per row: 128 + 8 pad
#define SUBP 128             // dst sub-partitions
#define SUB_SZ 782           // nodes per sub-partition (128*782 = 100096 >= 100000)
#define ECHUNK 2048          // edges per bin_kernel block
#define ACH 293              // ceil(600000/2048)
#define BCAP 6144            // per (rel,subpart) bin capacity (mean 4687, +21 sigma)

typedef __attribute__((ext_vector_type(8))) short short8;
typedef __attribute__((ext_vector_type(4))) float f32x4;
typedef __attribute__((ext_vector_type(8))) unsigned short ushort8v;

__device__ __forceinline__ unsigned short f2b(float f) {   // fp32 -> bf16 RNE
    unsigned u = __builtin_bit_cast(unsigned, f);
    return (unsigned short)((u + 0x7fffu + ((u >> 16) & 1u)) >> 16);
}
__device__ __forceinline__ float b2f(unsigned short b) {
    return __builtin_bit_cast(float, (unsigned)b << 16);
}

// ---------------------------------------------------------------------------
// Pass A: 128-way counting sort of edges by dst sub-partition. Edge packed
// into 4B: src (17b) | local-dst (10b, <782). LDS-staged compaction ->
// line-granular global writes into per-(rel,subpart) bins.
__global__ __launch_bounds__(256) void bin_kernel(const int* __restrict__ e0,
                                                  const int* __restrict__ e1,
                                                  const int* __restrict__ e2,
                                                  unsigned* __restrict__ bins,
                                                  int* __restrict__ bincur) {
    int r = blockIdx.y;
    const int* ei = (r == 0) ? e0 : (r == 1 ? e1 : e2);
    int base = blockIdx.x * ECHUNK;
    int nhere = min(ECHUNK, N_EDGES - base);
    __shared__ int lhist[SUBP], lstart[SUBP], lcur[SUBP], gbase[SUBP];
    __shared__ unsigned led[ECHUNK];
    __shared__ unsigned char lbkt[ECHUNK];
    int tid = threadIdx.x;
    for (int i = tid; i < SUBP; i += 256) { lhist[i] = 0; lcur[i] = 0; }
    __syncthreads();

    unsigned pk[8]; int bn[8];
#pragma unroll
    for (int k = 0; k < 8; k++) {
        int i = tid + k * 256;
        bn[k] = -1;
        if (i < nhere) {
            int e = base + i;
            int s = ei[e], d = ei[N_EDGES + e];
            int b = d / SUB_SZ;
            int ld = d - b * SUB_SZ;
            pk[k] = (unsigned)s | ((unsigned)ld << 17);
            bn[k] = b;
            atomicAdd(&lhist[b], 1);
        }
    }
    __syncthreads();
    if (tid == 0) {
        int run = 0;
        for (int b = 0; b < SUBP; b++) { lstart[b] = run; run += lhist[b]; }
    }
    __syncthreads();
#pragma unroll
    for (int k = 0; k < 8; k++) {
        if (bn[k] >= 0) {
            int slot = atomicAdd(&lcur[bn[k]], 1);
            int p = lstart[bn[k]] + slot;
            led[p] = pk[k];
            lbkt[p] = (unsigned char)bn[k];
        }
    }
    if (tid < SUBP) gbase[tid] = atomicAdd(&bincur[r * SUBP + tid], lhist[tid]);
    __syncthreads();
    for (int i = tid; i < nhere; i += 256) {
        int b = lbkt[i];
        int dstidx = gbase[b] + (i - lstart[b]);
        if (dstidx < BCAP)   // safety clamp: drop (never fault) on overflow
            bins[(size_t)(r * SUBP + b) * BCAP + dstidx] = led[i];
    }
}

// ---------------------------------------------------------------------------
// Tiny prefix over per-(rel,part) bin totals -> global partition edge bases.
__global__ __launch_bounds__(64) void pfx_kernel(const int* __restrict__ bincur,
                                                 int* __restrict__ pbase) {
    __shared__ int s[3 * SUBP];
    int tid = threadIdx.x;
    for (int i = tid; i < 3 * SUBP; i += 64) s[i] = bincur[i];
    __syncthreads();
    if (tid < 3) {
        int run = 0;
        for (int j = 0; j < SUBP; j++) { int t = s[tid * SUBP + j]; s[tid * SUBP + j] = run; run += t; }
    }
    __syncthreads();
    for (int i = tid; i < 3 * SUBP; i += 64) pbase[i] = s[i];
}

// ---------------------------------------------------------------------------
// Consolidated CSR build: one block per (rel,subpart). LDS histogram ->
// in-LDS 782-elem exclusive scan -> cnt/rowstart writes -> LDS-cursor fill
// -> coalesced adj streaming. Replaces count+scan1+scan2+scan3+fill.
__global__ __launch_bounds__(256) void csr_kernel(const unsigned* __restrict__ bins,
                                                  const int* __restrict__ bincur,
                                                  const int* __restrict__ pbase,
                                                  int* __restrict__ cnt,
                                                  int* __restrict__ rowstart,
                                                  int* __restrict__ adj) {
    int p = blockIdx.x, r = blockIdx.y;
    int n0 = p * SUB_SZ;
    int nodes = min(SUB_SZ, N_NODES - n0);
    __shared__ int hist[SUB_SZ];
    __shared__ int sstage[BCAP];
    __shared__ int wsums[4];
    int tid = threadIdx.x, lane = tid & 63, wid = tid >> 6;
    for (int i = tid; i < SUB_SZ; i += 256) hist[i] = 0;
    __syncthreads();
    int len = min(bincur[r * SUBP + p], BCAP);
    const unsigned* b = bins + (size_t)(r * SUBP + p) * BCAP;
    for (int i = tid; i < len; i += 256) atomicAdd(&hist[b[i] >> 17], 1);
    __syncthreads();
    // each thread owns hist[tid*4 .. tid*4+4)
    int base4 = tid * 4;
    int v[4]; int tsum = 0;
#pragma unroll
    for (int k = 0; k < 4; k++) {
        int i = base4 + k;
        v[k] = (i < SUB_SZ) ? hist[i] : 0;
        tsum += v[k];
    }
    for (int i = tid; i < nodes; i += 256) cnt[r * N_NODES + n0 + i] = hist[i];
    // wave-scan of thread sums
    int incl = tsum;
#pragma unroll
    for (int off = 1; off < 64; off <<= 1) {
        int t = __shfl_up(incl, off);
        if (lane >= off) incl += t;
    }
    if (lane == 63) wsums[wid] = incl;
    __syncthreads();   // hist reads done; wsums written
    if (tid == 0) { int run = 0; for (int w = 0; w < 4; w++) { int t = wsums[w]; wsums[w] = run; run += t; } }
    __syncthreads();
    int excl = incl - tsum + wsums[wid];
    int pb = pbase[r * SUBP + p];
    int run = excl;
#pragma unroll
    for (int k = 0; k < 4; k++) {
        int i = base4 + k;
        if (i < SUB_SZ) {
            if (i < nodes) rowstart[r * N_NODES + n0 + i] = pb + run;
            hist[i] = run;              // local cursor seed
        }
        run += v[k];
    }
    __syncthreads();
    for (int i = tid; i < len; i += 256) {
        unsigned vv = b[i];
        int pos = atomicAdd(&hist[vv >> 17], 1);
        if (pos < BCAP) sstage[pos] = (int)(vv & 0x1FFFFu);
    }
    __syncthreads();
    int* a = adj + (size_t)r * N_EDGES + pb;
    for (int i = tid; i < len; i += 256) a[i] = sstage[i];
}

// ---------------------------------------------------------------------------
// x (fp32) -> xb (bf16), 8 elems/thread.
__global__ void xcast_kernel(const float* __restrict__ x, unsigned short* __restrict__ xb) {
    int idx = blockIdx.x * 256 + threadIdx.x;
    const float4* p = (const float4*)x + (size_t)idx * 2;
    float4 a = p[0], b = p[1];
    ushort8v o;
    o[0] = f2b(a.x); o[1] = f2b(a.y); o[2] = f2b(a.z); o[3] = f2b(a.w);
    o[4] = f2b(b.x); o[5] = f2b(b.y); o[6] = f2b(b.z); o[7] = f2b(b.w);
    *(ushort8v*)(xb + (size_t)idx * 8) = o;
}

// ---------------------------------------------------------------------------
// Pre-swizzle weights into MFMA B-fragment order.
// Wfrag (layer1): unchanged. Wfrag2 (fused2): K=256 stacked [Wl_f;Wr_f], N=64;
// wave w owns cols [w*16,w*16+16); idx = ((w*8+s)*512 + lane*8 + j),
// value = (k<128 ? Wl_f[k][n] : Wr_f[k-128][n]), k=s*32+quad*8+j, n=w*16+l16.
__global__ void wprep_kernel(const float* __restrict__ Wl, const float* __restrict__ Wr,
                             const float* __restrict__ Wl_f, const float* __restrict__ Wr_f,
                             unsigned short* __restrict__ Wfrag, unsigned short* __restrict__ Wfrag2) {
    int idx = blockIdx.x * 256 + threadIdx.x;      // 448 blocks = 114688 threads
    int j = idx & 7, lane = (idx >> 3) & 63;
    int quad = lane >> 4, l16 = lane & 15;
    if (idx < 98304) {
        int t = (idx >> 9) & 1, s = (idx >> 10) & 7, w = (idx >> 13) & 3, r = idx >> 15;
        int k = s * 32 + quad * 8 + j;
        int n = w * 32 + t * 16 + l16;
        float v = (k < 128) ? Wl[((size_t)r * 128 + k) * 128 + n]
                            : Wr[((size_t)r * 128 + (k - 128)) * 128 + n];
        Wfrag[idx] = f2b(v);
    } else {
        int i2 = idx - 98304;
        if (i2 < 16384) {
            int s = (i2 >> 9) & 7, w = i2 >> 12;
            int k = s * 32 + quad * 8 + j;
            int n = w * 16 + l16;
            float v = (k < 128) ? Wl_f[(size_t)k * 64 + n] : Wr_f[(size_t)(k - 128) * 64 + n];
            Wfrag2[i2] = f2b(v);
        }
    }
}

// ---------------------------------------------------------------------------
// FUSED layer-1 with branch-free pipelined gather (ZROW sentinel): unchanged
// from round 10 (91 us steady-state).
__global__ __launch_bounds__(256, 4) void fused1_kernel(
    const unsigned short* __restrict__ xb, const int* __restrict__ adj,
    const int* __restrict__ rowstart, const int* __restrict__ cnt,
    const unsigned short* __restrict__ Wfrag, const float* __restrict__ bl,
    unsigned short* __restrict__ hb) {
    __shared__ unsigned short s_x[64 * LDS_STRIDE];
    __shared__ unsigned short s_a[64 * LDS_STRIDE];
    int tid = threadIdx.x, wave = tid >> 6, lane = tid & 63;
    int quad = lane >> 4, l16 = lane & 15;
    int rowbase = blockIdx.x * 64;

#pragma unroll
    for (int it = 0; it < 4; it++) {
        int idx = tid + it * 256;
        int row = idx >> 4, c = idx & 15;
        int grow = rowbase + row;
        short8 xv = {0, 0, 0, 0, 0, 0, 0, 0};
        if (grow < N_NODES) xv = *(const short8*)(xb + (size_t)grow * 128 + c * 8);
        *(short8*)&s_x[row * LDS_STRIDE + c * 8] = xv;
    }

    f32x4 hsum[4][2];
#pragma unroll
    for (int g = 0; g < 4; g++) { hsum[g][0] = (f32x4){0.f,0.f,0.f,0.f}; hsum[g][1] = (f32x4){0.f,0.f,0.f,0.f}; }

    for (int r = 0; r < 3; r++) {
        const int* rs = rowstart + r * N_NODES;
        const int* ct = cnt + r * N_NODES;
        const int* aj = adj + (size_t)r * N_EDGES;

        int startv[4], degv[4], jcapv[4], idxv[4];
#pragma unroll
        for (int g4 = 0; g4 < 4; g4++) {
            int node = rowbase + wave * 16 + g4 * 4 + quad;
            bool valid = node < N_NODES;
            startv[g4] = valid ? rs[node] : 0;
            degv[g4]   = valid ? ct[node] : 0;
        }
#pragma unroll
        for (int g4 = 0; g4 < 4; g4++) {
            jcapv[g4] = min(degv[g4], 16);
            idxv[g4] = (l16 < jcapv[g4]) ? aj[startv[g4] + l16] : ZROW;
        }
        int m = max(max(jcapv[0], jcapv[1]), max(jcapv[2], jcapv[3]));
        m = max(m, __shfl_xor(m, 16));
        m = max(m, __shfl_xor(m, 32));

        float ac[4][8];
#pragma unroll
        for (int g4 = 0; g4 < 4; g4++)
#pragma unroll
            for (int k = 0; k < 8; k++) ac[g4][k] = 0.f;

        int sb = quad * 16;
        for (int j = 0; j < m; j += 2) {
            int s0[4], s1[4];
#pragma unroll
            for (int g4 = 0; g4 < 4; g4++) {
                s0[g4] = __shfl(idxv[g4], sb + j);
                s1[g4] = __shfl(idxv[g4], sb + min(j + 1, 15));
            }
            ushort8v v0[4], v1[4];
#pragma unroll
            for (int g4 = 0; g4 < 4; g4++)
                v0[g4] = *(const ushort8v*)(xb + (size_t)s0[g4] * 128 + l16 * 8);
#pragma unroll
            for (int g4 = 0; g4 < 4; g4++)
                v1[g4] = *(const ushort8v*)(xb + (size_t)s1[g4] * 128 + l16 * 8);
#pragma unroll
            for (int g4 = 0; g4 < 4; g4++)
#pragma unroll
                for (int k = 0; k < 8; k++) ac[g4][k] += b2f(v0[g4][k]);
#pragma unroll
            for (int g4 = 0; g4 < 4; g4++)
#pragma unroll
                for (int k = 0; k < 8; k++) ac[g4][k] += b2f(v1[g4][k]);
        }
#pragma unroll
        for (int g4 = 0; g4 < 4; g4++) {
            for (int j = 16; j < degv[g4]; j++) {
                int s = aj[startv[g4] + j];
                ushort8v v = *(const ushort8v*)(xb + (size_t)s * 128 + l16 * 8);
#pragma unroll
                for (int k = 0; k < 8; k++) ac[g4][k] += b2f(v[k]);
            }
        }
#pragma unroll
        for (int g4 = 0; g4 < 4; g4++) {
            int nl = wave * 16 + g4 * 4 + quad;
            float inv = 1.0f / fmaxf((float)degv[g4], 1.0f);
            ushort8v o;
#pragma unroll
            for (int k = 0; k < 8; k++) o[k] = f2b(ac[g4][k] * inv);
            *(ushort8v*)&s_a[nl * LDS_STRIDE + l16 * 8] = o;
        }
        __syncthreads();

        f32x4 acc[4][2];
#pragma unroll
        for (int g = 0; g < 4; g++) { acc[g][0] = (f32x4){0.f,0.f,0.f,0.f}; acc[g][1] = (f32x4){0.f,0.f,0.f,0.f}; }

        const unsigned short* W = Wfrag + r * 32768 + wave * 8192;
#pragma unroll
        for (int s = 0; s < 8; s++) {
            short8 bf0 = *(const short8*)(W + s * 1024 + lane * 8);
            short8 bf1 = *(const short8*)(W + s * 1024 + 512 + lane * 8);
            const unsigned short* src = (s < 4) ? s_a : s_x;
            int ko = (s & 3) * 32 + quad * 8;
#pragma unroll
            for (int g = 0; g < 4; g++) {
                short8 af = *(const short8*)&src[(g * 16 + l16) * LDS_STRIDE + ko];
                acc[g][0] = __builtin_amdgcn_mfma_f32_16x16x32_bf16(af, bf0, acc[g][0], 0, 0, 0);
                acc[g][1] = __builtin_amdgcn_mfma_f32_16x16x32_bf16(af, bf1, acc[g][1], 0, 0, 0);
            }
        }

        float b0 = bl[r * 128 + wave * 32 + l16];
        float b1 = bl[r * 128 + wave * 32 + 16 + l16];
#pragma unroll
        for (int g = 0; g < 4; g++)
#pragma unroll
            for (int t = 0; t < 2; t++) {
                float bb = t ? b1 : b0;
#pragma unroll
                for (int q = 0; q < 4; q++)
                    hsum[g][t][q] += fmaxf(acc[g][t][q] + bb, 0.f) * (1.0f / 3.0f);
            }
        __syncthreads();
    }

#pragma unroll
    for (int g = 0; g < 4; g++)
#pragma unroll
        for (int t = 0; t < 2; t++) {
            int col = wave * 32 + t * 16 + l16;
#pragma unroll
            for (int q = 0; q < 4; q++) {
                int row = rowbase + g * 16 + quad * 4 + q;
                if (row < N_NODES)
                    hb[(size_t)row * 128 + col] = f2b(hsum[g][t][q]);
            }
        }
}

// ---------------------------------------------------------------------------
// FUSED layer-2 (gather-first): agg2 = mean-gather(h) into LDS (branch-free
// slot gather from hb rows), then out = [agg2|h](K=256) @ [Wl_f;Wr_f] + bl_f.
// Eliminates hWlb buffer and gather64 kernel. Wave w owns 16 output cols.
__global__ __launch_bounds__(256, 4) void fused2_kernel(
    const unsigned short* __restrict__ hb, const int* __restrict__ adj,
    const int* __restrict__ rowstart, const int* __restrict__ cnt,
    const unsigned short* __restrict__ Wfrag2, const float* __restrict__ bl_f,
    float* __restrict__ out) {
    __shared__ unsigned short s_h[64 * LDS_STRIDE];
    __shared__ unsigned short s_a[64 * LDS_STRIDE];
    int tid = threadIdx.x, wave = tid >> 6, lane = tid & 63;
    int quad = lane >> 4, l16 = lane & 15;
    int rowbase = blockIdx.x * 64;

    // stage h rows
#pragma unroll
    for (int it = 0; it < 4; it++) {
        int idx = tid + it * 256;
        int row = idx >> 4, c = idx & 15;
        int grow = rowbase + row;
        short8 hv = {0, 0, 0, 0, 0, 0, 0, 0};
        if (grow < N_NODES) hv = *(const short8*)(hb + (size_t)grow * 128 + c * 8);
        *(short8*)&s_h[row * LDS_STRIDE + c * 8] = hv;
    }

    // gather agg2 rows (relation 0) — branch-free, 16 nodes/wave
    int startv[4], degv[4], jcapv[4], idxv[4];
#pragma unroll
    for (int g4 = 0; g4 < 4; g4++) {
        int node = rowbase + wave * 16 + g4 * 4 + quad;
        bool valid = node < N_NODES;
        startv[g4] = valid ? rowstart[node] : 0;
        degv[g4]   = valid ? cnt[node] : 0;
    }
#pragma unroll
    for (int g4 = 0; g4 < 4; g4++) {
        jcapv[g4] = min(degv[g4], 16);
        idxv[g4] = (l16 < jcapv[g4]) ? adj[startv[g4] + l16] : ZROW;
    }
    int m = max(max(jcapv[0], jcapv[1]), max(jcapv[2], jcapv[3]));
    m = max(m, __shfl_xor(m, 16));
    m = max(m, __shfl_xor(m, 32));

    float ac[4][8];
#pragma unroll
    for (int g4 = 0; g4 < 4; g4++)
#pragma unroll
        for (int k = 0; k < 8; k++) ac[g4][k] = 0.f;

    int sb = quad * 16;
    for (int j = 0; j < m; j += 2) {
        int s0[4], s1[4];
#pragma unroll
        for (int g4 = 0; g4 < 4; g4++) {
            s0[g4] = __shfl(idxv[g4], sb + j);
            s1[g4] = __shfl(idxv[g4], sb + min(j + 1, 15));
        }
        ushort8v v0[4], v1[4];
#pragma unroll
        for (int g4 = 0; g4 < 4; g4++)
            v0[g4] = *(const ushort8v*)(hb + (size_t)s0[g4] * 128 + l16 * 8);
#pragma unroll
        for (int g4 = 0; g4 < 4; g4++)
            v1[g4] = *(const ushort8v*)(hb + (size_t)s1[g4] * 128 + l16 * 8);
#pragma unroll
        for (int g4 = 0; g4 < 4; g4++)
#pragma unroll
            for (int k = 0; k < 8; k++) ac[g4][k] += b2f(v0[g4][k]);
#pragma unroll
        for (int g4 = 0; g4 < 4; g4++)
#pragma unroll
            for (int k = 0; k < 8; k++) ac[g4][k] += b2f(v1[g4][k]);
    }
#pragma unroll
    for (int g4 = 0; g4 < 4; g4++) {
        for (int j = 16; j < degv[g4]; j++) {
            int s = adj[startv[g4] + j];
            ushort8v v = *(const ushort8v*)(hb + (size_t)s * 128 + l16 * 8);
#pragma unroll
            for (int k = 0; k < 8; k++) ac[g4][k] += b2f(v[k]);
        }
    }
#pragma unroll
    for (int g4 = 0; g4 < 4; g4++) {
        int nl = wave * 16 + g4 * 4 + quad;
        float inv = 1.0f / fmaxf((float)degv[g4], 1.0f);
        ushort8v o;
#pragma unroll
        for (int k = 0; k < 8; k++) o[k] = f2b(ac[g4][k] * inv);
        *(ushort8v*)&s_a[nl * LDS_STRIDE + l16 * 8] = o;
    }
    __syncthreads();

    f32x4 acc[4];
#pragma unroll
    for (int g = 0; g < 4; g++) acc[g] = (f32x4){0.f, 0.f, 0.f, 0.f};

    const unsigned short* W = Wfrag2 + wave * 4096;
#pragma unroll
    for (int s = 0; s < 8; s++) {
        short8 bf0 = *(const short8*)(W + s * 512 + lane * 8);
        const unsigned short* src = (s < 4) ? s_a : s_h;
        int ko = (s & 3) * 32 + quad * 8;
#pragma unroll
        for (int g = 0; g < 4; g++) {
            short8 af = *(const short8*)&src[(g * 16 + l16) * LDS_STRIDE + ko];
            acc[g] = __builtin_amdgcn_mfma_f32_16x16x32_bf16(af, bf0, acc[g], 0, 0, 0);
        }
    }

    float bb = bl_f[wave * 16 + l16];
    int col = wave * 16 + l16;
#pragma unroll
    for (int g = 0; g < 4; g++)
#pragma unroll
        for (int q = 0; q < 4; q++) {
            int row = rowbase + g * 16 + quad * 4 + q;
            if (row < N_NODES)
                out[(size_t)row * 64 + col] = acc[g][q] + bb;
        }
}

// ---------------------------------------------------------------------------
extern "C" void kernel_launch(void* const* d_in, const int* in_sizes, int n_in,
                              void* d_out, int out_size, void* d_ws, size_t ws_size,
                              hipStream_t stream) {
    const float* x    = (const float*)d_in[0];
    const float* Wl   = (const float*)d_in[1];
    const float* bl   = (const float*)d_in[2];
    const float* Wr   = (const float*)d_in[3];
    const float* Wl_f = (const float*)d_in[4];
    const float* bl_f = (const float*)d_in[5];
    const float* Wr_f = (const float*)d_in[6];
    const int* ei0 = (const int*)d_in[7];
    const int* ei1 = (const int*)d_in[8];
    const int* ei2 = (const int*)d_in[9];
    float* out = (float*)d_out;

    // workspace layout (offsets), total ~94 MB used
    char* ws = (char*)d_ws;
    int* cnt               = (int*)(ws);                                   // 1.2 MB
    int* bincur            = (int*)(ws + 0x128000);                        // 1.5 KB
    int* rowstart          = (int*)(ws + ((size_t)4  << 20));              // 1.2 MB
    int* pbase             = (int*)(ws + ((size_t)6  << 20));              // 1.5 KB
    unsigned short* Wfrag  = (unsigned short*)(ws + ((size_t)7  << 20));   // 192 KB
    unsigned short* Wfrag2 = (unsigned short*)(ws + ((size_t)15 << 19));   // 7.5MB, 32 KB
    int* adj               = (int*)(ws + ((size_t)8  << 20));              // 7.2 MB
    unsigned short* xb     = (unsigned short*)(ws + ((size_t)16 << 20));   // 25.6 MB (+ zero row)
    unsigned short* hb     = (unsigned short*)(ws + ((size_t)68 << 20));   // 25.6 MB (+ zero row)
    unsigned* bins         = (unsigned*)(ws + ((size_t)42 << 20));         // 9.4 MB

    hipMemsetAsync(bincur, 0, 3 * SUBP * sizeof(int), stream);
    hipMemsetAsync(xb + (size_t)ZROW * 128, 0, 128 * sizeof(unsigned short), stream);   // zero row
    hipMemsetAsync(hb + (size_t)ZROW * 128, 0, 128 * sizeof(unsigned short), stream);   // zero row

    bin_kernel<<<dim3(ACH, 3), 256, 0, stream>>>(ei0, ei1, ei2, bins, bincur);
    pfx_kernel<<<1, 64, 0, stream>>>(bincur, pbase);
    csr_kernel<<<dim3(SUBP, 3), 256, 0, stream>>>(bins, bincur, pbase, cnt, rowstart, adj);
    wprep_kernel<<<448, 256, 0, stream>>>(Wl, Wr, Wl_f, Wr_f, Wfrag, Wfrag2);
    xcast_kernel<<<(N_NODES * 128 / 8) / 256, 256, 0, stream>>>(x, xb);

    const int TILE_BLOCKS = (N_NODES + 63) / 64;     // 1563
    fused1_kernel<<<TILE_BLOCKS, 256, 0, stream>>>(xb, adj, rowstart, cnt, Wfrag, bl, hb);
    fused2_kernel<<<TILE_BLOCKS, 256, 0, stream>>>(hb, adj, rowstart, cnt, Wfrag2, bl_f, out);
}